// Round 4
// baseline (559.214 us; speedup 1.0000x reference)
//
#include <hip/hip_runtime.h>
#include <math.h>

#define HW 1024
typedef unsigned short u16;
typedef __attribute__((ext_vector_type(8))) short short8v;   // 8 bf16
typedef __attribute__((ext_vector_type(4))) float f32x4;
typedef __attribute__((ext_vector_type(16))) float f32x16;

__device__ __forceinline__ float elu_f(float x){ return x>0.f? x : (__expf(x)-1.f); }
__device__ __forceinline__ float sig_f(float x){ return 1.f/(1.f+__expf(-x)); }
__device__ __forceinline__ u16 f2bf(float f){ unsigned u=__float_as_uint(f); return (u16)((u + 0x7fffu + ((u>>16)&1u))>>16); }
__device__ __forceinline__ float bf2f(u16 h){ return __uint_as_float(((unsigned)h)<<16); }

// ---------------------------------------------------------------------------
// Weight converts (one-time): 2x2 convs get tap-major K reorder (k' = tap*128+c)
// ---------------------------------------------------------------------------
__global__ __launch_bounds__(256)
void wc2_k(const float* __restrict__ rw, u16* __restrict__ wb, int total)
{
    int i = blockIdx.x*256 + threadIdx.x;
    if (i >= total) return;
    int kp = i & 511, row = i >> 9;
    int tap = kp >> 7, c = kp & 127;
    wb[i] = f2bf(rw[(size_t)row*512 + c*4 + tap]);
}
__global__ __launch_bounds__(256)
void wc1_k(const float* __restrict__ w0, const float* __restrict__ w1,
           const float* __restrict__ w2, const float* __restrict__ w3, u16* __restrict__ wb)
{
    int i = blockIdx.x*256 + threadIdx.x;   // 0..65535
    const float* src = (i<16384)? w0 : (i<32768)? w1 : (i<49152)? w2 : w3;
    wb[i] = f2bf(src[i & 16383]);
}

// ---------------------------------------------------------------------------
// init: x (B,128,HW) f32 -> A (B,HW,128) f32 pixel-major + Eb bf16(elu(x))
// ---------------------------------------------------------------------------
__global__ __launch_bounds__(256)
void init_k(const float* __restrict__ x, float* __restrict__ A, u16* __restrict__ Eb)
{
    __shared__ float t[32][132];
    const int b = blockIdx.y, p0 = blockIdx.x*32;
    const int tid = threadIdx.x;
    const int cr = tid >> 3, p4 = (tid & 7)*4;
    #pragma unroll
    for (int cc = 0; cc < 128; cc += 32) {
        const float4 v = *(const float4*)(x + ((size_t)b*128 + cc + cr)*HW + p0 + p4);
        t[p4+0][cc+cr]=v.x; t[p4+1][cc+cr]=v.y; t[p4+2][cc+cr]=v.z; t[p4+3][cc+cr]=v.w;
    }
    __syncthreads();
    const int pr = tid >> 3, c4 = (tid & 7)*4;
    #pragma unroll
    for (int cc = 0; cc < 128; cc += 32) {
        const int c = cc + c4;
        float4 v; v.x=t[pr][c]; v.y=t[pr][c+1]; v.z=t[pr][c+2]; v.w=t[pr][c+3];
        *(float4*)(A + ((size_t)b*HW + p0 + pr)*128 + c) = v;
        ushort4 e;
        e.x=f2bf(elu_f(v.x)); e.y=f2bf(elu_f(v.y)); e.z=f2bf(elu_f(v.z)); e.w=f2bf(elu_f(v.w));
        *(ushort4*)(Eb + ((size_t)b*HW + p0 + pr)*128 + c) = e;
    }
}

// ---------------------------------------------------------------------------
// Flat MFMA conv (2x2 im2col tap-major or 1x1). LDS-free, depth-2 software
// pipeline: step ks+1's fragments load while step ks's MFMAs issue.
// Block = 64px x NOUT ch, 4 waves (2ch x 2px).
// EPI 0: out = bf16(elu(acc+bias))            (NOUT=128)
// EPI 1: gate fused (NOUT=256): o = A + t1*sig(t2); A=o (f32); out0=bf16(elu(o))
// EPI 2: s = elu(acc+bias) + bf16(aux); out0 = bf16(elu(s))   (NOUT=128)
// ---------------------------------------------------------------------------
#define LOADSTEP(ks, sl) do {                                                     \
    const int k0_ = (ks)*32;                                                      \
    const int tap_ = k0_>>7, c0_ = k0_&127;                                       \
    _Pragma("unroll")                                                             \
    for (int nf=0; nf<2; ++nf) {                                                  \
        const bool ok_ = (okm[nf]>>tap_)&1;                                       \
        const int prd_ = (TAPS==4 && ok_) ? OFF[tap_] : 0;                        \
        const short8v ld_ = *(const short8v*)(eb + (size_t)(pp[nf]+prd_)*128 + c0_ + lg*8); \
        be[sl][nf] = ok_ ? ld_ : zv;                                              \
    }                                                                             \
    _Pragma("unroll")                                                             \
    for (int mf=0; mf<NF; ++mf) aw[sl][mf] = *(const short8v*)(wp[mf] + k0_);     \
} while(0)

template<int NOUT, int TAPS, int EPI>
__global__ __launch_bounds__(256, 2)
void convf(const u16* __restrict__ Wb, const float* __restrict__ bias,
           const u16* __restrict__ Ein, u16* __restrict__ out0,
           float* __restrict__ Aio, const u16* __restrict__ aux)
{
    constexpr int K  = TAPS*128;
    constexpr int NF = NOUT/32;
    constexpr int NSTEP = K/32;
    const int tid = threadIdx.x;
    const int b = blockIdx.z, p0 = blockIdx.x*64;
    const int wave = tid>>6, lane = tid&63;
    const int px0 = (wave&1)*32, ch0 = (wave>>1)*64;
    const int lr = lane&15, lg = lane>>4;

    int cfr[NF];
    #pragma unroll
    for (int mf=0; mf<NF; ++mf)
        cfr[mf] = (EPI==1) ? ((mf<4)? ch0+mf*16 : 128+ch0+(mf-4)*16) : ch0+mf*16;
    const u16* wp[NF];
    #pragma unroll
    for (int mf=0; mf<NF; ++mf) wp[mf] = Wb + (size_t)(cfr[mf]+lr)*K + lg*8;
    int pp[2];
    #pragma unroll
    for (int nf=0; nf<2; ++nf) pp[nf] = p0 + px0 + nf*16 + lr;
    const u16* eb = Ein + (size_t)b*HW*128;
    unsigned okm[2];
    #pragma unroll
    for (int nf=0; nf<2; ++nf) {
        if (TAPS==1) okm[nf] = 0xF;
        else {
            int py = pp[nf]>>5, px = pp[nf]&31;
            okm[nf] = 8u | ((py>0&&px>0)?1u:0u) | ((py>0)?2u:0u) | ((px>0)?4u:0u);
        }
    }
    f32x4 acc[NF][2] = {};
    const int OFF[4] = {-33,-32,-1,0};
    const short8v zv = {};
    short8v aw[2][NF];       // weight frags, double slot
    short8v be[2][2];        // im2col frags, double slot

    LOADSTEP(0, 0);
    #pragma unroll
    for (int ks = 0; ks < NSTEP; ++ks) {
        if (ks + 1 < NSTEP) LOADSTEP(ks + 1, (ks + 1) & 1);
        const int sl = ks & 1;
        #pragma unroll
        for (int mf=0; mf<NF; ++mf) {
            acc[mf][0] = __builtin_amdgcn_mfma_f32_16x16x32_bf16(aw[sl][mf], be[sl][0], acc[mf][0],0,0,0);
            acc[mf][1] = __builtin_amdgcn_mfma_f32_16x16x32_bf16(aw[sl][mf], be[sl][1], acc[mf][1],0,0,0);
        }
    }
    // epilogue: D lane: col(px) = l&15 (== pp[nf]), rows(ch) = cfr[mf] + 4*lg + r
    if constexpr (EPI == 1) {
        #pragma unroll
        for (int mf=0; mf<4; ++mf) {
            const int c1b = ch0 + mf*16 + lg*4;
            const float4 b1 = *(const float4*)(bias + c1b);
            const float4 b2 = *(const float4*)(bias + 128 + c1b);
            #pragma unroll
            for (int nf=0; nf<2; ++nf) {
                const int px = pp[nf];
                float* ap = Aio + ((size_t)b*HW + px)*128 + c1b;
                const float4 pv = *(const float4*)ap;
                float o0 = pv.x + (acc[mf][nf][0]+b1.x)*sig_f(acc[mf+4][nf][0]+b2.x);
                float o1 = pv.y + (acc[mf][nf][1]+b1.y)*sig_f(acc[mf+4][nf][1]+b2.y);
                float o2 = pv.z + (acc[mf][nf][2]+b1.z)*sig_f(acc[mf+4][nf][2]+b2.z);
                float o3 = pv.w + (acc[mf][nf][3]+b1.w)*sig_f(acc[mf+4][nf][3]+b2.w);
                float4 ov; ov.x=o0; ov.y=o1; ov.z=o2; ov.w=o3;
                *(float4*)ap = ov;
                ushort4 e;
                e.x=f2bf(elu_f(o0)); e.y=f2bf(elu_f(o1)); e.z=f2bf(elu_f(o2)); e.w=f2bf(elu_f(o3));
                *(ushort4*)(out0 + ((size_t)b*HW + px)*128 + c1b) = e;
            }
        }
    } else {
        #pragma unroll
        for (int mf=0; mf<NF; ++mf) {
            const int cb = cfr[mf] + lg*4;
            const float4 bb = *(const float4*)(bias + cb);
            #pragma unroll
            for (int nf=0; nf<2; ++nf) {
                const int px = pp[nf];
                float v0 = acc[mf][nf][0]+bb.x, v1 = acc[mf][nf][1]+bb.y;
                float v2 = acc[mf][nf][2]+bb.z, v3 = acc[mf][nf][3]+bb.w;
                ushort4 e;
                if constexpr (EPI == 2) {
                    const ushort4 c4 = *(const ushort4*)(aux + ((size_t)b*HW + px)*128 + cb);
                    e.x = f2bf(elu_f(elu_f(v0) + bf2f(c4.x)));
                    e.y = f2bf(elu_f(elu_f(v1) + bf2f(c4.y)));
                    e.z = f2bf(elu_f(elu_f(v2) + bf2f(c4.z)));
                    e.w = f2bf(elu_f(elu_f(v3) + bf2f(c4.w)));
                } else {
                    e.x=f2bf(elu_f(v0)); e.y=f2bf(elu_f(v1));
                    e.z=f2bf(elu_f(v2)); e.w=f2bf(elu_f(v3));
                }
                *(ushort4*)(out0 + ((size_t)b*HW + px)*128 + cb) = e;
            }
        }
    }
}

// ---------------------------------------------------------------------------
// Final 1x1 conv, channel-major f32 out: y = elu(W*Es + b) + x. Depth-2 pipeline.
// ---------------------------------------------------------------------------
__global__ __launch_bounds__(256, 2)
void convcm(const u16* __restrict__ Wb, const float* __restrict__ bias,
            const u16* __restrict__ Es, const float* __restrict__ x, float* __restrict__ out)
{
    const int tid = threadIdx.x, b = blockIdx.z, p0 = blockIdx.x*64;
    const int wave = tid>>6, lane = tid&63;
    const int px0 = (wave&1)*32, oc0 = (wave>>1)*64;
    const int lr = lane&15, lg = lane>>4;
    f32x4 acc[2][4] = {};
    const u16* ep[2];
    #pragma unroll
    for (int mi=0; mi<2; ++mi) ep[mi] = Es + ((size_t)b*HW + p0+px0+mi*16+lr)*128 + lg*8;
    const u16* wq[4];
    #pragma unroll
    for (int ni=0; ni<4; ++ni) wq[ni] = Wb + (size_t)(oc0+ni*16+lr)*128 + lg*8;
    short8v am[2][2], bw[2][4];
    #pragma unroll
    for (int mi=0; mi<2; ++mi) am[0][mi] = *(const short8v*)(ep[mi]);
    #pragma unroll
    for (int ni=0; ni<4; ++ni) bw[0][ni] = *(const short8v*)(wq[ni]);
    #pragma unroll
    for (int ks=0; ks<4; ++ks) {
        if (ks+1 < 4) {
            const int k1 = (ks+1)*32, s1 = (ks+1)&1;
            #pragma unroll
            for (int mi=0; mi<2; ++mi) am[s1][mi] = *(const short8v*)(ep[mi]+k1);
            #pragma unroll
            for (int ni=0; ni<4; ++ni) bw[s1][ni] = *(const short8v*)(wq[ni]+k1);
        }
        const int sl = ks&1;
        #pragma unroll
        for (int ni=0; ni<4; ++ni) {
            acc[0][ni] = __builtin_amdgcn_mfma_f32_16x16x32_bf16(am[sl][0], bw[sl][ni], acc[0][ni],0,0,0);
            acc[1][ni] = __builtin_amdgcn_mfma_f32_16x16x32_bf16(am[sl][1], bw[sl][ni], acc[1][ni],0,0,0);
        }
    }
    #pragma unroll
    for (int mi=0; mi<2; ++mi) {
        const int pxb = p0 + px0 + mi*16 + lg*4;
        #pragma unroll
        for (int ni=0; ni<4; ++ni) {
            const int oc = oc0 + ni*16 + lr;
            const float bv = bias[oc];
            const float4 xr = *(const float4*)(x + ((size_t)b*128 + oc)*HW + pxb);
            float4 o;
            o.x = elu_f(acc[mi][ni][0]+bv) + xr.x;
            o.y = elu_f(acc[mi][ni][1]+bv) + xr.y;
            o.z = elu_f(acc[mi][ni][2]+bv) + xr.z;
            o.w = elu_f(acc[mi][ni][3]+bv) + xr.w;
            *(float4*)(out + ((size_t)b*128 + oc)*HW + pxb) = o;
        }
    }
}

// ---------------------------------------------------------------------------
// qkv: fp32 GEMM (M=160,K=128) + pos-enc cols; q,k -> bf16 (B,HW,16) (0.25 in q),
// v -> bf16 V^T (B,128,HW).
// ---------------------------------------------------------------------------
__global__ __launch_bounds__(256)
void qkv_k(const float* __restrict__ W, const float* __restrict__ bias,
           const float* __restrict__ A, u16* __restrict__ qo, u16* __restrict__ ko,
           u16* __restrict__ vo)
{
    __shared__ float As[32][68];
    __shared__ float Bs[32][68];
    const int tid = threadIdx.x, b = blockIdx.z;
    const int p0 = blockIdx.x*64, m0 = blockIdx.y*64;
    const int tx = tid&15, ty = tid>>4;
    float acc[4][4] = {};
    const float* Ab = A + (size_t)b*HW*128;
    for (int k0=0; k0<128; k0+=32) {
        {
            const int m = tid>>2, kb = (tid&3)*8;
            const bool mok = (m0+m) < 160;
            const float* wr = W + (size_t)(m0+m)*130 + k0 + kb;
            #pragma unroll
            for (int j=0;j<8;++j) As[kb+j][m] = mok ? wr[j] : 0.f;
        }
        #pragma unroll
        for (int half=0; half<2; ++half) {
            const int n = (tid>>3) + half*32, kk = (tid&7)*4;
            const float4 v4 = *(const float4*)(Ab + (size_t)(p0+n)*128 + k0+kk);
            Bs[kk][n]=v4.x; Bs[kk+1][n]=v4.y; Bs[kk+2][n]=v4.z; Bs[kk+3][n]=v4.w;
        }
        __syncthreads();
        #pragma unroll
        for (int kk=0; kk<32; ++kk) {
            const float4 a4 = *(const float4*)&As[kk][ty*4];
            const float4 b4 = *(const float4*)&Bs[kk][tx*4];
            const float av[4]={a4.x,a4.y,a4.z,a4.w}, bv[4]={b4.x,b4.y,b4.z,b4.w};
            #pragma unroll
            for (int mi=0;mi<4;++mi)
                #pragma unroll
                for (int ni=0;ni<4;++ni)
                    acc[mi][ni] = fmaf(av[mi], bv[ni], acc[mi][ni]);
        }
        __syncthreads();
    }
    #pragma unroll
    for (int mi=0;mi<4;++mi) {
        const int m = m0 + ty*4 + mi;
        if (m >= 160) continue;
        const float bv = bias[m];
        const float wy = W[(size_t)m*130 + 128], wx = W[(size_t)m*130 + 129];
        #pragma unroll
        for (int ni=0;ni<4;++ni) {
            const int p = p0 + tx*4 + ni;
            const float py = (float)(p>>5)*0.03125f - 0.5f;
            const float px = (float)(p&31)*0.03125f - 0.5f;
            const float v = acc[mi][ni] + bv + wy*py + wx*px;
            if (m < 16)       qo[((size_t)b*HW + p)*16 + m]        = f2bf(0.25f*v);
            else if (m < 32)  ko[((size_t)b*HW + p)*16 + (m-16)]   = f2bf(v);
            else              vo[((size_t)b*128 + (m-32))*HW + p]  = f2bf(v);
        }
    }
}

// ---------------------------------------------------------------------------
// MFMA causal attention. One wave per 32-query tile. 32x32x16 bf16 MFMAs.
// ---------------------------------------------------------------------------
__global__ __launch_bounds__(64)
void attn_mfma(const u16* __restrict__ qb, const u16* __restrict__ kb,
               const u16* __restrict__ vb, u16* __restrict__ ob)
{
    const int lane = threadIdx.x;
    const int bid  = blockIdx.x;            // 0..1023
    const int qt   = 31 - (bid >> 5);       // long tiles first
    const int b    = bid & 31;
    const int q0   = qt * 32;
    const int lq = lane & 31, hf = lane >> 5;

    const short8v Qf = *(const short8v*)(qb + ((size_t)b*HW + q0 + lq)*16 + hf*8);
    f32x16 acc[4] = {{},{},{},{}};
    float mrun = -1e30f, lrun = 0.f;

    unsigned diagm = 0;
    #pragma unroll
    for (int r=0; r<16; ++r) {
        const int row = (r&3) + 8*(r>>2) + 4*hf;
        diagm |= (row <= lq) ? (1u<<r) : 0u;
    }
    const f32x16 zc = {};
    for (int c = 0; c <= qt; ++c) {
        const int kv0 = c*32;
        const short8v Kf = *(const short8v*)(kb + ((size_t)b*HW + kv0 + lq)*16 + hf*8);
        f32x16 st = __builtin_amdgcn_mfma_f32_32x32x16_bf16(Kf, Qf, zc, 0,0,0);
        if (c == qt) {
            #pragma unroll
            for (int r=0; r<16; ++r)
                st[r] = ((diagm>>r)&1) ? st[r] : -1e30f;
        }
        float mc = st[0];
        #pragma unroll
        for (int r=1; r<16; ++r) mc = fmaxf(mc, st[r]);
        mc = fmaxf(mc, __shfl_xor(mc, 32));
        if (!__all(mc <= mrun)) {
            const float mnew = fmaxf(mrun, mc);
            const float corr = __expf(mrun - mnew);
            lrun *= corr;
            #pragma unroll
            for (int f=0; f<4; ++f)
                #pragma unroll
                for (int r=0; r<16; ++r) acc[f][r] *= corr;
            mrun = mnew;
        }
        float ps[16]; float lsum = 0.f;
        #pragma unroll
        for (int r=0; r<16; ++r) { ps[r] = __expf(st[r] - mrun); lsum += ps[r]; }
        lrun += lsum + __shfl_xor(lsum, 32);
        unsigned pk[8], sw[8];
        #pragma unroll
        for (int i=0; i<8; ++i)
            pk[i] = (unsigned)f2bf(ps[2*i]) | ((unsigned)f2bf(ps[2*i+1])<<16);
        #pragma unroll
        for (int i=0; i<8; ++i) sw[i] = __shfl_xor(pk[i], 32);
        union { unsigned u[4]; short8v v; } B1, B2;
        B1.u[0] = hf ? sw[2] : pk[0];  B1.u[1] = hf ? sw[3] : pk[1];
        B1.u[2] = hf ? pk[2] : sw[0];  B1.u[3] = hf ? pk[3] : sw[1];
        B2.u[0] = hf ? sw[6] : pk[4];  B2.u[1] = hf ? sw[7] : pk[5];
        B2.u[2] = hf ? pk[6] : sw[4];  B2.u[3] = hf ? pk[7] : sw[5];
        #pragma unroll
        for (int f=0; f<4; ++f) {
            const u16* vr = vb + ((size_t)b*128 + f*32 + lq)*HW + kv0 + hf*8;
            const short8v A1 = *(const short8v*)(vr);
            const short8v A2 = *(const short8v*)(vr + 16);
            acc[f] = __builtin_amdgcn_mfma_f32_32x32x16_bf16(A1, B1.v, acc[f], 0,0,0);
            acc[f] = __builtin_amdgcn_mfma_f32_32x32x16_bf16(A2, B2.v, acc[f], 0,0,0);
        }
    }
    const float inv = 1.f / lrun;
    u16* orow = ob + ((size_t)b*HW + q0 + lq)*128;
    #pragma unroll
    for (int f=0; f<4; ++f) {
        #pragma unroll
        for (int g=0; g<4; ++g) {
            const int d0 = f*32 + 8*g + 4*hf;
            ushort4 o4;
            o4.x = f2bf(acc[f][g*4+0]*inv);
            o4.y = f2bf(acc[f][g*4+1]*inv);
            o4.z = f2bf(acc[f][g*4+2]*inv);
            o4.w = f2bf(acc[f][g*4+3]*inv);
            *(ushort4*)(orow + d0) = o4;
        }
    }
}

extern "C" void kernel_launch(void* const* d_in, const int* in_sizes, int n_in,
                              void* d_out, int out_size, void* d_ws, size_t ws_size,
                              hipStream_t stream) {
    const float* x    = (const float*)d_in[0];
    const float* rw1  = (const float*)d_in[1];
    const float* rb1  = (const float*)d_in[2];
    const float* rw2  = (const float*)d_in[3];
    const float* rb2  = (const float*)d_in[4];
    const float* qkvw = (const float*)d_in[5];
    const float* qkvb = (const float*)d_in[6];
    const float* apw  = (const float*)d_in[7];
    const float* apb  = (const float*)d_in[8];
    const float* ocw  = (const float*)d_in[9];
    const float* ocb  = (const float*)d_in[10];
    const float* oaw  = (const float*)d_in[11];
    const float* oab  = (const float*)d_in[12];
    const float* opw  = (const float*)d_in[13];
    const float* opb  = (const float*)d_in[14];
    float* out = (float*)d_out;
    float* ws = (float*)d_ws;

    // Workspace (float offsets, 64 MiB total):
    float* A  = ws;                                  // [0, 4M)   (B,HW,128) f32
    u16* Eb   = (u16*)(ws + 4194304);                // [4M, 6M)  bf16(elu(state))
    u16* E2   = (u16*)(ws + 6291456);                // [6M, 8M)  conv1 out / c1'
    u16* qb   = (u16*)(ws + 8388608);                // [8M, 8.25M)
    u16* kb   = (u16*)(ws + 8650752);                // [8.25M, 8.5M)
    u16* vb   = (u16*)(ws + 8912896);                // [8.5M, 10.5M)  V^T
    u16* ob   = (u16*)(ws + 11010048);               // [10.5M, 12.5M)
    u16* Ea   = (u16*)(ws + 13107200);               // [12.5M, 14.5M)
    u16* Es   = (u16*)(ws + 8388608);                // reuse qkv region
    u16* w1b  = (u16*)(ws + 15204352);               // 6*128*512
    u16* w2b  = (u16*)(ws + 15400960);               // 6*256*512
    u16* wh   = (u16*)(ws + 15794176);               // 4*128*128 (ap, oc, oa, op)
    u16* c1p  = E2;

    dim3 blk(256);
    wc2_k<<<1536, blk, 0, stream>>>(rw1, w1b, 6*128*512);
    wc2_k<<<3072, blk, 0, stream>>>(rw2, w2b, 6*256*512);
    wc1_k<<<256,  blk, 0, stream>>>(apw, ocw, oaw, opw, wh);
    init_k<<<dim3(32, 32), blk, 0, stream>>>(x, A, Eb);
    for (int i = 0; i < 6; ++i) {
        convf<128,4,0><<<dim3(16,1,32), blk, 0, stream>>>(
            w1b + (size_t)i*65536, rb1 + i*128, Eb, E2, nullptr, nullptr);
        convf<256,4,1><<<dim3(16,1,32), blk, 0, stream>>>(
            w2b + (size_t)i*131072, rb2 + i*256, E2, Eb, A, nullptr);
    }
    qkv_k<<<dim3(16,3,32), blk, 0, stream>>>(qkvw, qkvb, A, qb, kb, vb);
    attn_mfma<<<1024, dim3(64), 0, stream>>>(qb, kb, vb, ob);
    // attn_proj -> Ea = bf16(elu(attn_out))
    convf<128,1,0><<<dim3(16,1,32), blk, 0, stream>>>(wh, apb, ob, Ea, nullptr, nullptr);
    // out_conv -> c1' = bf16(elu(c1))
    convf<128,1,0><<<dim3(16,1,32), blk, 0, stream>>>(wh + 16384, ocb, Eb, c1p, nullptr, nullptr);
    // out_attn + add c1 -> Es = bf16(elu(c1+a1))
    convf<128,1,2><<<dim3(16,1,32), blk, 0, stream>>>(wh + 32768, oab, Ea, Es, nullptr, c1p);
    // out_proj -> y = elu(.)+x, channel-major f32
    convcm<<<dim3(16,1,32), blk, 0, stream>>>(wh + 49152, opb, Es, x, out);
}

// Round 5
// 491.654 us; speedup vs baseline: 1.1374x; 1.1374x over previous
//
#include <hip/hip_runtime.h>
#include <math.h>

#define HW 1024
typedef unsigned short u16;
typedef __attribute__((ext_vector_type(8))) short short8v;   // 8 bf16
typedef __attribute__((ext_vector_type(4))) float f32x4;
typedef __attribute__((ext_vector_type(16))) float f32x16;

__device__ __forceinline__ float elu_f(float x){ return x>0.f? x : (__expf(x)-1.f); }
__device__ __forceinline__ float sig_f(float x){ return 1.f/(1.f+__expf(-x)); }
__device__ __forceinline__ u16 f2bf(float f){ unsigned u=__float_as_uint(f); return (u16)((u + 0x7fffu + ((u>>16)&1u))>>16); }
__device__ __forceinline__ float bf2f(u16 h){ return __uint_as_float(((unsigned)h)<<16); }

// ---------------------------------------------------------------------------
// One-time weight converts
// ---------------------------------------------------------------------------
__global__ __launch_bounds__(256)
void wc2_k(const float* __restrict__ rw, u16* __restrict__ wb, int total)
{
    int i = blockIdx.x*256 + threadIdx.x;
    if (i >= total) return;
    int kp = i & 511, row = i >> 9;
    int tap = kp >> 7, c = kp & 127;
    wb[i] = f2bf(rw[(size_t)row*512 + c*4 + tap]);   // k' = tap*128 + c
}
__global__ __launch_bounds__(256)
void wc1_k(const float* __restrict__ w0, const float* __restrict__ w1,
           const float* __restrict__ w2, const float* __restrict__ w3, u16* __restrict__ wb)
{
    int i = blockIdx.x*256 + threadIdx.x;   // 0..65535
    const float* src = (i<16384)? w0 : (i<32768)? w1 : (i<49152)? w2 : w3;
    wb[i] = f2bf(src[i & 16383]);
}
__global__ __launch_bounds__(256)
void wcq_k(const float* __restrict__ qkvw, u16* __restrict__ qw)
{
    int i = blockIdx.x*256 + threadIdx.x;   // 192*128 = 24576
    if (i >= 24576) return;
    int r = i >> 7, c = i & 127;
    qw[i] = (r < 160) ? f2bf(qkvw[(size_t)r*130 + c]) : (u16)0;
}

// ---------------------------------------------------------------------------
// init: x (B,128,HW) f32 -> A (B,HW,128) f32 pixel-major + Eb bf16(elu(x))
// ---------------------------------------------------------------------------
__global__ __launch_bounds__(256)
void init_k(const float* __restrict__ x, float* __restrict__ A, u16* __restrict__ Eb)
{
    __shared__ float t[32][132];
    const int b = blockIdx.y, p0 = blockIdx.x*32;
    const int tid = threadIdx.x;
    const int cr = tid >> 3, p4 = (tid & 7)*4;
    #pragma unroll
    for (int cc = 0; cc < 128; cc += 32) {
        const float4 v = *(const float4*)(x + ((size_t)b*128 + cc + cr)*HW + p0 + p4);
        t[p4+0][cc+cr]=v.x; t[p4+1][cc+cr]=v.y; t[p4+2][cc+cr]=v.z; t[p4+3][cc+cr]=v.w;
    }
    __syncthreads();
    const int pr = tid >> 3, c4 = (tid & 7)*4;
    #pragma unroll
    for (int cc = 0; cc < 128; cc += 32) {
        const int c = cc + c4;
        float4 v; v.x=t[pr][c]; v.y=t[pr][c+1]; v.z=t[pr][c+2]; v.w=t[pr][c+3];
        *(float4*)(A + ((size_t)b*HW + p0 + pr)*128 + c) = v;
        ushort4 e;
        e.x=f2bf(elu_f(v.x)); e.y=f2bf(elu_f(v.y)); e.z=f2bf(elu_f(v.z)); e.w=f2bf(elu_f(v.w));
        *(ushort4*)(Eb + ((size_t)b*HW + p0 + pr)*128 + c) = e;
    }
}

// ---------------------------------------------------------------------------
// LDS-staged MFMA conv GEMM (2x2 im2col tap-major or 1x1).
// out[px][ch] = epi( sum_k im2col[px][k] * W[ch][k] ).
// Block: BM px x 128 ch-rows, 4 waves = 2px x 2ch quadrants; BK=32; dbuf LDS,
// reg-staged coalesced global loads, 80B row stride (2-way bank = free).
// EPI 0: out0 = bf16(elu(acc+bias))
// EPI 1: gate (ch-rows = {t1 32 | t2 32} per wave-half): o = Aio + t1*sig(t2);
//        Aio = o (f32), out0 = bf16(elu(o)), raw0 = bf16(o) if RAW
// EPI 2: out0 = bf16(elu( elu(acc+bias) + aux ))
// EPI 3: fout[ch-major] = elu(acc+bias) + xres   (f32)
// ---------------------------------------------------------------------------
template<int BM, int TAPS, int EPI, bool RAW>
__global__ __launch_bounds__(256)
void convt(const u16* __restrict__ Wb, const float* __restrict__ bias,
           const u16* __restrict__ Ein, u16* __restrict__ out0,
           float* __restrict__ Aio, const u16* __restrict__ aux,
           u16* __restrict__ raw0, const float* __restrict__ xres,
           float* __restrict__ fout)
{
    constexpr int K  = TAPS*128;
    constexpr int NS = K/32;
    constexpr int MA = BM/32;          // pixel frags per wave
    constexpr int NCA = BM/64;         // A chunks per thread (1 or 2)
    __shared__ u16 As[2][BM*40];       // [px][32k] rows padded to 40 u16
    __shared__ u16 Bs[2][128*40];      // [ch-row][32k]
    const int tid = threadIdx.x;
    const int b = blockIdx.z, p0 = blockIdx.x*BM, cb0 = blockIdx.y*64;
    const int wv = tid>>6, lane = tid&63, lr = lane&15, lg = lane>>4;
    const int pxh = wv&1, chh = wv>>1;
    const u16* eb = Ein + (size_t)b*HW*128;

    // ---- staging descriptors ----
    int apx[NCA], ag[NCA], arow[NCA]; unsigned aok[NCA];
    #pragma unroll
    for (int c=0;c<NCA;++c) {
        const int ci = tid + c*256;
        arow[c] = ci>>2; ag[c] = ci&3;
        apx[c] = p0 + arow[c];
        if (TAPS==1) aok[c] = 0xF;
        else {
            const int py_=apx[c]>>5, px_=apx[c]&31;
            aok[c] = 8u | ((py_>0&&px_>0)?1u:0u) | ((py_>0)?2u:0u) | ((px_>0)?4u:0u);
        }
    }
    const u16* wsrc[2]; int brow[2], bgp[2];
    #pragma unroll
    for (int c=0;c<2;++c) {
        const int ci = tid + c*256;
        const int row = ci>>2, g = ci&3;
        brow[c]=row; bgp[c]=g;
        int ch;
        if (EPI==1) {   // interleave: wave-half h holds t1[cb0+h*32..] and t2[128+cb0+h*32..]
            const int h=row>>6, f=(row>>4)&3, r=row&15;
            ch = (f<2) ? (cb0 + h*32 + f*16 + r) : (128 + cb0 + h*32 + (f-2)*16 + r);
        } else ch = row;
        wsrc[c] = Wb + (size_t)ch*K + g*8;
    }
    const int OFF[4] = {-33,-32,-1,0};

    uint4 ra[NCA], rb[2];
    auto GLOAD = [&](int ks) {
        const int k0 = ks*32;
        const int tap = (TAPS==4)? (k0>>7) : 0;
        const int c0  = (TAPS==4)? (k0&127) : k0;
        #pragma unroll
        for (int c=0;c<NCA;++c) {
            const bool ok = (aok[c]>>tap)&1;
            const int prd = (TAPS==4 && ok) ? OFF[tap] : 0;
            uint4 v = *(const uint4*)(eb + (size_t)(apx[c]+prd)*128 + c0 + ag[c]*8);
            if (!ok) { v.x=0u; v.y=0u; v.z=0u; v.w=0u; }
            ra[c] = v;
        }
        #pragma unroll
        for (int c=0;c<2;++c) rb[c] = *(const uint4*)(wsrc[c] + k0);
    };
    auto SSTORE = [&](int buf) {
        #pragma unroll
        for (int c=0;c<NCA;++c)
            *(uint4*)&As[buf][arow[c]*40 + ag[c]*8] = ra[c];
        #pragma unroll
        for (int c=0;c<2;++c)
            *(uint4*)&Bs[buf][brow[c]*40 + bgp[c]*8] = rb[c];
    };

    f32x4 acc[4][MA] = {};
    GLOAD(0); SSTORE(0); __syncthreads();
    for (int ks=0; ks<NS; ++ks) {
        const int cur = ks&1;
        if (ks+1 < NS) GLOAD(ks+1);
        short8v wf[4], pf[MA];
        #pragma unroll
        for (int f=0;f<4;++f)
            wf[f] = *(const short8v*)&Bs[cur][(chh*64 + f*16 + lr)*40 + lg*8];
        #pragma unroll
        for (int m=0;m<MA;++m)
            pf[m] = *(const short8v*)&As[cur][(pxh*(BM/2) + m*16 + lr)*40 + lg*8];
        #pragma unroll
        for (int f=0;f<4;++f)
            #pragma unroll
            for (int m=0;m<MA;++m)
                acc[f][m] = __builtin_amdgcn_mfma_f32_16x16x32_bf16(wf[f], pf[m], acc[f][m],0,0,0);
        __syncthreads();
        if (ks+1 < NS) { SSTORE((ks+1)&1); __syncthreads(); }
    }

    // ---- epilogues: D lane -> px = ...+lr (col), ch = frag-row lg*4+r ----
    if constexpr (EPI == 1) {
        #pragma unroll
        for (int f=0; f<2; ++f) {
            const int c = cb0 + chh*32 + f*16 + lg*4;
            const float4 b1 = *(const float4*)(bias + c);
            const float4 b2 = *(const float4*)(bias + 128 + c);
            #pragma unroll
            for (int m=0;m<MA;++m) {
                const int px = p0 + pxh*(BM/2) + m*16 + lr;
                float* ap = Aio + ((size_t)b*HW+px)*128 + c;
                const float4 pv = *(const float4*)ap;
                const float o0 = pv.x + (acc[f][m][0]+b1.x)*sig_f(acc[f+2][m][0]+b2.x);
                const float o1 = pv.y + (acc[f][m][1]+b1.y)*sig_f(acc[f+2][m][1]+b2.y);
                const float o2 = pv.z + (acc[f][m][2]+b1.z)*sig_f(acc[f+2][m][2]+b2.z);
                const float o3 = pv.w + (acc[f][m][3]+b1.w)*sig_f(acc[f+2][m][3]+b2.w);
                float4 ov; ov.x=o0; ov.y=o1; ov.z=o2; ov.w=o3;
                *(float4*)ap = ov;
                ushort4 e;
                e.x=f2bf(elu_f(o0)); e.y=f2bf(elu_f(o1)); e.z=f2bf(elu_f(o2)); e.w=f2bf(elu_f(o3));
                *(ushort4*)(out0 + ((size_t)b*HW+px)*128 + c) = e;
                if constexpr (RAW) {
                    ushort4 rr;
                    rr.x=f2bf(o0); rr.y=f2bf(o1); rr.z=f2bf(o2); rr.w=f2bf(o3);
                    *(ushort4*)(raw0 + ((size_t)b*HW+px)*128 + c) = rr;
                }
            }
        }
    } else if constexpr (EPI == 0 || EPI == 2) {
        #pragma unroll
        for (int f=0; f<4; ++f) {
            const int c = chh*64 + f*16 + lg*4;
            const float4 bb = *(const float4*)(bias + c);
            #pragma unroll
            for (int m=0;m<MA;++m) {
                const int px = p0 + pxh*(BM/2) + m*16 + lr;
                const float v0=acc[f][m][0]+bb.x, v1=acc[f][m][1]+bb.y;
                const float v2=acc[f][m][2]+bb.z, v3=acc[f][m][3]+bb.w;
                ushort4 e;
                if constexpr (EPI == 2) {
                    const ushort4 c4 = *(const ushort4*)(aux + ((size_t)b*HW+px)*128 + c);
                    e.x = f2bf(elu_f(elu_f(v0) + bf2f(c4.x)));
                    e.y = f2bf(elu_f(elu_f(v1) + bf2f(c4.y)));
                    e.z = f2bf(elu_f(elu_f(v2) + bf2f(c4.z)));
                    e.w = f2bf(elu_f(elu_f(v3) + bf2f(c4.w)));
                } else {
                    e.x=f2bf(elu_f(v0)); e.y=f2bf(elu_f(v1));
                    e.z=f2bf(elu_f(v2)); e.w=f2bf(elu_f(v3));
                }
                *(ushort4*)(out0 + ((size_t)b*HW+px)*128 + c) = e;
            }
        }
    } else {   // EPI 3: channel-major f32 out + residual
        #pragma unroll
        for (int f=0; f<4; ++f) {
            const int c = chh*64 + f*16 + lg*4;
            const float* bp = bias + c;
            #pragma unroll
            for (int m=0;m<MA;++m) {
                const int px = p0 + pxh*(BM/2) + m*16 + lr;
                #pragma unroll
                for (int r=0;r<4;++r) {
                    const size_t o = ((size_t)b*128 + c + r)*HW + px;
                    fout[o] = elu_f(acc[f][m][r] + bp[r]) + xres[o];
                }
            }
        }
    }
}

// ---------------------------------------------------------------------------
// qkv bf16 MFMA GEMM: M=160 (padded 192), K=128. Input Ab raw bf16 state.
// Adds pos-enc columns in epilogue; q,k -> (B,HW,16) bf16 (0.25 in q);
// v -> V^T (B,128,HW) bf16.
// ---------------------------------------------------------------------------
__global__ __launch_bounds__(256)
void qkvm(const u16* __restrict__ Wq, const float* __restrict__ qkvw,
          const float* __restrict__ bias, const u16* __restrict__ Ab,
          u16* __restrict__ qo, u16* __restrict__ ko, u16* __restrict__ vo)
{
    __shared__ u16 As[2][64*40];
    __shared__ u16 Bs[2][192*40];
    const int tid = threadIdx.x;
    const int b = blockIdx.z, p0 = blockIdx.x*64;
    const int wv = tid>>6, lane = tid&63, lr = lane&15, lg = lane>>4;
    const int pxh = wv&1, chh = wv>>1;
    const u16* ab = Ab + (size_t)b*HW*128;
    const int arow = tid>>2, ag = tid&3;
    const int apx = p0 + arow;
    int brow[3], bg[3];
    #pragma unroll
    for (int c=0;c<3;++c){ const int ci=tid+c*256; brow[c]=ci>>2; bg[c]=ci&3; }
    uint4 ra, rb[3];
    f32x4 acc[6][2] = {};
    auto GL = [&](int ks){
        const int k0 = ks*32;
        ra = *(const uint4*)(ab + (size_t)apx*128 + k0 + ag*8);
        #pragma unroll
        for (int c=0;c<3;++c)
            rb[c] = *(const uint4*)(Wq + (size_t)brow[c]*128 + k0 + bg[c]*8);
    };
    auto ST = [&](int buf){
        *(uint4*)&As[buf][arow*40 + ag*8] = ra;
        #pragma unroll
        for (int c=0;c<3;++c)
            *(uint4*)&Bs[buf][brow[c]*40 + bg[c]*8] = rb[c];
    };
    GL(0); ST(0); __syncthreads();
    for (int ks=0; ks<4; ++ks) {
        const int cur = ks&1;
        if (ks < 3) GL(ks+1);
        short8v wf[6], pf[2];
        #pragma unroll
        for (int f=0;f<6;++f)
            wf[f] = *(const short8v*)&Bs[cur][(chh*96 + f*16 + lr)*40 + lg*8];
        #pragma unroll
        for (int m=0;m<2;++m)
            pf[m] = *(const short8v*)&As[cur][(pxh*32 + m*16 + lr)*40 + lg*8];
        #pragma unroll
        for (int f=0;f<6;++f)
            #pragma unroll
            for (int m=0;m<2;++m)
                acc[f][m] = __builtin_amdgcn_mfma_f32_16x16x32_bf16(wf[f], pf[m], acc[f][m],0,0,0);
        __syncthreads();
        if (ks < 3) { ST((ks+1)&1); __syncthreads(); }
    }
    #pragma unroll
    for (int f=0; f<6; ++f) {
        const int row0 = chh*96 + f*16;
        if (row0 >= 160) continue;   // padded rows
        #pragma unroll
        for (int m=0;m<2;++m) {
            const int px = p0 + pxh*32 + m*16 + lr;
            const float pyv = (float)(px>>5)*0.03125f - 0.5f;
            const float pxv = (float)(px&31)*0.03125f - 0.5f;
            #pragma unroll
            for (int r=0;r<4;++r) {
                const int mm = row0 + lg*4 + r;
                const float val = acc[f][m][r] + bias[mm]
                                + qkvw[(size_t)mm*130 + 128]*pyv
                                + qkvw[(size_t)mm*130 + 129]*pxv;
                if (mm < 16)      qo[((size_t)b*HW+px)*16 + mm]        = f2bf(0.25f*val);
                else if (mm < 32) ko[((size_t)b*HW+px)*16 + (mm-16)]   = f2bf(val);
                else              vo[((size_t)b*128 + (mm-32))*HW + px] = f2bf(val);
            }
        }
    }
}

// ---------------------------------------------------------------------------
// MFMA causal attention. One wave per 32-query tile. 32x32x16 bf16 MFMAs.
// ---------------------------------------------------------------------------
__global__ __launch_bounds__(64)
void attn_mfma(const u16* __restrict__ qb, const u16* __restrict__ kb,
               const u16* __restrict__ vb, u16* __restrict__ ob)
{
    const int lane = threadIdx.x;
    const int bid  = blockIdx.x;            // 0..1023
    const int qt   = 31 - (bid >> 5);       // long tiles first
    const int b    = bid & 31;
    const int q0   = qt * 32;
    const int lq = lane & 31, hf = lane >> 5;

    const short8v Qf = *(const short8v*)(qb + ((size_t)b*HW + q0 + lq)*16 + hf*8);
    f32x16 acc[4] = {{},{},{},{}};
    float mrun = -1e30f, lrun = 0.f;

    unsigned diagm = 0;
    #pragma unroll
    for (int r=0; r<16; ++r) {
        const int row = (r&3) + 8*(r>>2) + 4*hf;
        diagm |= (row <= lq) ? (1u<<r) : 0u;
    }
    const f32x16 zc = {};
    for (int c = 0; c <= qt; ++c) {
        const int kv0 = c*32;
        const short8v Kf = *(const short8v*)(kb + ((size_t)b*HW + kv0 + lq)*16 + hf*8);
        f32x16 st = __builtin_amdgcn_mfma_f32_32x32x16_bf16(Kf, Qf, zc, 0,0,0);
        if (c == qt) {
            #pragma unroll
            for (int r=0; r<16; ++r)
                st[r] = ((diagm>>r)&1) ? st[r] : -1e30f;
        }
        float mc = st[0];
        #pragma unroll
        for (int r=1; r<16; ++r) mc = fmaxf(mc, st[r]);
        mc = fmaxf(mc, __shfl_xor(mc, 32));
        if (!__all(mc <= mrun)) {
            const float mnew = fmaxf(mrun, mc);
            const float corr = __expf(mrun - mnew);
            lrun *= corr;
            #pragma unroll
            for (int f=0; f<4; ++f)
                #pragma unroll
                for (int r=0; r<16; ++r) acc[f][r] *= corr;
            mrun = mnew;
        }
        float ps[16]; float lsum = 0.f;
        #pragma unroll
        for (int r=0; r<16; ++r) { ps[r] = __expf(st[r] - mrun); lsum += ps[r]; }
        lrun += lsum + __shfl_xor(lsum, 32);
        unsigned pk[8], sw[8];
        #pragma unroll
        for (int i=0; i<8; ++i)
            pk[i] = (unsigned)f2bf(ps[2*i]) | ((unsigned)f2bf(ps[2*i+1])<<16);
        #pragma unroll
        for (int i=0; i<8; ++i) sw[i] = __shfl_xor(pk[i], 32);
        union { unsigned u[4]; short8v v; } B1, B2;
        B1.u[0] = hf ? sw[2] : pk[0];  B1.u[1] = hf ? sw[3] : pk[1];
        B1.u[2] = hf ? pk[2] : sw[0];  B1.u[3] = hf ? pk[3] : sw[1];
        B2.u[0] = hf ? sw[6] : pk[4];  B2.u[1] = hf ? sw[7] : pk[5];
        B2.u[2] = hf ? pk[6] : sw[4];  B2.u[3] = hf ? pk[7] : sw[5];
        #pragma unroll
        for (int f=0; f<4; ++f) {
            const u16* vr = vb + ((size_t)b*128 + f*32 + lq)*HW + kv0 + hf*8;
            const short8v A1 = *(const short8v*)(vr);
            const short8v A2 = *(const short8v*)(vr + 16);
            acc[f] = __builtin_amdgcn_mfma_f32_32x32x16_bf16(A1, B1.v, acc[f], 0,0,0);
            acc[f] = __builtin_amdgcn_mfma_f32_32x32x16_bf16(A2, B2.v, acc[f], 0,0,0);
        }
    }
    const float inv = 1.f / lrun;
    u16* orow = ob + ((size_t)b*HW + q0 + lq)*128;
    #pragma unroll
    for (int f=0; f<4; ++f) {
        #pragma unroll
        for (int g=0; g<4; ++g) {
            const int d0 = f*32 + 8*g + 4*hf;
            ushort4 o4;
            o4.x = f2bf(acc[f][g*4+0]*inv);
            o4.y = f2bf(acc[f][g*4+1]*inv);
            o4.z = f2bf(acc[f][g*4+2]*inv);
            o4.w = f2bf(acc[f][g*4+3]*inv);
            *(ushort4*)(orow + d0) = o4;
        }
    }
}

extern "C" void kernel_launch(void* const* d_in, const int* in_sizes, int n_in,
                              void* d_out, int out_size, void* d_ws, size_t ws_size,
                              hipStream_t stream) {
    const float* x    = (const float*)d_in[0];
    const float* rw1  = (const float*)d_in[1];
    const float* rb1  = (const float*)d_in[2];
    const float* rw2  = (const float*)d_in[3];
    const float* rb2  = (const float*)d_in[4];
    const float* qkvw = (const float*)d_in[5];
    const float* qkvb = (const float*)d_in[6];
    const float* apw  = (const float*)d_in[7];
    const float* apb  = (const float*)d_in[8];
    const float* ocw  = (const float*)d_in[9];
    const float* ocb  = (const float*)d_in[10];
    const float* oaw  = (const float*)d_in[11];
    const float* oab  = (const float*)d_in[12];
    const float* opw  = (const float*)d_in[13];
    const float* opb  = (const float*)d_in[14];
    float* out = (float*)d_out;
    float* ws = (float*)d_ws;

    // Workspace (float offsets, 16M floats = 64 MiB):
    float* A  = ws;                                  // [0,4M)      (B,HW,128) f32 state
    u16* Eb   = (u16*)(ws + 4194304);                // [4M,6M)     bf16(elu(state))
    u16* E2   = (u16*)(ws + 6291456);                // [6M,8M)     conv1 out; later Ea
    u16* Ab   = (u16*)(ws + 8388608);                // [8M,10M)    raw bf16 state (layer 5)
    u16* qb   = (u16*)(ws + 10485760);               // [10M,10.25M)
    u16* kb   = (u16*)(ws + 10747904);               // [10.25M,10.5M)
    u16* vb   = (u16*)(ws + 11010048);               // [10.5M,12.5M)  V^T; later c1p
    u16* ob   = (u16*)(ws + 13107200);               // [12.5M,14.5M)  attn out; later Es
    u16* w1b  = (u16*)(ws + 15204352);               // 6*128*512 u16
    u16* w2b  = (u16*)(ws + 15400960);               // 6*256*512 u16
    u16* wh   = (u16*)(ws + 15794176);               // 4*128*128 u16 (ap, oc, oa, op)
    u16* qw   = (u16*)(ws + 15826944);               // 192*128 u16
    u16* Ea   = E2;
    u16* c1p  = vb;
    u16* Es   = ob;

    dim3 blk(256);
    wc2_k<<<1536, blk, 0, stream>>>(rw1, w1b, 6*128*512);
    wc2_k<<<3072, blk, 0, stream>>>(rw2, w2b, 6*256*512);
    wc1_k<<<256,  blk, 0, stream>>>(apw, ocw, oaw, opw, wh);
    wcq_k<<<96,   blk, 0, stream>>>(qkvw, qw);
    init_k<<<dim3(32, 32), blk, 0, stream>>>(x, A, Eb);
    for (int i = 0; i < 6; ++i) {
        convt<64,4,0,false><<<dim3(16,1,32), blk, 0, stream>>>(
            w1b + (size_t)i*65536, rb1 + i*128, Eb, E2,
            nullptr, nullptr, nullptr, nullptr, nullptr);
        if (i < 5)
            convt<128,4,1,false><<<dim3(8,2,32), blk, 0, stream>>>(
                w2b + (size_t)i*131072, rb2 + i*256, E2, Eb,
                A, nullptr, nullptr, nullptr, nullptr);
        else
            convt<128,4,1,true><<<dim3(8,2,32), blk, 0, stream>>>(
                w2b + (size_t)i*131072, rb2 + i*256, E2, Eb,
                A, nullptr, Ab, nullptr, nullptr);
    }
    qkvm<<<dim3(16,1,32), blk, 0, stream>>>(qw, qkvw, qkvb, Ab, qb, kb, vb);
    attn_mfma<<<1024, dim3(64), 0, stream>>>(qb, kb, vb, ob);
    // attn_proj -> Ea = bf16(elu(attn_out))
    convt<64,1,0,false><<<dim3(16,1,32), blk, 0, stream>>>(
        wh, apb, ob, Ea, nullptr, nullptr, nullptr, nullptr, nullptr);
    // out_conv -> c1p = bf16(elu(c1))
    convt<64,1,0,false><<<dim3(16,1,32), blk, 0, stream>>>(
        wh + 16384, ocb, Eb, c1p, nullptr, nullptr, nullptr, nullptr, nullptr);
    // out_attn + add c1 -> Es = bf16(elu(c1+a1))
    convt<64,1,2,false><<<dim3(16,1,32), blk, 0, stream>>>(
        wh + 32768, oab, Ea, Es, nullptr, c1p, nullptr, nullptr, nullptr);
    // out_proj -> y = elu(.)+x, channel-major f32
    convt<64,1,3,false><<<dim3(16,1,32), blk, 0, stream>>>(
        wh + 49152, opb, Es, nullptr, nullptr, nullptr, nullptr, x, out);
}

// Round 6
// 470.130 us; speedup vs baseline: 1.1895x; 1.0458x over previous
//
#include <hip/hip_runtime.h>
#include <math.h>

#define HW 1024
typedef unsigned short u16;
typedef __attribute__((ext_vector_type(8))) short short8v;   // 8 bf16
typedef __attribute__((ext_vector_type(4))) float f32x4;
typedef __attribute__((ext_vector_type(16))) float f32x16;

__device__ __forceinline__ float elu_f(float x){ return x>0.f? x : (__expf(x)-1.f); }
__device__ __forceinline__ float sig_f(float x){ return 1.f/(1.f+__expf(-x)); }
__device__ __forceinline__ u16 f2bf(float f){ unsigned u=__float_as_uint(f); return (u16)((u + 0x7fffu + ((u>>16)&1u))>>16); }
__device__ __forceinline__ float bf2f(u16 h){ return __uint_as_float(((unsigned)h)<<16); }

// ---------------------------------------------------------------------------
// One-time weight converts
// ---------------------------------------------------------------------------
__global__ __launch_bounds__(256)
void wc2_k(const float* __restrict__ rw, u16* __restrict__ wb, int total)
{
    int i = blockIdx.x*256 + threadIdx.x;
    if (i >= total) return;
    int kp = i & 511, row = i >> 9;
    int tap = kp >> 7, c = kp & 127;
    wb[i] = f2bf(rw[(size_t)row*512 + c*4 + tap]);   // k' = tap*128 + c
}
__global__ __launch_bounds__(256)
void wc1_k(const float* __restrict__ w0, const float* __restrict__ w1,
           const float* __restrict__ w2, const float* __restrict__ w3, u16* __restrict__ wb)
{
    int i = blockIdx.x*256 + threadIdx.x;   // 0..65535
    const float* src = (i<16384)? w0 : (i<32768)? w1 : (i<49152)? w2 : w3;
    wb[i] = f2bf(src[i & 16383]);
}
__global__ __launch_bounds__(256)
void wcq_k(const float* __restrict__ qkvw, u16* __restrict__ qw)
{
    int i = blockIdx.x*256 + threadIdx.x;   // 192*128 = 24576
    if (i >= 24576) return;
    int r = i >> 7, c = i & 127;
    qw[i] = (r < 160) ? f2bf(qkvw[(size_t)r*130 + c]) : (u16)0;
}

// ---------------------------------------------------------------------------
// init: x (B,128,HW) f32 -> A (B,HW,128) f32 pixel-major + Eb bf16(elu(x))
// ---------------------------------------------------------------------------
__global__ __launch_bounds__(256)
void init_k(const float* __restrict__ x, float* __restrict__ A, u16* __restrict__ Eb)
{
    __shared__ float t[32][132];
    const int b = blockIdx.y, p0 = blockIdx.x*32;
    const int tid = threadIdx.x;
    const int cr = tid >> 3, p4 = (tid & 7)*4;
    #pragma unroll
    for (int cc = 0; cc < 128; cc += 32) {
        const float4 v = *(const float4*)(x + ((size_t)b*128 + cc + cr)*HW + p0 + p4);
        t[p4+0][cc+cr]=v.x; t[p4+1][cc+cr]=v.y; t[p4+2][cc+cr]=v.z; t[p4+3][cc+cr]=v.w;
    }
    __syncthreads();
    const int pr = tid >> 3, c4 = (tid & 7)*4;
    #pragma unroll
    for (int cc = 0; cc < 128; cc += 32) {
        const int c = cc + c4;
        float4 v; v.x=t[pr][c]; v.y=t[pr][c+1]; v.z=t[pr][c+2]; v.w=t[pr][c+3];
        *(float4*)(A + ((size_t)b*HW + p0 + pr)*128 + c) = v;
        ushort4 e;
        e.x=f2bf(elu_f(v.x)); e.y=f2bf(elu_f(v.y)); e.z=f2bf(elu_f(v.z)); e.w=f2bf(elu_f(v.w));
        *(ushort4*)(Eb + ((size_t)b*HW + p0 + pr)*128 + c) = e;
    }
}

// ---------------------------------------------------------------------------
// LDS-staged MFMA conv GEMM (2x2 im2col tap-major or 1x1).
// Phase-paired dbuf loop: ONE barrier per k-step, two register staging sets
// so each global load has ~a full step before its ds_write consumes it.
// ---------------------------------------------------------------------------
#define CGLOAD(ks, RA, RB) do {                                                \
    const int k0_ = (ks)*32;                                                   \
    const int tap_ = (TAPS==4)? (k0_>>7) : 0;                                  \
    const int c0_  = (TAPS==4)? (k0_&127) : k0_;                               \
    _Pragma("unroll")                                                          \
    for (int c=0;c<NCA;++c) {                                                  \
        const bool ok_ = (aok[c]>>tap_)&1;                                     \
        const int prd_ = (TAPS==4 && ok_) ? OFF[tap_] : 0;                     \
        uint4 v_ = *(const uint4*)(eb + (size_t)(apx[c]+prd_)*128 + c0_ + ag[c]*8); \
        if (!ok_) { v_.x=0u; v_.y=0u; v_.z=0u; v_.w=0u; }                      \
        RA[c] = v_;                                                            \
    }                                                                          \
    _Pragma("unroll")                                                          \
    for (int c=0;c<2;++c) RB[c] = *(const uint4*)(wsrc[c] + k0_);              \
} while(0)

#define CSTORE(buf, RA, RB) do {                                               \
    _Pragma("unroll")                                                          \
    for (int c=0;c<NCA;++c) *(uint4*)&As[buf][arow[c]*40 + ag[c]*8] = RA[c];   \
    _Pragma("unroll")                                                          \
    for (int c=0;c<2;++c)   *(uint4*)&Bs[buf][brow[c]*40 + bgp[c]*8] = RB[c];  \
} while(0)

#define CCOMPUTE(buf) do {                                                     \
    short8v wf[4], pf[MA];                                                     \
    _Pragma("unroll")                                                          \
    for (int f=0; f<4; ++f)                                                    \
        wf[f] = *(const short8v*)&Bs[buf][(chh*64 + f*16 + lr)*40 + lg*8];     \
    _Pragma("unroll")                                                          \
    for (int m=0; m<MA; ++m)                                                   \
        pf[m] = *(const short8v*)&As[buf][(pxh*(BM/2) + m*16 + lr)*40 + lg*8]; \
    _Pragma("unroll")                                                          \
    for (int f=0; f<4; ++f)                                                    \
        _Pragma("unroll")                                                      \
        for (int m=0; m<MA; ++m)                                               \
            acc[f][m] = __builtin_amdgcn_mfma_f32_16x16x32_bf16(wf[f], pf[m], acc[f][m],0,0,0); \
} while(0)

template<int BM, int TAPS, int EPI, bool RAW>
__global__ __launch_bounds__(256)
void convt(const u16* __restrict__ Wb, const float* __restrict__ bias,
           const u16* __restrict__ Ein, u16* __restrict__ out0,
           float* __restrict__ Aio, const u16* __restrict__ aux,
           u16* __restrict__ raw0, const float* __restrict__ xres,
           float* __restrict__ fout)
{
    constexpr int K  = TAPS*128;
    constexpr int NS = K/32;           // even (16 or 4)
    constexpr int MA = BM/32;
    constexpr int NCA = BM/64;
    __shared__ u16 As[2][BM*40];
    __shared__ u16 Bs[2][128*40];
    const int tid = threadIdx.x;
    const int b = blockIdx.z, p0 = blockIdx.x*BM, cb0 = blockIdx.y*64;
    const int wv = tid>>6, lane = tid&63, lr = lane&15, lg = lane>>4;
    const int pxh = wv&1, chh = wv>>1;
    const u16* eb = Ein + (size_t)b*HW*128;

    int apx[NCA], ag[NCA], arow[NCA]; unsigned aok[NCA];
    #pragma unroll
    for (int c=0;c<NCA;++c) {
        const int ci = tid + c*256;
        arow[c] = ci>>2; ag[c] = ci&3;
        apx[c] = p0 + arow[c];
        if (TAPS==1) aok[c] = 0xF;
        else {
            const int py_=apx[c]>>5, px_=apx[c]&31;
            aok[c] = 8u | ((py_>0&&px_>0)?1u:0u) | ((py_>0)?2u:0u) | ((px_>0)?4u:0u);
        }
    }
    const u16* wsrc[2]; int brow[2], bgp[2];
    #pragma unroll
    for (int c=0;c<2;++c) {
        const int ci = tid + c*256;
        const int row = ci>>2, g = ci&3;
        brow[c]=row; bgp[c]=g;
        int ch;
        if (EPI==1) {
            const int h=row>>6, f=(row>>4)&3, r=row&15;
            ch = (f<2) ? (cb0 + h*32 + f*16 + r) : (128 + cb0 + h*32 + (f-2)*16 + r);
        } else ch = row;
        wsrc[c] = Wb + (size_t)ch*K + g*8;
    }
    const int OFF[4] = {-33,-32,-1,0};

    uint4 raA[NCA], rbA[2], raB[NCA], rbB[2];
    f32x4 acc[4][MA] = {};

    CGLOAD(0, raA, rbA); CSTORE(0, raA, rbA);
    if (NS > 1) CGLOAD(1, raB, rbB);
    __syncthreads();
    for (int s = 0; s < NS; s += 2) {
        CCOMPUTE(0);
        if (s+1 < NS) CSTORE(1, raB, rbB);
        if (s+2 < NS) CGLOAD(s+2, raA, rbA);
        __syncthreads();
        if (s+1 >= NS) break;
        CCOMPUTE(1);
        if (s+2 < NS) CSTORE(0, raA, rbA);
        if (s+3 < NS) CGLOAD(s+3, raB, rbB);
        __syncthreads();
    }

    // ---- epilogues: D lane -> px = ...+lr (col), ch = frag-row lg*4+r ----
    if constexpr (EPI == 1) {
        #pragma unroll
        for (int f=0; f<2; ++f) {
            const int c = cb0 + chh*32 + f*16 + lg*4;
            const float4 b1 = *(const float4*)(bias + c);
            const float4 b2 = *(const float4*)(bias + 128 + c);
            #pragma unroll
            for (int m=0;m<MA;++m) {
                const int px = p0 + pxh*(BM/2) + m*16 + lr;
                float* ap = Aio + ((size_t)b*HW+px)*128 + c;
                const float4 pv = *(const float4*)ap;
                const float o0 = pv.x + (acc[f][m][0]+b1.x)*sig_f(acc[f+2][m][0]+b2.x);
                const float o1 = pv.y + (acc[f][m][1]+b1.y)*sig_f(acc[f+2][m][1]+b2.y);
                const float o2 = pv.z + (acc[f][m][2]+b1.z)*sig_f(acc[f+2][m][2]+b2.z);
                const float o3 = pv.w + (acc[f][m][3]+b1.w)*sig_f(acc[f+2][m][3]+b2.w);
                float4 ov; ov.x=o0; ov.y=o1; ov.z=o2; ov.w=o3;
                *(float4*)ap = ov;
                ushort4 e;
                e.x=f2bf(elu_f(o0)); e.y=f2bf(elu_f(o1)); e.z=f2bf(elu_f(o2)); e.w=f2bf(elu_f(o3));
                *(ushort4*)(out0 + ((size_t)b*HW+px)*128 + c) = e;
                if constexpr (RAW) {
                    ushort4 rr;
                    rr.x=f2bf(o0); rr.y=f2bf(o1); rr.z=f2bf(o2); rr.w=f2bf(o3);
                    *(ushort4*)(raw0 + ((size_t)b*HW+px)*128 + c) = rr;
                }
            }
        }
    } else if constexpr (EPI == 0 || EPI == 2) {
        #pragma unroll
        for (int f=0; f<4; ++f) {
            const int c = chh*64 + f*16 + lg*4;
            const float4 bb = *(const float4*)(bias + c);
            #pragma unroll
            for (int m=0;m<MA;++m) {
                const int px = p0 + pxh*(BM/2) + m*16 + lr;
                const float v0=acc[f][m][0]+bb.x, v1=acc[f][m][1]+bb.y;
                const float v2=acc[f][m][2]+bb.z, v3=acc[f][m][3]+bb.w;
                ushort4 e;
                if constexpr (EPI == 2) {
                    const ushort4 c4 = *(const ushort4*)(aux + ((size_t)b*HW+px)*128 + c);
                    e.x = f2bf(elu_f(elu_f(v0) + bf2f(c4.x)));
                    e.y = f2bf(elu_f(elu_f(v1) + bf2f(c4.y)));
                    e.z = f2bf(elu_f(elu_f(v2) + bf2f(c4.z)));
                    e.w = f2bf(elu_f(elu_f(v3) + bf2f(c4.w)));
                } else {
                    e.x=f2bf(elu_f(v0)); e.y=f2bf(elu_f(v1));
                    e.z=f2bf(elu_f(v2)); e.w=f2bf(elu_f(v3));
                }
                *(ushort4*)(out0 + ((size_t)b*HW+px)*128 + c) = e;
            }
        }
    } else {   // EPI 3: channel-major f32 out + residual
        #pragma unroll
        for (int f=0; f<4; ++f) {
            const int c = chh*64 + f*16 + lg*4;
            const float* bp = bias + c;
            #pragma unroll
            for (int m=0;m<MA;++m) {
                const int px = p0 + pxh*(BM/2) + m*16 + lr;
                #pragma unroll
                for (int r=0;r<4;++r) {
                    const size_t o = ((size_t)b*128 + c + r)*HW + px;
                    fout[o] = elu_f(acc[f][m][r] + bp[r]) + xres[o];
                }
            }
        }
    }
}

// ---------------------------------------------------------------------------
// qkv bf16 MFMA GEMM: M=160 (padded 192), K=128.
// ---------------------------------------------------------------------------
__global__ __launch_bounds__(256)
void qkvm(const u16* __restrict__ Wq, const float* __restrict__ qkvw,
          const float* __restrict__ bias, const u16* __restrict__ Ab,
          u16* __restrict__ qo, u16* __restrict__ ko, u16* __restrict__ vo)
{
    __shared__ u16 As[2][64*40];
    __shared__ u16 Bs[2][192*40];
    const int tid = threadIdx.x;
    const int b = blockIdx.z, p0 = blockIdx.x*64;
    const int wv = tid>>6, lane = tid&63, lr = lane&15, lg = lane>>4;
    const int pxh = wv&1, chh = wv>>1;
    const u16* ab = Ab + (size_t)b*HW*128;
    const int arow = tid>>2, ag = tid&3;
    const int apx = p0 + arow;
    int brow[3], bg[3];
    #pragma unroll
    for (int c=0;c<3;++c){ const int ci=tid+c*256; brow[c]=ci>>2; bg[c]=ci&3; }
    uint4 ra, rb[3];
    f32x4 acc[6][2] = {};
    auto GL = [&](int ks){
        const int k0 = ks*32;
        ra = *(const uint4*)(ab + (size_t)apx*128 + k0 + ag*8);
        #pragma unroll
        for (int c=0;c<3;++c)
            rb[c] = *(const uint4*)(Wq + (size_t)brow[c]*128 + k0 + bg[c]*8);
    };
    auto ST = [&](int buf){
        *(uint4*)&As[buf][arow*40 + ag*8] = ra;
        #pragma unroll
        for (int c=0;c<3;++c)
            *(uint4*)&Bs[buf][brow[c]*40 + bg[c]*8] = rb[c];
    };
    GL(0); ST(0); __syncthreads();
    for (int ks=0; ks<4; ++ks) {
        const int cur = ks&1;
        if (ks < 3) GL(ks+1);
        short8v wf[6], pf[2];
        #pragma unroll
        for (int f=0;f<6;++f)
            wf[f] = *(const short8v*)&Bs[cur][(chh*96 + f*16 + lr)*40 + lg*8];
        #pragma unroll
        for (int m=0;m<2;++m)
            pf[m] = *(const short8v*)&As[cur][(pxh*32 + m*16 + lr)*40 + lg*8];
        #pragma unroll
        for (int f=0;f<6;++f)
            #pragma unroll
            for (int m=0;m<2;++m)
                acc[f][m] = __builtin_amdgcn_mfma_f32_16x16x32_bf16(wf[f], pf[m], acc[f][m],0,0,0);
        __syncthreads();
        if (ks < 3) { ST((ks+1)&1); __syncthreads(); }
    }
    #pragma unroll
    for (int f=0; f<6; ++f) {
        const int row0 = chh*96 + f*16;
        if (row0 >= 160) continue;
        #pragma unroll
        for (int m=0;m<2;++m) {
            const int px = p0 + pxh*32 + m*16 + lr;
            const float pyv = (float)(px>>5)*0.03125f - 0.5f;
            const float pxv = (float)(px&31)*0.03125f - 0.5f;
            #pragma unroll
            for (int r=0;r<4;++r) {
                const int mm = row0 + lg*4 + r;
                const float val = acc[f][m][r] + bias[mm]
                                + qkvw[(size_t)mm*130 + 128]*pyv
                                + qkvw[(size_t)mm*130 + 129]*pxv;
                if (mm < 16)      qo[((size_t)b*HW+px)*16 + mm]        = f2bf(0.25f*val);
                else if (mm < 32) ko[((size_t)b*HW+px)*16 + (mm-16)]   = f2bf(val);
                else              vo[((size_t)b*128 + (mm-32))*HW + px] = f2bf(val);
            }
        }
    }
}

// ---------------------------------------------------------------------------
// MFMA causal attention, multi-wave: block = 256 thr = 4 waves =
// 2 q-tiles (2t, 2t+1) x 2 d-halves; K/V chunks dbuf-staged in LDS.
// q,k (B,HW,16) bf16 (0.25 in q); v = V^T (B,128,HW) bf16; o (B,HW,128) bf16.
// ---------------------------------------------------------------------------
__global__ __launch_bounds__(256)
void attn_mfma(const u16* __restrict__ qb, const u16* __restrict__ kb,
               const u16* __restrict__ vb, u16* __restrict__ ob)
{
    __shared__ u16 ks_[2][32*24];    // [key][16d], rows padded to 24 u16 (48B)
    __shared__ u16 vs_[2][128*40];   // [d][32k],  rows padded to 40 u16 (80B)
    const int tid = threadIdx.x;
    const int bid = blockIdx.x;              // 0..511
    const int tp  = 15 - (bid >> 5);         // tile-pair, long first
    const int b   = bid & 31;
    const int wv = tid>>6, lane = tid&63;
    const int lq = lane&31, hf = lane>>5;
    const int qt = tp*2 + (wv&1);            // this wave's q-tile
    const int dh = wv>>1;                    // d half (0: d0-63, 1: d64-127)
    const int q0 = qt*32;
    const int NC = tp*2 + 2;                 // chunks processed by this block (even)

    const short8v Qf = *(const short8v*)(qb + ((size_t)b*HW + q0 + lq)*16 + hf*8);
    f32x16 acc[2] = {{},{}};
    float mrun = -1e30f, lrun = 0.f;
    unsigned diagm = 0;
    #pragma unroll
    for (int r=0; r<16; ++r) {
        const int row = (r&3) + 8*(r>>2) + 4*hf;
        diagm |= (row <= lq) ? (1u<<r) : 0u;
    }
    const f32x16 zc = {};

    const int vrow = tid>>2, vg = tid&3;     // V staging: 64 rows/pass x 4 chunks
    const int krow = tid>>1, kg = tid&1;     // K staging: tid<64
    const u16* vbb = vb + (size_t)b*128*HW;
    const u16* kbb = kb + (size_t)b*HW*16;
    uint4 rv0A, rv1A, rkA, rv0B, rv1B, rkB;

#define AGLD(c, RV0, RV1, RK) do {                                             \
    const int kv0_ = (c)*32;                                                   \
    RV0 = *(const uint4*)(vbb + (size_t)vrow*HW + kv0_ + vg*8);                \
    RV1 = *(const uint4*)(vbb + (size_t)(64+vrow)*HW + kv0_ + vg*8);           \
    if (tid < 64) RK = *(const uint4*)(kbb + (size_t)(kv0_ + krow)*16 + kg*8); \
} while(0)
#define ASST(buf, RV0, RV1, RK) do {                                           \
    *(uint4*)&vs_[buf][vrow*40 + vg*8] = RV0;                                  \
    *(uint4*)&vs_[buf][(64+vrow)*40 + vg*8] = RV1;                             \
    if (tid < 64) *(uint4*)&ks_[buf][krow*24 + kg*8] = RK;                     \
} while(0)

    auto CHUNK = [&](int buf, int cc) {
        if (cc > qt) return;                 // wave-uniform branch
        const short8v Kf = *(const short8v*)&ks_[buf][lq*24 + hf*8];
        f32x16 st = __builtin_amdgcn_mfma_f32_32x32x16_bf16(Kf, Qf, zc, 0,0,0);
        if (cc == qt) {
            #pragma unroll
            for (int r=0;r<16;++r) st[r] = ((diagm>>r)&1) ? st[r] : -1e30f;
        }
        float mc = st[0];
        #pragma unroll
        for (int r=1;r<16;++r) mc = fmaxf(mc, st[r]);
        mc = fmaxf(mc, __shfl_xor(mc, 32));
        if (!__all(mc <= mrun)) {
            const float mnew = fmaxf(mrun, mc);
            const float corr = __expf(mrun - mnew);
            lrun *= corr;
            #pragma unroll
            for (int f=0;f<2;++f)
                #pragma unroll
                for (int r=0;r<16;++r) acc[f][r] *= corr;
            mrun = mnew;
        }
        float ps[16]; float lsum = 0.f;
        #pragma unroll
        for (int r=0;r<16;++r){ ps[r]=__expf(st[r]-mrun); lsum += ps[r]; }
        lrun += lsum + __shfl_xor(lsum, 32);
        unsigned pk[8], sw[8];
        #pragma unroll
        for (int i=0;i<8;++i)
            pk[i] = (unsigned)f2bf(ps[2*i]) | ((unsigned)f2bf(ps[2*i+1])<<16);
        #pragma unroll
        for (int i=0;i<8;++i) sw[i] = __shfl_xor(pk[i], 32);
        union { unsigned u[4]; short8v v; } B1, B2;
        B1.u[0]=hf?sw[2]:pk[0]; B1.u[1]=hf?sw[3]:pk[1];
        B1.u[2]=hf?pk[2]:sw[0]; B1.u[3]=hf?pk[3]:sw[1];
        B2.u[0]=hf?sw[6]:pk[4]; B2.u[1]=hf?sw[7]:pk[5];
        B2.u[2]=hf?pk[6]:sw[4]; B2.u[3]=hf?pk[7]:sw[5];
        #pragma unroll
        for (int f=0;f<2;++f) {
            const int fg = dh*2 + f;
            const short8v A1 = *(const short8v*)&vs_[buf][(fg*32+lq)*40 + hf*8];
            const short8v A2 = *(const short8v*)&vs_[buf][(fg*32+lq)*40 + 16 + hf*8];
            acc[f] = __builtin_amdgcn_mfma_f32_32x32x16_bf16(A1, B1.v, acc[f],0,0,0);
            acc[f] = __builtin_amdgcn_mfma_f32_32x32x16_bf16(A2, B2.v, acc[f],0,0,0);
        }
    };

    AGLD(0, rv0A, rv1A, rkA); ASST(0, rv0A, rv1A, rkA);
    AGLD(1, rv0B, rv1B, rkB);
    __syncthreads();
    for (int c = 0; c < NC; c += 2) {
        CHUNK(0, c);
        ASST(1, rv0B, rv1B, rkB);
        if (c+2 < NC) AGLD(c+2, rv0A, rv1A, rkA);
        __syncthreads();
        CHUNK(1, c+1);
        if (c+2 < NC) {
            ASST(0, rv0A, rv1A, rkA);
            if (c+3 < NC) AGLD(c+3, rv0B, rv1B, rkB);
        }
        __syncthreads();
    }
#undef AGLD
#undef ASST

    const float inv = 1.f / lrun;
    u16* orow = ob + ((size_t)b*HW + q0 + lq)*128;
    #pragma unroll
    for (int f=0; f<2; ++f) {
        #pragma unroll
        for (int g=0; g<4; ++g) {
            const int d0 = (dh*2+f)*32 + 8*g + 4*hf;
            ushort4 o4;
            o4.x = f2bf(acc[f][g*4+0]*inv);
            o4.y = f2bf(acc[f][g*4+1]*inv);
            o4.z = f2bf(acc[f][g*4+2]*inv);
            o4.w = f2bf(acc[f][g*4+3]*inv);
            *(ushort4*)(orow + d0) = o4;
        }
    }
}

extern "C" void kernel_launch(void* const* d_in, const int* in_sizes, int n_in,
                              void* d_out, int out_size, void* d_ws, size_t ws_size,
                              hipStream_t stream) {
    const float* x    = (const float*)d_in[0];
    const float* rw1  = (const float*)d_in[1];
    const float* rb1  = (const float*)d_in[2];
    const float* rw2  = (const float*)d_in[3];
    const float* rb2  = (const float*)d_in[4];
    const float* qkvw = (const float*)d_in[5];
    const float* qkvb = (const float*)d_in[6];
    const float* apw  = (const float*)d_in[7];
    const float* apb  = (const float*)d_in[8];
    const float* ocw  = (const float*)d_in[9];
    const float* ocb  = (const float*)d_in[10];
    const float* oaw  = (const float*)d_in[11];
    const float* oab  = (const float*)d_in[12];
    const float* opw  = (const float*)d_in[13];
    const float* opb  = (const float*)d_in[14];
    float* out = (float*)d_out;
    float* ws = (float*)d_ws;

    // Workspace (float offsets, 16M floats = 64 MiB):
    float* A  = ws;                                  // [0,4M)      (B,HW,128) f32 state
    u16* Eb   = (u16*)(ws + 4194304);                // [4M,6M)     bf16(elu(state))
    u16* E2   = (u16*)(ws + 6291456);                // [6M,8M)     conv1 out; later Ea
    u16* Ab   = (u16*)(ws + 8388608);                // [8M,10M)    raw bf16 state (layer 5)
    u16* qb   = (u16*)(ws + 10485760);               // [10M,10.25M)
    u16* kb   = (u16*)(ws + 10747904);               // [10.25M,10.5M)
    u16* vb   = (u16*)(ws + 11010048);               // [10.5M,12.5M)  V^T; later c1p
    u16* ob   = (u16*)(ws + 13107200);               // [12.5M,14.5M)  attn out; later Es
    u16* w1b  = (u16*)(ws + 15204352);               // 6*128*512 u16
    u16* w2b  = (u16*)(ws + 15400960);               // 6*256*512 u16
    u16* wh   = (u16*)(ws + 15794176);               // 4*128*128 u16 (ap, oc, oa, op)
    u16* qw   = (u16*)(ws + 15826944);               // 192*128 u16
    u16* Ea   = E2;
    u16* c1p  = vb;
    u16* Es   = ob;

    dim3 blk(256);
    wc2_k<<<1536, blk, 0, stream>>>(rw1, w1b, 6*128*512);
    wc2_k<<<3072, blk, 0, stream>>>(rw2, w2b, 6*256*512);
    wc1_k<<<256,  blk, 0, stream>>>(apw, ocw, oaw, opw, wh);
    wcq_k<<<96,   blk, 0, stream>>>(qkvw, qw);
    init_k<<<dim3(32, 32), blk, 0, stream>>>(x, A, Eb);
    for (int i = 0; i < 6; ++i) {
        convt<64,4,0,false><<<dim3(16,1,32), blk, 0, stream>>>(
            w1b + (size_t)i*65536, rb1 + i*128, Eb, E2,
            nullptr, nullptr, nullptr, nullptr, nullptr);
        if (i < 5)
            convt<128,4,1,false><<<dim3(8,2,32), blk, 0, stream>>>(
                w2b + (size_t)i*131072, rb2 + i*256, E2, Eb,
                A, nullptr, nullptr, nullptr, nullptr);
        else
            convt<128,4,1,true><<<dim3(8,2,32), blk, 0, stream>>>(
                w2b + (size_t)i*131072, rb2 + i*256, E2, Eb,
                A, nullptr, Ab, nullptr, nullptr);
    }
    qkvm<<<dim3(16,1,32), blk, 0, stream>>>(qw, qkvw, qkvb, Ab, qb, kb, vb);
    attn_mfma<<<512, blk, 0, stream>>>(qb, kb, vb, ob);
    // attn_proj -> Ea = bf16(elu(attn_out))
    convt<64,1,0,false><<<dim3(16,1,32), blk, 0, stream>>>(
        wh, apb, ob, Ea, nullptr, nullptr, nullptr, nullptr, nullptr);
    // out_conv -> c1p = bf16(elu(c1))
    convt<64,1,0,false><<<dim3(16,1,32), blk, 0, stream>>>(
        wh + 16384, ocb, Eb, c1p, nullptr, nullptr, nullptr, nullptr, nullptr);
    // out_attn + add c1 -> Es = bf16(elu(c1+a1))
    convt<64,1,2,false><<<dim3(16,1,32), blk, 0, stream>>>(
        wh + 32768, oab, Ea, Es, nullptr, c1p, nullptr, nullptr, nullptr);
    // out_proj -> y = elu(.)+x, channel-major f32
    convt<64,1,3,false><<<dim3(16,1,32), blk, 0, stream>>>(
        wh + 49152, opb, Es, nullptr, nullptr, nullptr, nullptr, x, out);
}

// Round 7
// 303.416 us; speedup vs baseline: 1.8431x; 1.5495x over previous
//
#include <hip/hip_runtime.h>
#include <math.h>

#define HW 1024
#define RS 33            // padded row stride (32 px + 1 zero col)
#define GP 34            // zero guard pixels before each image
#define PB 1120          // padded pixels per batch image (>= 34+33*31+31+1)

typedef unsigned short u16;
typedef __attribute__((ext_vector_type(8))) short short8v;   // 8 bf16
typedef __attribute__((ext_vector_type(4))) float f32x4;
typedef __attribute__((ext_vector_type(16))) float f32x16;

__device__ __forceinline__ float elu_f(float x){ return x>0.f? x : (__expf(x)-1.f); }
__device__ __forceinline__ float sig_f(float x){ return 1.f/(1.f+__expf(-x)); }
__device__ __forceinline__ u16 f2bf(float f){ unsigned u=__float_as_uint(f); return (u16)((u + 0x7fffu + ((u>>16)&1u))>>16); }
__device__ __forceinline__ float bf2f(u16 h){ return __uint_as_float(((unsigned)h)<<16); }

__device__ __forceinline__ void gld16(const void* g, void* l) {
    __builtin_amdgcn_global_load_lds(
        (const __attribute__((address_space(1))) void*)g,
        (__attribute__((address_space(3))) void*)l, 16, 0, 0);
}

// ---------------------------------------------------------------------------
// One-time weight converts. Conv weights: tap-major K (k' = tap*128+c),
// BK=64 granule-XOR swizzle baked in: stored slot s holds granule g = s^(row&7).
// ---------------------------------------------------------------------------
__global__ __launch_bounds__(256)
void wcc1(const float* __restrict__ rw, u16* __restrict__ wb)
{
    const int i = blockIdx.x*256 + threadIdx.x;     // exactly 6*128*512
    const int layer = i >> 16;
    const int r = (i >> 9) & 127;
    const int k = i & 511;
    const int ks = k >> 6, s = (k >> 3) & 7, j = k & 7;
    const int g = s ^ (r & 7);
    const int tap = ks >> 1;
    const int c = ((ks & 1) << 6) + g*8 + j;
    wb[i] = f2bf(rw[(size_t)layer*65536 + r*512 + c*4 + tap]);
}
// conv2 weights also pre-interleaved into Bs-row order (gate t1/t2 pairing)
__global__ __launch_bounds__(256)
void wcc2(const float* __restrict__ rw, u16* __restrict__ wb)
{
    const int i = blockIdx.x*256 + threadIdx.x;     // exactly 6*256*512
    const int layer = i >> 17;
    const int R = (i >> 9) & 255;
    const int k = i & 511;
    const int by = R >> 7, r = R & 127;
    const int h = (r >> 6) & 1, f2 = (r >> 4) & 3, rr = r & 15;
    const int ch = (f2 < 2) ? (by*64 + h*32 + f2*16 + rr)
                            : (128 + by*64 + h*32 + (f2-2)*16 + rr);
    const int ks = k >> 6, s = (k >> 3) & 7, j = k & 7;
    const int g = s ^ (R & 7);
    const int tap = ks >> 1;
    const int c = ((ks & 1) << 6) + g*8 + j;
    wb[i] = f2bf(rw[(size_t)layer*131072 + ch*512 + c*4 + tap]);
}
__global__ __launch_bounds__(256)
void wc1_k(const float* __restrict__ w0, const float* __restrict__ w1,
           const float* __restrict__ w2, const float* __restrict__ w3, u16* __restrict__ wb)
{
    int i = blockIdx.x*256 + threadIdx.x;   // 0..65535
    const float* src = (i<16384)? w0 : (i<32768)? w1 : (i<49152)? w2 : w3;
    wb[i] = f2bf(src[i & 16383]);
}
__global__ __launch_bounds__(256)
void wcq_k(const float* __restrict__ qkvw, u16* __restrict__ qw)
{
    int i = blockIdx.x*256 + threadIdx.x;   // 192*128 = 24576
    if (i >= 24576) return;
    int r = i >> 7, c = i & 127;
    qw[i] = (r < 160) ? f2bf(qkvw[(size_t)r*130 + c]) : (u16)0;
}

// ---------------------------------------------------------------------------
// init: x (B,128,HW) f32 -> A (B,PB,128) f32 padded + Eb (B,PB,128) bf16(elu)
// ---------------------------------------------------------------------------
__global__ __launch_bounds__(256)
void init_k(const float* __restrict__ x, float* __restrict__ A, u16* __restrict__ Eb)
{
    __shared__ float t[32][132];
    const int b = blockIdx.y, p0 = blockIdx.x*32;   // one image row
    const int tid = threadIdx.x;
    const int cr = tid >> 3, p4 = (tid & 7)*4;
    #pragma unroll
    for (int cc = 0; cc < 128; cc += 32) {
        const float4 v = *(const float4*)(x + ((size_t)b*128 + cc + cr)*HW + p0 + p4);
        t[p4+0][cc+cr]=v.x; t[p4+1][cc+cr]=v.y; t[p4+2][cc+cr]=v.z; t[p4+3][cc+cr]=v.w;
    }
    __syncthreads();
    const int pr = tid >> 3, c4 = (tid & 7)*4;
    const int px = p0 + pr;
    const int pad = GP + px + (px>>5);
    #pragma unroll
    for (int cc = 0; cc < 128; cc += 32) {
        const int c = cc + c4;
        float4 v; v.x=t[pr][c]; v.y=t[pr][c+1]; v.z=t[pr][c+2]; v.w=t[pr][c+3];
        *(float4*)(A + ((size_t)b*PB + pad)*128 + c) = v;
        ushort4 e;
        e.x=f2bf(elu_f(v.x)); e.y=f2bf(elu_f(v.y)); e.z=f2bf(elu_f(v.z)); e.w=f2bf(elu_f(v.w));
        *(ushort4*)(Eb + ((size_t)b*PB + pad)*128 + c) = e;
    }
}

// ---------------------------------------------------------------------------
// global_load_lds conv2x2 GEMM. BK=64, double-buffered, 1 barrier/step.
// Padded image geometry -> no im2col masking. Swizzle: LDS slot s of row r
// holds k-granule g = s^(r&7); weights pre-swizzled; A source pre-swizzled.
// EPI 0: out0 = bf16(elu(acc+bias)), padded                        (conv1)
// EPI 1: gate: o = Aio + t1*sig(t2); Aio=o; out0=bf16(elu(o)) padded;
//        raw0 (unpadded bf16 state) if non-null                    (conv2)
// ---------------------------------------------------------------------------
#define GSTAGE(ks, buf) do {                                                     \
    const int tap_ = (ks) >> 1;                                                  \
    const int off_ = (tap_>>1)*RS + (tap_&1) - RS - 1;                           \
    const int c0_  = ((ks) & 1) << 6;                                            \
    _Pragma("unroll")                                                            \
    for (int ca_=0; ca_<NCALLA; ++ca_) {                                         \
        const int row_ = ca_*32 + wv*8 + (lane>>3);                              \
        const int px_  = p0 + row_;                                              \
        const int pad_ = GP + px_ + (px_>>5);                                    \
        const int g_   = (lane&7) ^ (lane>>3);                                   \
        gld16(ebB + (size_t)(pad_ + off_)*128 + c0_ + g_*8,                      \
              (char*)As[buf] + (ca_*32 + wv*8)*128 + lane*16);                   \
    }                                                                            \
    _Pragma("unroll")                                                            \
    for (int cb_=0; cb_<4; ++cb_) {                                              \
        const int row_ = cb_*32 + wv*8 + (lane>>3);                              \
        gld16(wbB + (size_t)row_*512 + (ks)*64 + (lane&7)*8,                     \
              (char*)Bs[buf] + (cb_*32 + wv*8)*128 + lane*16);                   \
    }                                                                            \
} while(0)

#define GCOMP(buf) do {                                                          \
    _Pragma("unroll")                                                            \
    for (int k2_=0; k2_<2; ++k2_) {                                              \
        short8v wf_[4], pf_[MA];                                                 \
        const int sl_ = ((k2_*4 + lg) ^ (lr & 7)) * 8;                           \
        _Pragma("unroll")                                                        \
        for (int f_=0; f_<4; ++f_)                                               \
            wf_[f_] = *(const short8v*)&Bs[buf][(chh*64 + f_*16 + lr)*64 + sl_]; \
        _Pragma("unroll")                                                        \
        for (int m_=0; m_<MA; ++m_)                                              \
            pf_[m_] = *(const short8v*)&As[buf][(pxh*(BM/2) + m_*16 + lr)*64 + sl_]; \
        _Pragma("unroll")                                                        \
        for (int f_=0; f_<4; ++f_)                                               \
            _Pragma("unroll")                                                    \
            for (int m_=0; m_<MA; ++m_)                                          \
                acc[f_][m_] = __builtin_amdgcn_mfma_f32_16x16x32_bf16(wf_[f_], pf_[m_], acc[f_][m_],0,0,0); \
    }                                                                            \
} while(0)

template<int BM, int EPI>
__global__ __launch_bounds__(256)
void convg(const u16* __restrict__ Wb, const float* __restrict__ bias,
           const u16* __restrict__ Ein, u16* __restrict__ out0,
           float* __restrict__ Aio, u16* __restrict__ raw0)
{
    constexpr int NS = 8;              // K=512, BK=64
    constexpr int MA = BM/32;
    constexpr int NCALLA = BM/32;
    __shared__ u16 As[2][BM*64];
    __shared__ u16 Bs[2][128*64];
    const int tid = threadIdx.x;
    const int b = blockIdx.z, p0 = blockIdx.x*BM, cb0 = blockIdx.y*64;
    const int wv = tid>>6, lane = tid&63, lr = lane&15, lg = lane>>4;
    const int pxh = wv&1, chh = wv>>1;
    const u16* ebB = Ein + (size_t)b*PB*128;
    const u16* wbB = Wb + (size_t)blockIdx.y*128*512;
    f32x4 acc[4][MA] = {};

    GSTAGE(0, 0);
    __syncthreads();
    #pragma unroll
    for (int ks = 0; ks < NS; ++ks) {
        if (ks + 1 < NS) GSTAGE(ks+1, (ks+1)&1);
        GCOMP(ks&1);
        __syncthreads();
    }

    if constexpr (EPI == 1) {
        #pragma unroll
        for (int f=0; f<2; ++f) {
            const int c = cb0 + chh*32 + f*16 + lg*4;
            const float4 b1 = *(const float4*)(bias + c);
            const float4 b2 = *(const float4*)(bias + 128 + c);
            #pragma unroll
            for (int m=0; m<MA; ++m) {
                const int px = p0 + pxh*(BM/2) + m*16 + lr;
                const int pad = GP + px + (px>>5);
                float* ap = Aio + ((size_t)b*PB + pad)*128 + c;
                const float4 pv = *(const float4*)ap;
                const float o0 = pv.x + (acc[f][m][0]+b1.x)*sig_f(acc[f+2][m][0]+b2.x);
                const float o1 = pv.y + (acc[f][m][1]+b1.y)*sig_f(acc[f+2][m][1]+b2.y);
                const float o2 = pv.z + (acc[f][m][2]+b1.z)*sig_f(acc[f+2][m][2]+b2.z);
                const float o3 = pv.w + (acc[f][m][3]+b1.w)*sig_f(acc[f+2][m][3]+b2.w);
                float4 ov; ov.x=o0; ov.y=o1; ov.z=o2; ov.w=o3;
                *(float4*)ap = ov;
                ushort4 e;
                e.x=f2bf(elu_f(o0)); e.y=f2bf(elu_f(o1)); e.z=f2bf(elu_f(o2)); e.w=f2bf(elu_f(o3));
                *(ushort4*)(out0 + ((size_t)b*PB + pad)*128 + c) = e;
                if (raw0) {
                    ushort4 rr;
                    rr.x=f2bf(o0); rr.y=f2bf(o1); rr.z=f2bf(o2); rr.w=f2bf(o3);
                    *(ushort4*)(raw0 + ((size_t)b*HW + px)*128 + c) = rr;
                }
            }
        }
    } else {
        #pragma unroll
        for (int f=0; f<4; ++f) {
            const int c = chh*64 + f*16 + lg*4;
            const float4 bb = *(const float4*)(bias + c);
            #pragma unroll
            for (int m=0; m<MA; ++m) {
                const int px = p0 + pxh*(BM/2) + m*16 + lr;
                const int pad = GP + px + (px>>5);
                ushort4 e;
                e.x=f2bf(elu_f(acc[f][m][0]+bb.x));
                e.y=f2bf(elu_f(acc[f][m][1]+bb.y));
                e.z=f2bf(elu_f(acc[f][m][2]+bb.z));
                e.w=f2bf(elu_f(acc[f][m][3]+bb.w));
                *(ushort4*)(out0 + ((size_t)b*PB + pad)*128 + c) = e;
            }
        }
    }
}

// ---------------------------------------------------------------------------
// Head 1x1 conv (reg-staged, r6-proven structure). BM=64, K=128.
// EPI 0: out0 = bf16(elu(acc+bias)) unpadded
// EPI 2: out0 = bf16(elu( elu(acc+bias) + aux )) unpadded
// EPI 3: fout[ch-major] = elu(acc+bias) + xres (f32)
// PADIN: input buffer uses padded geometry (Eb)
// ---------------------------------------------------------------------------
template<int EPI, int PADIN>
__global__ __launch_bounds__(256)
void convh(const u16* __restrict__ Wb, const float* __restrict__ bias,
           const u16* __restrict__ Ein, u16* __restrict__ out0,
           const u16* __restrict__ aux, const float* __restrict__ xres,
           float* __restrict__ fout)
{
    __shared__ u16 As[2][64*40];
    __shared__ u16 Bs[2][128*40];
    const int tid = threadIdx.x;
    const int b = blockIdx.z, p0 = blockIdx.x*64;
    const int wv = tid>>6, lane = tid&63, lr = lane&15, lg = lane>>4;
    const int pxh = wv&1, chh = wv>>1;
    const u16* eb = Ein + (size_t)b*(PADIN ? PB : HW)*128;
    const int arow = tid>>2, ag = tid&3;
    const int apx0 = p0 + arow;
    const int apx = PADIN ? (GP + apx0 + (apx0>>5)) : apx0;
    int brow[2], bg[2];
    #pragma unroll
    for (int c=0;c<2;++c){ const int ci=tid+c*256; brow[c]=ci>>2; bg[c]=ci&3; }
    uint4 ra, rb[2];
    f32x4 acc[4][2] = {};
    auto GL = [&](int ks){
        const int k0 = ks*32;
        ra = *(const uint4*)(eb + (size_t)apx*128 + k0 + ag*8);
        #pragma unroll
        for (int c=0;c<2;++c)
            rb[c] = *(const uint4*)(Wb + (size_t)brow[c]*128 + k0 + bg[c]*8);
    };
    auto ST = [&](int buf){
        *(uint4*)&As[buf][arow*40 + ag*8] = ra;
        #pragma unroll
        for (int c=0;c<2;++c) *(uint4*)&Bs[buf][brow[c]*40 + bg[c]*8] = rb[c];
    };
    GL(0); ST(0); __syncthreads();
    #pragma unroll
    for (int ks=0; ks<4; ++ks) {
        const int cur = ks&1;
        if (ks < 3) GL(ks+1);
        short8v wf[4], pf[2];
        #pragma unroll
        for (int f=0;f<4;++f)
            wf[f] = *(const short8v*)&Bs[cur][(chh*64 + f*16 + lr)*40 + lg*8];
        #pragma unroll
        for (int m=0;m<2;++m)
            pf[m] = *(const short8v*)&As[cur][(pxh*32 + m*16 + lr)*40 + lg*8];
        #pragma unroll
        for (int f=0;f<4;++f)
            #pragma unroll
            for (int m=0;m<2;++m)
                acc[f][m] = __builtin_amdgcn_mfma_f32_16x16x32_bf16(wf[f], pf[m], acc[f][m],0,0,0);
        __syncthreads();
        if (ks < 3) { ST((ks+1)&1); __syncthreads(); }
    }
    #pragma unroll
    for (int f=0; f<4; ++f) {
        const int c = chh*64 + f*16 + lg*4;
        #pragma unroll
        for (int m=0;m<2;++m) {
            const int px = p0 + pxh*32 + m*16 + lr;
            if constexpr (EPI == 3) {
                const float* bp = bias + c;
                #pragma unroll
                for (int r=0;r<4;++r) {
                    const size_t o = ((size_t)b*128 + c + r)*HW + px;
                    fout[o] = elu_f(acc[f][m][r] + bp[r]) + xres[o];
                }
            } else {
                const float4 bb = *(const float4*)(bias + c);
                const float v0=acc[f][m][0]+bb.x, v1=acc[f][m][1]+bb.y;
                const float v2=acc[f][m][2]+bb.z, v3=acc[f][m][3]+bb.w;
                ushort4 e;
                if constexpr (EPI == 2) {
                    const ushort4 c4 = *(const ushort4*)(aux + ((size_t)b*HW+px)*128 + c);
                    e.x = f2bf(elu_f(elu_f(v0) + bf2f(c4.x)));
                    e.y = f2bf(elu_f(elu_f(v1) + bf2f(c4.y)));
                    e.z = f2bf(elu_f(elu_f(v2) + bf2f(c4.z)));
                    e.w = f2bf(elu_f(elu_f(v3) + bf2f(c4.w)));
                } else {
                    e.x=f2bf(elu_f(v0)); e.y=f2bf(elu_f(v1));
                    e.z=f2bf(elu_f(v2)); e.w=f2bf(elu_f(v3));
                }
                *(ushort4*)(out0 + ((size_t)b*HW+px)*128 + c) = e;
            }
        }
    }
}

// ---------------------------------------------------------------------------
// qkv bf16 MFMA GEMM: M=160 (padded 192), K=128. Input Ab (B,HW,128) raw bf16.
// ---------------------------------------------------------------------------
__global__ __launch_bounds__(256)
void qkvm(const u16* __restrict__ Wq, const float* __restrict__ qkvw,
          const float* __restrict__ bias, const u16* __restrict__ Ab,
          u16* __restrict__ qo, u16* __restrict__ ko, u16* __restrict__ vo)
{
    __shared__ u16 As[2][64*40];
    __shared__ u16 Bs[2][192*40];
    const int tid = threadIdx.x;
    const int b = blockIdx.z, p0 = blockIdx.x*64;
    const int wv = tid>>6, lane = tid&63, lr = lane&15, lg = lane>>4;
    const int pxh = wv&1, chh = wv>>1;
    const u16* ab = Ab + (size_t)b*HW*128;
    const int arow = tid>>2, ag = tid&3;
    const int apx = p0 + arow;
    int brow[3], bg[3];
    #pragma unroll
    for (int c=0;c<3;++c){ const int ci=tid+c*256; brow[c]=ci>>2; bg[c]=ci&3; }
    uint4 ra, rb[3];
    f32x4 acc[6][2] = {};
    auto GL = [&](int ks){
        const int k0 = ks*32;
        ra = *(const uint4*)(ab + (size_t)apx*128 + k0 + ag*8);
        #pragma unroll
        for (int c=0;c<3;++c)
            rb[c] = *(const uint4*)(Wq + (size_t)brow[c]*128 + k0 + bg[c]*8);
    };
    auto ST = [&](int buf){
        *(uint4*)&As[buf][arow*40 + ag*8] = ra;
        #pragma unroll
        for (int c=0;c<3;++c)
            *(uint4*)&Bs[buf][brow[c]*40 + bg[c]*8] = rb[c];
    };
    GL(0); ST(0); __syncthreads();
    for (int ks=0; ks<4; ++ks) {
        const int cur = ks&1;
        if (ks < 3) GL(ks+1);
        short8v wf[6], pf[2];
        #pragma unroll
        for (int f=0;f<6;++f)
            wf[f] = *(const short8v*)&Bs[cur][(chh*96 + f*16 + lr)*40 + lg*8];
        #pragma unroll
        for (int m=0;m<2;++m)
            pf[m] = *(const short8v*)&As[cur][(pxh*32 + m*16 + lr)*40 + lg*8];
        #pragma unroll
        for (int f=0;f<6;++f)
            #pragma unroll
            for (int m=0;m<2;++m)
                acc[f][m] = __builtin_amdgcn_mfma_f32_16x16x32_bf16(wf[f], pf[m], acc[f][m],0,0,0);
        __syncthreads();
        if (ks < 3) { ST((ks+1)&1); __syncthreads(); }
    }
    #pragma unroll
    for (int f=0; f<6; ++f) {
        const int row0 = chh*96 + f*16;
        if (row0 >= 160) continue;
        #pragma unroll
        for (int m=0;m<2;++m) {
            const int px = p0 + pxh*32 + m*16 + lr;
            const float pyv = (float)(px>>5)*0.03125f - 0.5f;
            const float pxv = (float)(px&31)*0.03125f - 0.5f;
            #pragma unroll
            for (int r=0;r<4;++r) {
                const int mm = row0 + lg*4 + r;
                const float val = acc[f][m][r] + bias[mm]
                                + qkvw[(size_t)mm*130 + 128]*pyv
                                + qkvw[(size_t)mm*130 + 129]*pxv;
                if (mm < 16)      qo[((size_t)b*HW+px)*16 + mm]        = f2bf(0.25f*val);
                else if (mm < 32) ko[((size_t)b*HW+px)*16 + (mm-16)]   = f2bf(val);
                else              vo[((size_t)b*128 + (mm-32))*HW + px] = f2bf(val);
            }
        }
    }
}

// ---------------------------------------------------------------------------
// MFMA causal attention, 4 waves: 2 q-tiles x 2 d-halves; dbuf LDS K/V chunks.
// ---------------------------------------------------------------------------
__global__ __launch_bounds__(256)
void attn_mfma(const u16* __restrict__ qb, const u16* __restrict__ kb,
               const u16* __restrict__ vb, u16* __restrict__ ob)
{
    __shared__ u16 ks_[2][32*24];
    __shared__ u16 vs_[2][128*40];
    const int tid = threadIdx.x;
    const int bid = blockIdx.x;              // 0..511
    const int tp  = 15 - (bid >> 5);         // tile-pair, long first
    const int b   = bid & 31;
    const int wv = tid>>6, lane = tid&63;
    const int lq = lane&31, hf = lane>>5;
    const int qt = tp*2 + (wv&1);
    const int dh = wv>>1;
    const int q0 = qt*32;
    const int NC = tp*2 + 2;

    const short8v Qf = *(const short8v*)(qb + ((size_t)b*HW + q0 + lq)*16 + hf*8);
    f32x16 acc[2] = {{},{}};
    float mrun = -1e30f, lrun = 0.f;
    unsigned diagm = 0;
    #pragma unroll
    for (int r=0; r<16; ++r) {
        const int row = (r&3) + 8*(r>>2) + 4*hf;
        diagm |= (row <= lq) ? (1u<<r) : 0u;
    }
    const f32x16 zc = {};

    const int vrow = tid>>2, vg = tid&3;
    const int krow = tid>>1, kg = tid&1;
    const u16* vbb = vb + (size_t)b*128*HW;
    const u16* kbb = kb + (size_t)b*HW*16;
    uint4 rv0A, rv1A, rkA, rv0B, rv1B, rkB;

#define AGLD(c, RV0, RV1, RK) do {                                             \
    const int kv0_ = (c)*32;                                                   \
    RV0 = *(const uint4*)(vbb + (size_t)vrow*HW + kv0_ + vg*8);                \
    RV1 = *(const uint4*)(vbb + (size_t)(64+vrow)*HW + kv0_ + vg*8);           \
    if (tid < 64) RK = *(const uint4*)(kbb + (size_t)(kv0_ + krow)*16 + kg*8); \
} while(0)
#define ASST(buf, RV0, RV1, RK) do {                                           \
    *(uint4*)&vs_[buf][vrow*40 + vg*8] = RV0;                                  \
    *(uint4*)&vs_[buf][(64+vrow)*40 + vg*8] = RV1;                             \
    if (tid < 64) *(uint4*)&ks_[buf][krow*24 + kg*8] = RK;                     \
} while(0)

    auto CHUNK = [&](int buf, int cc) {
        if (cc > qt) return;
        const short8v Kf = *(const short8v*)&ks_[buf][lq*24 + hf*8];
        f32x16 st = __builtin_amdgcn_mfma_f32_32x32x16_bf16(Kf, Qf, zc, 0,0,0);
        if (cc == qt) {
            #pragma unroll
            for (int r=0;r<16;++r) st[r] = ((diagm>>r)&1) ? st[r] : -1e30f;
        }
        float mc = st[0];
        #pragma unroll
        for (int r=1;r<16;++r) mc = fmaxf(mc, st[r]);
        mc = fmaxf(mc, __shfl_xor(mc, 32));
        if (!__all(mc <= mrun)) {
            const float mnew = fmaxf(mrun, mc);
            const float corr = __expf(mrun - mnew);
            lrun *= corr;
            #pragma unroll
            for (int f=0;f<2;++f)
                #pragma unroll
                for (int r=0;r<16;++r) acc[f][r] *= corr;
            mrun = mnew;
        }
        float ps[16]; float lsum = 0.f;
        #pragma unroll
        for (int r=0;r<16;++r){ ps[r]=__expf(st[r]-mrun); lsum += ps[r]; }
        lrun += lsum + __shfl_xor(lsum, 32);
        unsigned pk[8], sw[8];
        #pragma unroll
        for (int i=0;i<8;++i)
            pk[i] = (unsigned)f2bf(ps[2*i]) | ((unsigned)f2bf(ps[2*i+1])<<16);
        #pragma unroll
        for (int i=0;i<8;++i) sw[i] = __shfl_xor(pk[i], 32);
        union { unsigned u[4]; short8v v; } B1, B2;
        B1.u[0]=hf?sw[2]:pk[0]; B1.u[1]=hf?sw[3]:pk[1];
        B1.u[2]=hf?pk[2]:sw[0]; B1.u[3]=hf?pk[3]:sw[1];
        B2.u[0]=hf?sw[6]:pk[4]; B2.u[1]=hf?sw[7]:pk[5];
        B2.u[2]=hf?pk[6]:sw[4]; B2.u[3]=hf?pk[7]:sw[5];
        #pragma unroll
        for (int f=0;f<2;++f) {
            const int fg = dh*2 + f;
            const short8v A1 = *(const short8v*)&vs_[buf][(fg*32+lq)*40 + hf*8];
            const short8v A2 = *(const short8v*)&vs_[buf][(fg*32+lq)*40 + 16 + hf*8];
            acc[f] = __builtin_amdgcn_mfma_f32_32x32x16_bf16(A1, B1.v, acc[f],0,0,0);
            acc[f] = __builtin_amdgcn_mfma_f32_32x32x16_bf16(A2, B2.v, acc[f],0,0,0);
        }
    };

    AGLD(0, rv0A, rv1A, rkA); ASST(0, rv0A, rv1A, rkA);
    AGLD(1, rv0B, rv1B, rkB);
    __syncthreads();
    for (int c = 0; c < NC; c += 2) {
        CHUNK(0, c);
        ASST(1, rv0B, rv1B, rkB);
        if (c+2 < NC) AGLD(c+2, rv0A, rv1A, rkA);
        __syncthreads();
        CHUNK(1, c+1);
        if (c+2 < NC) {
            ASST(0, rv0A, rv1A, rkA);
            if (c+3 < NC) AGLD(c+3, rv0B, rv1B, rkB);
        }
        __syncthreads();
    }
#undef AGLD
#undef ASST

    const float inv = 1.f / lrun;
    u16* orow = ob + ((size_t)b*HW + q0 + lq)*128;
    #pragma unroll
    for (int f=0; f<2; ++f) {
        #pragma unroll
        for (int g=0; g<4; ++g) {
            const int d0 = (dh*2+f)*32 + 8*g + 4*hf;
            ushort4 o4;
            o4.x = f2bf(acc[f][g*4+0]*inv);
            o4.y = f2bf(acc[f][g*4+1]*inv);
            o4.z = f2bf(acc[f][g*4+2]*inv);
            o4.w = f2bf(acc[f][g*4+3]*inv);
            *(ushort4*)(orow + d0) = o4;
        }
    }
}

extern "C" void kernel_launch(void* const* d_in, const int* in_sizes, int n_in,
                              void* d_out, int out_size, void* d_ws, size_t ws_size,
                              hipStream_t stream) {
    const float* x    = (const float*)d_in[0];
    const float* rw1  = (const float*)d_in[1];
    const float* rb1  = (const float*)d_in[2];
    const float* rw2  = (const float*)d_in[3];
    const float* rb2  = (const float*)d_in[4];
    const float* qkvw = (const float*)d_in[5];
    const float* qkvb = (const float*)d_in[6];
    const float* apw  = (const float*)d_in[7];
    const float* apb  = (const float*)d_in[8];
    const float* ocw  = (const float*)d_in[9];
    const float* ocb  = (const float*)d_in[10];
    const float* oaw  = (const float*)d_in[11];
    const float* oab  = (const float*)d_in[12];
    const float* opw  = (const float*)d_in[13];
    const float* opb  = (const float*)d_in[14];
    float* out = (float*)d_out;
    float* ws = (float*)d_ws;

    // Workspace (float offsets):
    float* A  = ws;                          // [0, 4,587,520) padded f32 state
    u16* Eb   = (u16*)(ws + 4587520);        // padded bf16(elu(state))
    u16* E2   = (u16*)(ws + 6881280);        // padded conv1 out; later Ea
    u16* Ab   = (u16*)(ws + 9175040);        // (B,HW,128) raw bf16 state; later ob, Es
    u16* qb   = (u16*)(ws + 11272192);
    u16* kb   = (u16*)(ws + 11534336);
    u16* vb   = (u16*)(ws + 11796480);       // V^T; later c1p
    u16* w1b  = (u16*)(ws + 13893632);       // 6*128*512
    u16* w2b  = (u16*)(ws + 14090240);       // 6*256*512
    u16* wh   = (u16*)(ws + 14483456);       // 4*128*128
    u16* qw   = (u16*)(ws + 14516224);       // 192*128
    u16* ob   = Ab;
    u16* Ea   = E2;
    u16* c1p  = vb;
    u16* Es   = Ab;

    dim3 blk(256);
    hipMemsetAsync(Eb, 0, (size_t)32*PB*128*2, stream);
    hipMemsetAsync(E2, 0, (size_t)32*PB*128*2, stream);
    wcc1<<<1536, blk, 0, stream>>>(rw1, w1b);
    wcc2<<<3072, blk, 0, stream>>>(rw2, w2b);
    wc1_k<<<256,  blk, 0, stream>>>(apw, ocw, oaw, opw, wh);
    wcq_k<<<96,   blk, 0, stream>>>(qkvw, qw);
    init_k<<<dim3(32, 32), blk, 0, stream>>>(x, A, Eb);
    for (int i = 0; i < 6; ++i) {
        convg<64,0><<<dim3(16,1,32), blk, 0, stream>>>(
            w1b + (size_t)i*65536, rb1 + i*128, Eb, E2, nullptr, nullptr);
        convg<128,1><<<dim3(8,2,32), blk, 0, stream>>>(
            w2b + (size_t)i*131072, rb2 + i*256, E2, Eb, A, (i==5)? Ab : nullptr);
    }
    qkvm<<<dim3(16,1,32), blk, 0, stream>>>(qw, qkvw, qkvb, Ab, qb, kb, vb);
    attn_mfma<<<512, blk, 0, stream>>>(qb, kb, vb, ob);
    convh<0,0><<<dim3(16,1,32), blk, 0, stream>>>(wh,        apb, ob, Ea, nullptr, nullptr, nullptr);
    convh<0,1><<<dim3(16,1,32), blk, 0, stream>>>(wh+16384,  ocb, Eb, c1p, nullptr, nullptr, nullptr);
    convh<2,0><<<dim3(16,1,32), blk, 0, stream>>>(wh+32768,  oab, Ea, Es, c1p, nullptr, nullptr);
    convh<3,0><<<dim3(16,1,32), blk, 0, stream>>>(wh+49152,  opb, Es, nullptr, nullptr, x, out);
}

// Round 8
// 286.478 us; speedup vs baseline: 1.9520x; 1.0591x over previous
//
#include <hip/hip_runtime.h>
#include <math.h>

#define HW 1024
#define RS 33            // padded row stride (32 px + 1 zero col)
#define GP 34            // zero guard pixels before each image
#define PB 1120          // padded pixels per batch image

typedef unsigned short u16;
typedef __attribute__((ext_vector_type(8))) short short8v;   // 8 bf16
typedef __attribute__((ext_vector_type(4))) float f32x4;
typedef __attribute__((ext_vector_type(16))) float f32x16;

__device__ __forceinline__ float elu_f(float x){ return x>0.f? x : (__expf(x)-1.f); }
__device__ __forceinline__ float sig_f(float x){ return 1.f/(1.f+__expf(-x)); }
__device__ __forceinline__ u16 f2bf(float f){ unsigned u=__float_as_uint(f); return (u16)((u + 0x7fffu + ((u>>16)&1u))>>16); }
__device__ __forceinline__ float bf2f(u16 h){ return __uint_as_float(((unsigned)h)<<16); }

__device__ __forceinline__ void gld16(const void* g, void* l) {
    __builtin_amdgcn_global_load_lds(
        (const __attribute__((address_space(1))) void*)g,
        (__attribute__((address_space(3))) void*)l, 16, 0, 0);
}

// ---------------------------------------------------------------------------
// Merged one-time weight convert (conv weights tap-major K + BK64 granule-XOR
// swizzle baked in; conv2 additionally pre-interleaved to gate Bs-row order).
// ---------------------------------------------------------------------------
__global__ __launch_bounds__(256)
void wconv(const float* __restrict__ rw1, const float* __restrict__ rw2,
           const float* __restrict__ apw, const float* __restrict__ ocw,
           const float* __restrict__ oaw, const float* __restrict__ opw,
           const float* __restrict__ qkvw,
           u16* __restrict__ w1b, u16* __restrict__ w2b,
           u16* __restrict__ wh,  u16* __restrict__ qw)
{
    const int i = blockIdx.x*256 + threadIdx.x;
    if (i < 393216) {                       // conv1 weights: 6*128*512
        const int layer = i >> 16;
        const int r = (i >> 9) & 127;
        const int k = i & 511;
        const int ks = k >> 6, s = (k >> 3) & 7, j = k & 7;
        const int g = s ^ (r & 7);
        const int tap = ks >> 1;
        const int c = ((ks & 1) << 6) + g*8 + j;
        w1b[i] = f2bf(rw1[(size_t)layer*65536 + r*512 + c*4 + tap]);
    } else if (i < 1179648) {               // conv2 weights: 6*256*512
        const int ii = i - 393216;
        const int layer = ii >> 17;
        const int R = (ii >> 9) & 255;
        const int k = ii & 511;
        const int by = R >> 7, r = R & 127;
        const int h = (r >> 6) & 1, f2 = (r >> 4) & 3, rr = r & 15;
        const int ch = (f2 < 2) ? (by*64 + h*32 + f2*16 + rr)
                                : (128 + by*64 + h*32 + (f2-2)*16 + rr);
        const int ks = k >> 6, s = (k >> 3) & 7, j = k & 7;
        const int g = s ^ (R & 7);
        const int tap = ks >> 1;
        const int c = ((ks & 1) << 6) + g*8 + j;
        w2b[ii] = f2bf(rw2[(size_t)layer*131072 + ch*512 + c*4 + tap]);
    } else if (i < 1245184) {               // head 1x1 weights: 4*128*128
        const int ii = i - 1179648;
        const float* src = (ii<16384)? apw : (ii<32768)? ocw : (ii<49152)? oaw : opw;
        wh[ii] = f2bf(src[ii & 16383]);
    } else if (i < 1269760) {               // qkv weights padded to 192 rows
        const int ii = i - 1245184;
        const int r = ii >> 7, c = ii & 127;
        qw[ii] = (r < 160) ? f2bf(qkvw[(size_t)r*130 + c]) : (u16)0;
    }
}

// Zero the 96 guard slots per batch image in Eb and E2 (1.6 MB total).
__global__ __launch_bounds__(256)
void gz(u16* __restrict__ Eb, u16* __restrict__ E2)
{
    const int half = blockIdx.x / 192;
    const int idx = (blockIdx.x % 192)*256 + threadIdx.x;   // 0..49151
    const int b = idx / 1536;
    const int rem = idx % 1536;
    const int g = rem >> 4, c8 = rem & 15;
    const int slot = (g < 34) ? g : (g < 65) ? (66 + 33*(g-34)) : (1089 + (g-65));
    u16* dst = (half ? E2 : Eb) + ((size_t)b*PB + slot)*128 + c8*8;
    uint4 z; z.x=0u; z.y=0u; z.z=0u; z.w=0u;
    *(uint4*)dst = z;
}

// ---------------------------------------------------------------------------
// init: x (B,128,HW) f32 -> Sb (B,PB,128) bf16 state + Eb bf16(elu(x)) padded
// ---------------------------------------------------------------------------
__global__ __launch_bounds__(256)
void init_k(const float* __restrict__ x, u16* __restrict__ Sb, u16* __restrict__ Eb)
{
    __shared__ float t[32][132];
    const int b = blockIdx.y, p0 = blockIdx.x*32;
    const int tid = threadIdx.x;
    const int cr = tid >> 3, p4 = (tid & 7)*4;
    #pragma unroll
    for (int cc = 0; cc < 128; cc += 32) {
        const float4 v = *(const float4*)(x + ((size_t)b*128 + cc + cr)*HW + p0 + p4);
        t[p4+0][cc+cr]=v.x; t[p4+1][cc+cr]=v.y; t[p4+2][cc+cr]=v.z; t[p4+3][cc+cr]=v.w;
    }
    __syncthreads();
    const int pr = tid >> 3, c4 = (tid & 7)*4;
    const int px = p0 + pr;
    const int pad = GP + px + (px>>5);
    #pragma unroll
    for (int cc = 0; cc < 128; cc += 32) {
        const int c = cc + c4;
        float4 v; v.x=t[pr][c]; v.y=t[pr][c+1]; v.z=t[pr][c+2]; v.w=t[pr][c+3];
        ushort4 s4;
        s4.x=f2bf(v.x); s4.y=f2bf(v.y); s4.z=f2bf(v.z); s4.w=f2bf(v.w);
        *(ushort4*)(Sb + ((size_t)b*PB + pad)*128 + c) = s4;
        ushort4 e;
        e.x=f2bf(elu_f(v.x)); e.y=f2bf(elu_f(v.y)); e.z=f2bf(elu_f(v.z)); e.w=f2bf(elu_f(v.w));
        *(ushort4*)(Eb + ((size_t)b*PB + pad)*128 + c) = e;
    }
}

// ---------------------------------------------------------------------------
// global_load_lds conv2x2 GEMM (r7 structure, state now bf16).
// EPI 0: out0 = bf16(elu(acc+bias)) padded                         (conv1)
// EPI 1: gate: o = Sio + t1*sig(t2); Sio=bf16(o); out0=bf16(elu(o)) (conv2)
// ---------------------------------------------------------------------------
#define GSTAGE(ks, buf) do {                                                     \
    const int tap_ = (ks) >> 1;                                                  \
    const int off_ = (tap_>>1)*RS + (tap_&1) - RS - 1;                           \
    const int c0_  = ((ks) & 1) << 6;                                            \
    _Pragma("unroll")                                                            \
    for (int ca_=0; ca_<NCALLA; ++ca_) {                                         \
        const int row_ = ca_*32 + wv*8 + (lane>>3);                              \
        const int px_  = p0 + row_;                                              \
        const int pad_ = GP + px_ + (px_>>5);                                    \
        const int g_   = (lane&7) ^ (lane>>3);                                   \
        gld16(ebB + (size_t)(pad_ + off_)*128 + c0_ + g_*8,                      \
              (char*)As[buf] + (ca_*32 + wv*8)*128 + lane*16);                   \
    }                                                                            \
    _Pragma("unroll")                                                            \
    for (int cb_=0; cb_<4; ++cb_) {                                              \
        const int row_ = cb_*32 + wv*8 + (lane>>3);                              \
        gld16(wbB + (size_t)row_*512 + (ks)*64 + (lane&7)*8,                     \
              (char*)Bs[buf] + (cb_*32 + wv*8)*128 + lane*16);                   \
    }                                                                            \
} while(0)

#define GCOMP(buf) do {                                                          \
    _Pragma("unroll")                                                            \
    for (int k2_=0; k2_<2; ++k2_) {                                              \
        short8v wf_[4], pf_[MA];                                                 \
        const int sl_ = ((k2_*4 + lg) ^ (lr & 7)) * 8;                           \
        _Pragma("unroll")                                                        \
        for (int f_=0; f_<4; ++f_)                                               \
            wf_[f_] = *(const short8v*)&Bs[buf][(chh*64 + f_*16 + lr)*64 + sl_]; \
        _Pragma("unroll")                                                        \
        for (int m_=0; m_<MA; ++m_)                                              \
            pf_[m_] = *(const short8v*)&As[buf][(pxh*(BM/2) + m_*16 + lr)*64 + sl_]; \
        _Pragma("unroll")                                                        \
        for (int f_=0; f_<4; ++f_)                                               \
            _Pragma("unroll")                                                    \
            for (int m_=0; m_<MA; ++m_)                                          \
                acc[f_][m_] = __builtin_amdgcn_mfma_f32_16x16x32_bf16(wf_[f_], pf_[m_], acc[f_][m_],0,0,0); \
    }                                                                            \
} while(0)

template<int BM, int EPI>
__global__ __launch_bounds__(256)
void convg(const u16* __restrict__ Wb, const float* __restrict__ bias,
           const u16* __restrict__ Ein, u16* __restrict__ out0,
           u16* __restrict__ Sio)
{
    constexpr int NS = 8;              // K=512, BK=64
    constexpr int MA = BM/32;
    constexpr int NCALLA = BM/32;
    __shared__ u16 As[2][BM*64];
    __shared__ u16 Bs[2][128*64];
    const int tid = threadIdx.x;
    const int b = blockIdx.z, p0 = blockIdx.x*BM, cb0 = blockIdx.y*64;
    const int wv = tid>>6, lane = tid&63, lr = lane&15, lg = lane>>4;
    const int pxh = wv&1, chh = wv>>1;
    const u16* ebB = Ein + (size_t)b*PB*128;
    const u16* wbB = Wb + (size_t)blockIdx.y*128*512;
    f32x4 acc[4][MA] = {};

    GSTAGE(0, 0);
    __syncthreads();
    #pragma unroll
    for (int ks = 0; ks < NS; ++ks) {
        if (ks + 1 < NS) GSTAGE(ks+1, (ks+1)&1);
        GCOMP(ks&1);
        __syncthreads();
    }

    if constexpr (EPI == 1) {
        #pragma unroll
        for (int f=0; f<2; ++f) {
            const int c = cb0 + chh*32 + f*16 + lg*4;
            const float4 b1 = *(const float4*)(bias + c);
            const float4 b2 = *(const float4*)(bias + 128 + c);
            #pragma unroll
            for (int m=0; m<MA; ++m) {
                const int px = p0 + pxh*(BM/2) + m*16 + lr;
                const int pad = GP + px + (px>>5);
                u16* sp = Sio + ((size_t)b*PB + pad)*128 + c;
                const ushort4 sv = *(const ushort4*)sp;
                const float o0 = bf2f(sv.x) + (acc[f][m][0]+b1.x)*sig_f(acc[f+2][m][0]+b2.x);
                const float o1 = bf2f(sv.y) + (acc[f][m][1]+b1.y)*sig_f(acc[f+2][m][1]+b2.y);
                const float o2 = bf2f(sv.z) + (acc[f][m][2]+b1.z)*sig_f(acc[f+2][m][2]+b2.z);
                const float o3 = bf2f(sv.w) + (acc[f][m][3]+b1.w)*sig_f(acc[f+2][m][3]+b2.w);
                ushort4 so;
                so.x=f2bf(o0); so.y=f2bf(o1); so.z=f2bf(o2); so.w=f2bf(o3);
                *(ushort4*)sp = so;
                ushort4 e;
                e.x=f2bf(elu_f(o0)); e.y=f2bf(elu_f(o1)); e.z=f2bf(elu_f(o2)); e.w=f2bf(elu_f(o3));
                *(ushort4*)(out0 + ((size_t)b*PB + pad)*128 + c) = e;
            }
        }
    } else {
        #pragma unroll
        for (int f=0; f<4; ++f) {
            const int c = chh*64 + f*16 + lg*4;
            const float4 bb = *(const float4*)(bias + c);
            #pragma unroll
            for (int m=0; m<MA; ++m) {
                const int px = p0 + pxh*(BM/2) + m*16 + lr;
                const int pad = GP + px + (px>>5);
                ushort4 e;
                e.x=f2bf(elu_f(acc[f][m][0]+bb.x));
                e.y=f2bf(elu_f(acc[f][m][1]+bb.y));
                e.z=f2bf(elu_f(acc[f][m][2]+bb.z));
                e.w=f2bf(elu_f(acc[f][m][3]+bb.w));
                *(ushort4*)(out0 + ((size_t)b*PB + pad)*128 + c) = e;
            }
        }
    }
}

// ---------------------------------------------------------------------------
// qkv bf16 MFMA GEMM: M=160 (padded 192), K=128. Input = padded bf16 state Sb.
// ---------------------------------------------------------------------------
__global__ __launch_bounds__(256)
void qkvm(const u16* __restrict__ Wq, const float* __restrict__ qkvw,
          const float* __restrict__ bias, const u16* __restrict__ Sb,
          u16* __restrict__ qo, u16* __restrict__ ko, u16* __restrict__ vo)
{
    __shared__ u16 As[2][64*40];
    __shared__ u16 Bs[2][192*40];
    const int tid = threadIdx.x;
    const int b = blockIdx.z, p0 = blockIdx.x*64;
    const int wv = tid>>6, lane = tid&63, lr = lane&15, lg = lane>>4;
    const int pxh = wv&1, chh = wv>>1;
    const u16* ab = Sb + (size_t)b*PB*128;
    const int arow = tid>>2, ag = tid&3;
    const int apx0 = p0 + arow;
    const int apx = GP + apx0 + (apx0>>5);
    int brow[3], bg[3];
    #pragma unroll
    for (int c=0;c<3;++c){ const int ci=tid+c*256; brow[c]=ci>>2; bg[c]=ci&3; }
    uint4 ra, rb[3];
    f32x4 acc[6][2] = {};
    auto GL = [&](int ks){
        const int k0 = ks*32;
        ra = *(const uint4*)(ab + (size_t)apx*128 + k0 + ag*8);
        #pragma unroll
        for (int c=0;c<3;++c)
            rb[c] = *(const uint4*)(Wq + (size_t)brow[c]*128 + k0 + bg[c]*8);
    };
    auto ST = [&](int buf){
        *(uint4*)&As[buf][arow*40 + ag*8] = ra;
        #pragma unroll
        for (int c=0;c<3;++c)
            *(uint4*)&Bs[buf][brow[c]*40 + bg[c]*8] = rb[c];
    };
    GL(0); ST(0); __syncthreads();
    for (int ks=0; ks<4; ++ks) {
        const int cur = ks&1;
        if (ks < 3) GL(ks+1);
        short8v wf[6], pf[2];
        #pragma unroll
        for (int f=0;f<6;++f)
            wf[f] = *(const short8v*)&Bs[cur][(chh*96 + f*16 + lr)*40 + lg*8];
        #pragma unroll
        for (int m=0;m<2;++m)
            pf[m] = *(const short8v*)&As[cur][(pxh*32 + m*16 + lr)*40 + lg*8];
        #pragma unroll
        for (int f=0;f<6;++f)
            #pragma unroll
            for (int m=0;m<2;++m)
                acc[f][m] = __builtin_amdgcn_mfma_f32_16x16x32_bf16(wf[f], pf[m], acc[f][m],0,0,0);
        __syncthreads();
        if (ks < 3) { ST((ks+1)&1); __syncthreads(); }
    }
    #pragma unroll
    for (int f=0; f<6; ++f) {
        const int row0 = chh*96 + f*16;
        if (row0 >= 160) continue;
        #pragma unroll
        for (int m=0;m<2;++m) {
            const int px = p0 + pxh*32 + m*16 + lr;
            const float pyv = (float)(px>>5)*0.03125f - 0.5f;
            const float pxv = (float)(px&31)*0.03125f - 0.5f;
            #pragma unroll
            for (int r=0;r<4;++r) {
                const int mm = row0 + lg*4 + r;
                const float val = acc[f][m][r] + bias[mm]
                                + qkvw[(size_t)mm*130 + 128]*pyv
                                + qkvw[(size_t)mm*130 + 129]*pxv;
                if (mm < 16)      qo[((size_t)b*HW+px)*16 + mm]        = f2bf(0.25f*val);
                else if (mm < 32) ko[((size_t)b*HW+px)*16 + (mm-16)]   = f2bf(val);
                else              vo[((size_t)b*128 + (mm-32))*HW + px] = f2bf(val);
            }
        }
    }
}

// ---------------------------------------------------------------------------
// MFMA causal attention (r7-proven), 4 waves: 2 q-tiles x 2 d-halves.
// ---------------------------------------------------------------------------
__global__ __launch_bounds__(256)
void attn_mfma(const u16* __restrict__ qb, const u16* __restrict__ kb,
               const u16* __restrict__ vb, u16* __restrict__ ob)
{
    __shared__ u16 ks_[2][32*24];
    __shared__ u16 vs_[2][128*40];
    const int tid = threadIdx.x;
    const int bid = blockIdx.x;              // 0..511
    const int tp  = 15 - (bid >> 5);         // tile-pair, long first
    const int b   = bid & 31;
    const int wv = tid>>6, lane = tid&63;
    const int lq = lane&31, hf = lane>>5;
    const int qt = tp*2 + (wv&1);
    const int dh = wv>>1;
    const int q0 = qt*32;
    const int NC = tp*2 + 2;

    const short8v Qf = *(const short8v*)(qb + ((size_t)b*HW + q0 + lq)*16 + hf*8);
    f32x16 acc[2] = {{},{}};
    float mrun = -1e30f, lrun = 0.f;
    unsigned diagm = 0;
    #pragma unroll
    for (int r=0; r<16; ++r) {
        const int row = (r&3) + 8*(r>>2) + 4*hf;
        diagm |= (row <= lq) ? (1u<<r) : 0u;
    }
    const f32x16 zc = {};

    const int vrow = tid>>2, vg = tid&3;
    const int krow = tid>>1, kg = tid&1;
    const u16* vbb = vb + (size_t)b*128*HW;
    const u16* kbb = kb + (size_t)b*HW*16;
    uint4 rv0A, rv1A, rkA, rv0B, rv1B, rkB;

#define AGLD(c, RV0, RV1, RK) do {                                             \
    const int kv0_ = (c)*32;                                                   \
    RV0 = *(const uint4*)(vbb + (size_t)vrow*HW + kv0_ + vg*8);                \
    RV1 = *(const uint4*)(vbb + (size_t)(64+vrow)*HW + kv0_ + vg*8);           \
    if (tid < 64) RK = *(const uint4*)(kbb + (size_t)(kv0_ + krow)*16 + kg*8); \
} while(0)
#define ASST(buf, RV0, RV1, RK) do {                                           \
    *(uint4*)&vs_[buf][vrow*40 + vg*8] = RV0;                                  \
    *(uint4*)&vs_[buf][(64+vrow)*40 + vg*8] = RV1;                             \
    if (tid < 64) *(uint4*)&ks_[buf][krow*24 + kg*8] = RK;                     \
} while(0)

    auto CHUNK = [&](int buf, int cc) {
        if (cc > qt) return;
        const short8v Kf = *(const short8v*)&ks_[buf][lq*24 + hf*8];
        f32x16 st = __builtin_amdgcn_mfma_f32_32x32x16_bf16(Kf, Qf, zc, 0,0,0);
        if (cc == qt) {
            #pragma unroll
            for (int r=0;r<16;++r) st[r] = ((diagm>>r)&1) ? st[r] : -1e30f;
        }
        float mc = st[0];
        #pragma unroll
        for (int r=1;r<16;++r) mc = fmaxf(mc, st[r]);
        mc = fmaxf(mc, __shfl_xor(mc, 32));
        if (!__all(mc <= mrun)) {
            const float mnew = fmaxf(mrun, mc);
            const float corr = __expf(mrun - mnew);
            lrun *= corr;
            #pragma unroll
            for (int f=0;f<2;++f)
                #pragma unroll
                for (int r=0;r<16;++r) acc[f][r] *= corr;
            mrun = mnew;
        }
        float ps[16]; float lsum = 0.f;
        #pragma unroll
        for (int r=0;r<16;++r){ ps[r]=__expf(st[r]-mrun); lsum += ps[r]; }
        lrun += lsum + __shfl_xor(lsum, 32);
        unsigned pk[8], sw[8];
        #pragma unroll
        for (int i=0;i<8;++i)
            pk[i] = (unsigned)f2bf(ps[2*i]) | ((unsigned)f2bf(ps[2*i+1])<<16);
        #pragma unroll
        for (int i=0;i<8;++i) sw[i] = __shfl_xor(pk[i], 32);
        union { unsigned u[4]; short8v v; } B1, B2;
        B1.u[0]=hf?sw[2]:pk[0]; B1.u[1]=hf?sw[3]:pk[1];
        B1.u[2]=hf?pk[2]:sw[0]; B1.u[3]=hf?pk[3]:sw[1];
        B2.u[0]=hf?sw[6]:pk[4]; B2.u[1]=hf?sw[7]:pk[5];
        B2.u[2]=hf?pk[6]:sw[4]; B2.u[3]=hf?pk[7]:sw[5];
        #pragma unroll
        for (int f=0;f<2;++f) {
            const int fg = dh*2 + f;
            const short8v A1 = *(const short8v*)&vs_[buf][(fg*32+lq)*40 + hf*8];
            const short8v A2 = *(const short8v*)&vs_[buf][(fg*32+lq)*40 + 16 + hf*8];
            acc[f] = __builtin_amdgcn_mfma_f32_32x32x16_bf16(A1, B1.v, acc[f],0,0,0);
            acc[f] = __builtin_amdgcn_mfma_f32_32x32x16_bf16(A2, B2.v, acc[f],0,0,0);
        }
    };

    AGLD(0, rv0A, rv1A, rkA); ASST(0, rv0A, rv1A, rkA);
    AGLD(1, rv0B, rv1B, rkB);
    __syncthreads();
    for (int c = 0; c < NC; c += 2) {
        CHUNK(0, c);
        ASST(1, rv0B, rv1B, rkB);
        if (c+2 < NC) AGLD(c+2, rv0A, rv1A, rkA);
        __syncthreads();
        CHUNK(1, c+1);
        if (c+2 < NC) {
            ASST(0, rv0A, rv1A, rkA);
            if (c+3 < NC) AGLD(c+3, rv0B, rv1B, rkB);
        }
        __syncthreads();
    }
#undef AGLD
#undef ASST

    const float inv = 1.f / lrun;
    u16* orow = ob + ((size_t)b*HW + q0 + lq)*128;
    #pragma unroll
    for (int f=0; f<2; ++f) {
        #pragma unroll
        for (int g=0; g<4; ++g) {
            const int d0 = (dh*2+f)*32 + 8*g + 4*hf;
            ushort4 o4;
            o4.x = f2bf(acc[f][g*4+0]*inv);
            o4.y = f2bf(acc[f][g*4+1]*inv);
            o4.z = f2bf(acc[f][g*4+2]*inv);
            o4.w = f2bf(acc[f][g*4+3]*inv);
            *(ushort4*)(orow + d0) = o4;
        }
    }
}

// ---------------------------------------------------------------------------
// Fused head: 4 chained K=128 GEMMs per 64-px block, intermediates in LDS.
//   g0: X0 = bf16(elu(W_ap·ob + b_ap))          (= elu(attn_out))
//   g1: X1 = bf16(elu(W_oc·Eb + b_oc))          (= elu(c1))
//   g2: X0 = bf16(elu(X1 + elu(W_oa·X0 + b_oa)))(= elu(c1+a1))
//   g3: out = elu(W_op·X0 + b_op) + x           (f32, channel-major)
// ---------------------------------------------------------------------------
#define HZERO() do{ _Pragma("unroll") for(int f=0;f<4;++f){ _Pragma("unroll") for(int m=0;m<2;++m){ acc[f][m][0]=0.f; acc[f][m][1]=0.f; acc[f][m][2]=0.f; acc[f][m][3]=0.f; } } }while(0)

#define HGEMM_GLOB(ASRC, WG) do{                                                 \
    uint4 ra_, rb_[2];                                                           \
    ra_ = *(const uint4*)((ASRC));                                               \
    rb_[0] = *(const uint4*)((WG) + (size_t)brow[0]*128 + bg[0]*8);              \
    rb_[1] = *(const uint4*)((WG) + (size_t)brow[1]*128 + bg[1]*8);              \
    *(uint4*)&As[0][arow*40+ag*8]=ra_;                                           \
    *(uint4*)&Ws[0][brow[0]*40+bg[0]*8]=rb_[0];                                  \
    *(uint4*)&Ws[0][brow[1]*40+bg[1]*8]=rb_[1];                                  \
    __syncthreads();                                                             \
    _Pragma("unroll")                                                            \
    for(int s=0;s<4;++s){                                                        \
        const int cur=s&1;                                                       \
        if(s<3){ const int k1=(s+1)*32;                                          \
            ra_ = *(const uint4*)((ASRC) + k1);                                  \
            rb_[0]=*(const uint4*)((WG)+(size_t)brow[0]*128+k1+bg[0]*8);         \
            rb_[1]=*(const uint4*)((WG)+(size_t)brow[1]*128+k1+bg[1]*8); }       \
        short8v wf_[4], pf_[2];                                                  \
        _Pragma("unroll") for(int f=0;f<4;++f)                                   \
            wf_[f]=*(const short8v*)&Ws[cur][(chh*64+f*16+lr)*40+lg*8];          \
        _Pragma("unroll") for(int m=0;m<2;++m)                                   \
            pf_[m]=*(const short8v*)&As[cur][(pxh*32+m*16+lr)*40+lg*8];          \
        _Pragma("unroll") for(int f=0;f<4;++f)                                   \
            _Pragma("unroll") for(int m=0;m<2;++m)                               \
                acc[f][m]=__builtin_amdgcn_mfma_f32_16x16x32_bf16(wf_[f],pf_[m],acc[f][m],0,0,0); \
        __syncthreads();                                                         \
        if(s<3){ const int nb=(s+1)&1;                                           \
            *(uint4*)&As[nb][arow*40+ag*8]=ra_;                                  \
            *(uint4*)&Ws[nb][brow[0]*40+bg[0]*8]=rb_[0];                         \
            *(uint4*)&Ws[nb][brow[1]*40+bg[1]*8]=rb_[1];                         \
            __syncthreads(); }                                                   \
    }                                                                            \
}while(0)

#define HGEMM_XB(XB, WG) do{                                                     \
    uint4 rb_[2];                                                                \
    rb_[0] = *(const uint4*)((WG) + (size_t)brow[0]*128 + bg[0]*8);              \
    rb_[1] = *(const uint4*)((WG) + (size_t)brow[1]*128 + bg[1]*8);              \
    *(uint4*)&Ws[0][brow[0]*40+bg[0]*8]=rb_[0];                                  \
    *(uint4*)&Ws[0][brow[1]*40+bg[1]*8]=rb_[1];                                  \
    __syncthreads();                                                             \
    _Pragma("unroll")                                                            \
    for(int s=0;s<4;++s){                                                        \
        const int cur=s&1;                                                       \
        if(s<3){ const int k1=(s+1)*32;                                          \
            rb_[0]=*(const uint4*)((WG)+(size_t)brow[0]*128+k1+bg[0]*8);         \
            rb_[1]=*(const uint4*)((WG)+(size_t)brow[1]*128+k1+bg[1]*8); }       \
        short8v wf_[4], pf_[2];                                                  \
        _Pragma("unroll") for(int f=0;f<4;++f)                                   \
            wf_[f]=*(const short8v*)&Ws[cur][(chh*64+f*16+lr)*40+lg*8];          \
        _Pragma("unroll") for(int m=0;m<2;++m)                                   \
            pf_[m]=*(const short8v*)&(XB)[(pxh*32+m*16+lr)*136 + s*32 + lg*8];   \
        _Pragma("unroll") for(int f=0;f<4;++f)                                   \
            _Pragma("unroll") for(int m=0;m<2;++m)                               \
                acc[f][m]=__builtin_amdgcn_mfma_f32_16x16x32_bf16(wf_[f],pf_[m],acc[f][m],0,0,0); \
        __syncthreads();                                                         \
        if(s<3){ const int nb=(s+1)&1;                                           \
            *(uint4*)&Ws[nb][brow[0]*40+bg[0]*8]=rb_[0];                         \
            *(uint4*)&Ws[nb][brow[1]*40+bg[1]*8]=rb_[1];                         \
            __syncthreads(); }                                                   \
    }                                                                            \
}while(0)

__global__ __launch_bounds__(256)
void headk(const u16* __restrict__ wh,
           const float* __restrict__ apb, const float* __restrict__ ocb,
           const float* __restrict__ oab, const float* __restrict__ opb,
           const u16* __restrict__ ob, const u16* __restrict__ Eb,
           const float* __restrict__ x, float* __restrict__ out)
{
    __shared__ u16 As[2][64*40];
    __shared__ u16 Ws[2][128*40];
    __shared__ u16 X0[64*136];
    __shared__ u16 X1[64*136];
    const int tid = threadIdx.x;
    const int b = blockIdx.z, p0 = blockIdx.x*64;
    const int wv = tid>>6, lane = tid&63, lr = lane&15, lg = lane>>4;
    const int pxh = wv&1, chh = wv>>1;
    const int arow = tid>>2, ag = tid&3;
    const int apx0 = p0 + arow;
    const int apadEb = GP + apx0 + (apx0>>5);
    int brow[2], bg[2];
    #pragma unroll
    for (int c=0;c<2;++c){ const int ci=tid+c*256; brow[c]=ci>>2; bg[c]=ci&3; }
    f32x4 acc[4][2];

    const u16* asrc0 = ob + ((size_t)b*HW + apx0)*128 + ag*8;
    const u16* asrc1 = Eb + ((size_t)b*PB + apadEb)*128 + ag*8;

    // ---- g0: attn_proj -> X0 = elu ----
    HZERO();
    HGEMM_GLOB(asrc0, wh);
    #pragma unroll
    for (int f=0; f<4; ++f) {
        const int c = chh*64 + f*16 + lg*4;
        const float4 bb = *(const float4*)(apb + c);
        #pragma unroll
        for (int m=0;m<2;++m) {
            const int rowl = pxh*32 + m*16 + lr;
            ushort4 e;
            e.x=f2bf(elu_f(acc[f][m][0]+bb.x)); e.y=f2bf(elu_f(acc[f][m][1]+bb.y));
            e.z=f2bf(elu_f(acc[f][m][2]+bb.z)); e.w=f2bf(elu_f(acc[f][m][3]+bb.w));
            *(ushort4*)&X0[rowl*136 + c] = e;
        }
    }
    __syncthreads();

    // ---- g1: out_conv -> X1 = elu(c1) ----
    HZERO();
    HGEMM_GLOB(asrc1, wh + 16384);
    #pragma unroll
    for (int f=0; f<4; ++f) {
        const int c = chh*64 + f*16 + lg*4;
        const float4 bb = *(const float4*)(ocb + c);
        #pragma unroll
        for (int m=0;m<2;++m) {
            const int rowl = pxh*32 + m*16 + lr;
            ushort4 e;
            e.x=f2bf(elu_f(acc[f][m][0]+bb.x)); e.y=f2bf(elu_f(acc[f][m][1]+bb.y));
            e.z=f2bf(elu_f(acc[f][m][2]+bb.z)); e.w=f2bf(elu_f(acc[f][m][3]+bb.w));
            *(ushort4*)&X1[rowl*136 + c] = e;
        }
    }
    __syncthreads();

    // ---- g2: out_attn, Es = elu(c1 + a1) -> X0 ----
    HZERO();
    HGEMM_XB(X0, wh + 32768);
    #pragma unroll
    for (int f=0; f<4; ++f) {
        const int c = chh*64 + f*16 + lg*4;
        const float4 bb = *(const float4*)(oab + c);
        #pragma unroll
        for (int m=0;m<2;++m) {
            const int rowl = pxh*32 + m*16 + lr;
            const ushort4 c4 = *(const ushort4*)&X1[rowl*136 + c];
            ushort4 e;
            e.x = f2bf(elu_f(bf2f(c4.x) + elu_f(acc[f][m][0]+bb.x)));
            e.y = f2bf(elu_f(bf2f(c4.y) + elu_f(acc[f][m][1]+bb.y)));
            e.z = f2bf(elu_f(bf2f(c4.z) + elu_f(acc[f][m][2]+bb.z)));
            e.w = f2bf(elu_f(bf2f(c4.w) + elu_f(acc[f][m][3]+bb.w)));
            *(ushort4*)&X0[rowl*136 + c] = e;
        }
    }
    __syncthreads();

    // ---- g3: out_proj -> out = elu + x (f32 channel-major) ----
    HZERO();
    HGEMM_XB(X0, wh + 49152);
    #pragma unroll
    for (int f=0; f<4; ++f) {
        const int c = chh*64 + f*16 + lg*4;
        const float* bp = opb + c;
        #pragma unroll
        for (int m=0;m<2;++m) {
            const int px = p0 + pxh*32 + m*16 + lr;
            #pragma unroll
            for (int r=0;r<4;++r) {
                const size_t o = ((size_t)b*128 + c + r)*HW + px;
                out[o] = elu_f(acc[f][m][r] + bp[r]) + x[o];
            }
        }
    }
}

extern "C" void kernel_launch(void* const* d_in, const int* in_sizes, int n_in,
                              void* d_out, int out_size, void* d_ws, size_t ws_size,
                              hipStream_t stream) {
    const float* x    = (const float*)d_in[0];
    const float* rw1  = (const float*)d_in[1];
    const float* rb1  = (const float*)d_in[2];
    const float* rw2  = (const float*)d_in[3];
    const float* rb2  = (const float*)d_in[4];
    const float* qkvw = (const float*)d_in[5];
    const float* qkvb = (const float*)d_in[6];
    const float* apw  = (const float*)d_in[7];
    const float* apb  = (const float*)d_in[8];
    const float* ocw  = (const float*)d_in[9];
    const float* ocb  = (const float*)d_in[10];
    const float* oaw  = (const float*)d_in[11];
    const float* oab  = (const float*)d_in[12];
    const float* opw  = (const float*)d_in[13];
    const float* opb  = (const float*)d_in[14];
    float* out = (float*)d_out;
    float* ws = (float*)d_ws;

    // Workspace (float offsets, all within 16M floats = 64 MiB):
    u16* Sb  = (u16*)ws;                     // padded bf16 state (B,PB,128)
    u16* Eb  = (u16*)(ws + 2293760);         // padded bf16(elu(state))
    u16* E2  = (u16*)(ws + 4587520);         // padded conv1 out
    u16* ob  = (u16*)(ws + 6881280);         // (B,HW,128) attn out
    u16* qb  = (u16*)(ws + 8978432);
    u16* kb  = (u16*)(ws + 9240576);
    u16* vb  = (u16*)(ws + 9502720);         // V^T (B,128,HW)
    u16* w1b = (u16*)(ws + 11599872);        // 6*128*512
    u16* w2b = (u16*)(ws + 11796480);        // 6*256*512
    u16* wh  = (u16*)(ws + 12189696);        // 4*128*128
    u16* qw  = (u16*)(ws + 12222464);        // 192*128

    dim3 blk(256);
    wconv<<<4960, blk, 0, stream>>>(rw1, rw2, apw, ocw, oaw, opw, qkvw, w1b, w2b, wh, qw);
    gz<<<384, blk, 0, stream>>>(Eb, E2);
    init_k<<<dim3(32, 32), blk, 0, stream>>>(x, Sb, Eb);
    for (int i = 0; i < 6; ++i) {
        convg<32,0><<<dim3(32,1,32), blk, 0, stream>>>(
            w1b + (size_t)i*65536, rb1 + i*128, Eb, E2, nullptr);
        convg<128,1><<<dim3(8,2,32), blk, 0, stream>>>(
            w2b + (size_t)i*131072, rb2 + i*256, E2, Eb, Sb);
    }
    qkvm<<<dim3(16,1,32), blk, 0, stream>>>(qw, qkvw, qkvb, Sb, qb, kb, vb);
    attn_mfma<<<512, blk, 0, stream>>>(qb, kb, vb, ob);
    headk<<<dim3(16,1,32), blk, 0, stream>>>(wh, apb, ocb, oab, opb, ob, Eb, x, out);
}

// Round 9
// 278.760 us; speedup vs baseline: 2.0061x; 1.0277x over previous
//
#include <hip/hip_runtime.h>
#include <math.h>

#define HW 1024
#define RS 33            // padded row stride (32 px + 1 zero col)
#define GP 34            // zero guard pixels before each image
#define PB 1120          // padded pixels per batch image

typedef unsigned short u16;
typedef __attribute__((ext_vector_type(8))) short short8v;   // 8 bf16
typedef __attribute__((ext_vector_type(4))) float f32x4;
typedef __attribute__((ext_vector_type(16))) float f32x16;

__device__ __forceinline__ float elu_f(float x){ return x>0.f? x : (__expf(x)-1.f); }
__device__ __forceinline__ float sig_f(float x){ return 1.f/(1.f+__expf(-x)); }
__device__ __forceinline__ u16 f2bf(float f){ unsigned u=__float_as_uint(f); return (u16)((u + 0x7fffu + ((u>>16)&1u))>>16); }
__device__ __forceinline__ float bf2f(u16 h){ return __uint_as_float(((unsigned)h)<<16); }

__device__ __forceinline__ void gld16(const void* g, void* l) {
    __builtin_amdgcn_global_load_lds(
        (const __attribute__((address_space(1))) void*)g,
        (__attribute__((address_space(3))) void*)l, 16, 0, 0);
}

// ---------------------------------------------------------------------------
// Merged one-time weight convert. All GEMM weights get the BK64 granule-XOR
// swizzle baked in (stored slot s of row r holds granule g = s^(r&7)).
// Conv weights tap-major K; conv2 additionally pre-interleaved to gate order.
// ---------------------------------------------------------------------------
__global__ __launch_bounds__(256)
void wconv(const float* __restrict__ rw1, const float* __restrict__ rw2,
           const float* __restrict__ apw, const float* __restrict__ ocw,
           const float* __restrict__ oaw, const float* __restrict__ opw,
           const float* __restrict__ qkvw,
           u16* __restrict__ w1b, u16* __restrict__ w2b,
           u16* __restrict__ whs, u16* __restrict__ qws)
{
    const int i = blockIdx.x*256 + threadIdx.x;
    if (i < 393216) {                       // conv1 weights: 6*128*512
        const int layer = i >> 16;
        const int r = (i >> 9) & 127;
        const int k = i & 511;
        const int ks = k >> 6, s = (k >> 3) & 7, j = k & 7;
        const int g = s ^ (r & 7);
        const int tap = ks >> 1;
        const int c = ((ks & 1) << 6) + g*8 + j;
        w1b[i] = f2bf(rw1[(size_t)layer*65536 + r*512 + c*4 + tap]);
    } else if (i < 1179648) {               // conv2 weights: 6*256*512
        const int ii = i - 393216;
        const int layer = ii >> 17;
        const int R = (ii >> 9) & 255;
        const int k = ii & 511;
        const int by = R >> 7, r = R & 127;
        const int h = (r >> 6) & 1, f2 = (r >> 4) & 3, rr = r & 15;
        const int ch = (f2 < 2) ? (by*64 + h*32 + f2*16 + rr)
                                : (128 + by*64 + h*32 + (f2-2)*16 + rr);
        const int ks = k >> 6, s = (k >> 3) & 7, j = k & 7;
        const int g = s ^ (R & 7);
        const int tap = ks >> 1;
        const int c = ((ks & 1) << 6) + g*8 + j;
        w2b[ii] = f2bf(rw2[(size_t)layer*131072 + ch*512 + c*4 + tap]);
    } else if (i < 1245184) {               // head 1x1 weights: 4*128*128, swizzled
        const int ii = i - 1179648;
        const int m = ii >> 14;
        const int rem = ii & 16383;
        const int r = rem >> 7, k = rem & 127;
        const int ks = k >> 6, s = (k >> 3) & 7, j = k & 7;
        const int g = s ^ (r & 7);
        const int c = (ks << 6) + g*8 + j;
        const float* src = (m==0)? apw : (m==1)? ocw : (m==2)? oaw : opw;
        whs[ii] = f2bf(src[r*128 + c]);
    } else if (i < 1269760) {               // qkv weights padded to 192 rows, swizzled
        const int ii = i - 1245184;
        const int r = ii >> 7, k = ii & 127;
        const int ks = k >> 6, s = (k >> 3) & 7, j = k & 7;
        const int g = s ^ (r & 7);
        const int c = (ks << 6) + g*8 + j;
        qws[ii] = (r < 160) ? f2bf(qkvw[(size_t)r*130 + c]) : (u16)0;
    }
}

// Zero the 96 guard slots per batch image in Eb and E2 (1.6 MB total).
__global__ __launch_bounds__(256)
void gz(u16* __restrict__ Eb, u16* __restrict__ E2)
{
    const int half = blockIdx.x / 192;
    const int idx = (blockIdx.x % 192)*256 + threadIdx.x;   // 0..49151
    const int b = idx / 1536;
    const int rem = idx % 1536;
    const int g = rem >> 4, c8 = rem & 15;
    const int slot = (g < 34) ? g : (g < 65) ? (66 + 33*(g-34)) : (1089 + (g-65));
    u16* dst = (half ? E2 : Eb) + ((size_t)b*PB + slot)*128 + c8*8;
    uint4 z; z.x=0u; z.y=0u; z.z=0u; z.w=0u;
    *(uint4*)dst = z;
}

// ---------------------------------------------------------------------------
// init: x (B,128,HW) f32 -> Sb (B,PB,128) bf16 state + Eb bf16(elu(x)) padded
// ---------------------------------------------------------------------------
__global__ __launch_bounds__(256)
void init_k(const float* __restrict__ x, u16* __restrict__ Sb, u16* __restrict__ Eb)
{
    __shared__ float t[32][132];
    const int b = blockIdx.y, p0 = blockIdx.x*32;
    const int tid = threadIdx.x;
    const int cr = tid >> 3, p4 = (tid & 7)*4;
    #pragma unroll
    for (int cc = 0; cc < 128; cc += 32) {
        const float4 v = *(const float4*)(x + ((size_t)b*128 + cc + cr)*HW + p0 + p4);
        t[p4+0][cc+cr]=v.x; t[p4+1][cc+cr]=v.y; t[p4+2][cc+cr]=v.z; t[p4+3][cc+cr]=v.w;
    }
    __syncthreads();
    const int pr = tid >> 3, c4 = (tid & 7)*4;
    const int px = p0 + pr;
    const int pad = GP + px + (px>>5);
    #pragma unroll
    for (int cc = 0; cc < 128; cc += 32) {
        const int c = cc + c4;
        float4 v; v.x=t[pr][c]; v.y=t[pr][c+1]; v.z=t[pr][c+2]; v.w=t[pr][c+3];
        ushort4 s4;
        s4.x=f2bf(v.x); s4.y=f2bf(v.y); s4.z=f2bf(v.z); s4.w=f2bf(v.w);
        *(ushort4*)(Sb + ((size_t)b*PB + pad)*128 + c) = s4;
        ushort4 e;
        e.x=f2bf(elu_f(v.x)); e.y=f2bf(elu_f(v.y)); e.z=f2bf(elu_f(v.z)); e.w=f2bf(elu_f(v.w));
        *(ushort4*)(Eb + ((size_t)b*PB + pad)*128 + c) = e;
    }
}

// ---------------------------------------------------------------------------
// global_load_lds conv2x2 GEMM (r7/r8-proven structure).
// EPI 0: out0 = bf16(elu(acc+bias)) padded                          (conv1)
// EPI 1: gate: o = Sio + t1*sig(t2); Sio=bf16(o); out0=bf16(elu(o)) (conv2)
// ---------------------------------------------------------------------------
#define GSTAGE(ks, buf) do {                                                     \
    const int tap_ = (ks) >> 1;                                                  \
    const int off_ = (tap_>>1)*RS + (tap_&1) - RS - 1;                           \
    const int c0_  = ((ks) & 1) << 6;                                            \
    _Pragma("unroll")                                                            \
    for (int ca_=0; ca_<NCALLA; ++ca_) {                                         \
        const int row_ = ca_*32 + wv*8 + (lane>>3);                              \
        const int px_  = p0 + row_;                                              \
        const int pad_ = GP + px_ + (px_>>5);                                    \
        const int g_   = (lane&7) ^ (lane>>3);                                   \
        gld16(ebB + (size_t)(pad_ + off_)*128 + c0_ + g_*8,                      \
              (char*)As[buf] + (ca_*32 + wv*8)*128 + lane*16);                   \
    }                                                                            \
    _Pragma("unroll")                                                            \
    for (int cb_=0; cb_<4; ++cb_) {                                              \
        const int row_ = cb_*32 + wv*8 + (lane>>3);                              \
        gld16(wbB + (size_t)row_*512 + (ks)*64 + (lane&7)*8,                     \
              (char*)Bs[buf] + (cb_*32 + wv*8)*128 + lane*16);                   \
    }                                                                            \
} while(0)

#define GCOMP(buf) do {                                                          \
    _Pragma("unroll")                                                            \
    for (int k2_=0; k2_<2; ++k2_) {                                              \
        short8v wf_[4], pf_[MA];                                                 \
        const int sl_ = ((k2_*4 + lg) ^ (lr & 7)) * 8;                           \
        _Pragma("unroll")                                                        \
        for (int f_=0; f_<4; ++f_)                                               \
            wf_[f_] = *(const short8v*)&Bs[buf][(chh*64 + f_*16 + lr)*64 + sl_]; \
        _Pragma("unroll")                                                        \
        for (int m_=0; m_<MA; ++m_)                                              \
            pf_[m_] = *(const short8v*)&As[buf][(pxh*(BM/2) + m_*16 + lr)*64 + sl_]; \
        _Pragma("unroll")                                                        \
        for (int f_=0; f_<4; ++f_)                                               \
            _Pragma("unroll")                                                    \
            for (int m_=0; m_<MA; ++m_)                                          \
                acc[f_][m_] = __builtin_amdgcn_mfma_f32_16x16x32_bf16(wf_[f_], pf_[m_], acc[f_][m_],0,0,0); \
    }                                                                            \
} while(0)

template<int BM, int EPI>
__global__ __launch_bounds__(256)
void convg(const u16* __restrict__ Wb, const float* __restrict__ bias,
           const u16* __restrict__ Ein, u16* __restrict__ out0,
           u16* __restrict__ Sio)
{
    constexpr int NS = 8;              // K=512, BK=64
    constexpr int MA = BM/32;
    constexpr int NCALLA = BM/32;
    __shared__ u16 As[2][BM*64];
    __shared__ u16 Bs[2][128*64];
    const int tid = threadIdx.x;
    const int b = blockIdx.z, p0 = blockIdx.x*BM, cb0 = blockIdx.y*64;
    const int wv = tid>>6, lane = tid&63, lr = lane&15, lg = lane>>4;
    const int pxh = wv&1, chh = wv>>1;
    const u16* ebB = Ein + (size_t)b*PB*128;
    const u16* wbB = Wb + (size_t)blockIdx.y*128*512;
    f32x4 acc[4][MA] = {};

    GSTAGE(0, 0);
    __syncthreads();
    #pragma unroll
    for (int ks = 0; ks < NS; ++ks) {
        if (ks + 1 < NS) GSTAGE(ks+1, (ks+1)&1);
        GCOMP(ks&1);
        __syncthreads();
    }

    if constexpr (EPI == 1) {
        #pragma unroll
        for (int f=0; f<2; ++f) {
            const int c = cb0 + chh*32 + f*16 + lg*4;
            const float4 b1 = *(const float4*)(bias + c);
            const float4 b2 = *(const float4*)(bias + 128 + c);
            #pragma unroll
            for (int m=0; m<MA; ++m) {
                const int px = p0 + pxh*(BM/2) + m*16 + lr;
                const int pad = GP + px + (px>>5);
                u16* sp = Sio + ((size_t)b*PB + pad)*128 + c;
                const ushort4 sv = *(const ushort4*)sp;
                const float o0 = bf2f(sv.x) + (acc[f][m][0]+b1.x)*sig_f(acc[f+2][m][0]+b2.x);
                const float o1 = bf2f(sv.y) + (acc[f][m][1]+b1.y)*sig_f(acc[f+2][m][1]+b2.y);
                const float o2 = bf2f(sv.z) + (acc[f][m][2]+b1.z)*sig_f(acc[f+2][m][2]+b2.z);
                const float o3 = bf2f(sv.w) + (acc[f][m][3]+b1.w)*sig_f(acc[f+2][m][3]+b2.w);
                ushort4 so;
                so.x=f2bf(o0); so.y=f2bf(o1); so.z=f2bf(o2); so.w=f2bf(o3);
                *(ushort4*)sp = so;
                ushort4 e;
                e.x=f2bf(elu_f(o0)); e.y=f2bf(elu_f(o1)); e.z=f2bf(elu_f(o2)); e.w=f2bf(elu_f(o3));
                *(ushort4*)(out0 + ((size_t)b*PB + pad)*128 + c) = e;
            }
        }
    } else {
        #pragma unroll
        for (int f=0; f<4; ++f) {
            const int c = chh*64 + f*16 + lg*4;
            const float4 bb = *(const float4*)(bias + c);
            #pragma unroll
            for (int m=0; m<MA; ++m) {
                const int px = p0 + pxh*(BM/2) + m*16 + lr;
                const int pad = GP + px + (px>>5);
                ushort4 e;
                e.x=f2bf(elu_f(acc[f][m][0]+bb.x));
                e.y=f2bf(elu_f(acc[f][m][1]+bb.y));
                e.z=f2bf(elu_f(acc[f][m][2]+bb.z));
                e.w=f2bf(elu_f(acc[f][m][3]+bb.w));
                *(ushort4*)(out0 + ((size_t)b*PB + pad)*128 + c) = e;
            }
        }
    }
}

// ---------------------------------------------------------------------------
// Head 1x1 GEMM, gload_lds BK=64, NS=2, dbuf, 2 barriers total. BM=64.
// EPI 0 (DUAL): by=0: dst0 = bf16(elu(W0·in0 + bias0))   (attn_proj, unpadded in)
//               by=1: dst1 = bf16(elu(W1·in1 + bias1))   (out_conv, padded in)
// EPI 2: dst0 = bf16(elu( aux + elu(acc+bias0) ))        (out_attn + add c1)
// EPI 3: fout[ch-major] = elu(acc+bias0) + xres          (out_proj, f32)
// ---------------------------------------------------------------------------
template<int EPI, int DUAL>
__global__ __launch_bounds__(256)
void headg(const u16* __restrict__ Wh,
           const float* __restrict__ bias0, const float* __restrict__ bias1,
           const u16* __restrict__ in0, const u16* __restrict__ in1,
           u16* __restrict__ dst0, u16* __restrict__ dst1,
           const u16* __restrict__ aux, const float* __restrict__ xres,
           float* __restrict__ fout)
{
    __shared__ u16 As[2][64*64];
    __shared__ u16 Bs[2][128*64];
    const int tid = threadIdx.x;
    const int b = blockIdx.z, p0 = blockIdx.x*64;
    const int by = DUAL ? (int)blockIdx.y : 0;
    const int wv = tid>>6, lane = tid&63, lr = lane&15, lg = lane>>4;
    const int pxh = wv&1, chh = wv>>1;
    const u16* wsrcB = Wh + (size_t)by*16384;
    const float* bias = (DUAL && by) ? bias1 : bias0;
    const u16* inB = (DUAL && by) ? in1 : in0;
    f32x4 acc[4][2] = {};

    auto HSTAGE = [&](int ks, int buf) {
        #pragma unroll
        for (int ca=0; ca<2; ++ca) {
            const int row = ca*32 + wv*8 + (lane>>3);
            const int px = p0 + row;
            size_t aoff;
            if (DUAL && by) aoff = (size_t)b*PB + (GP + px + (px>>5));
            else            aoff = (size_t)b*HW + px;
            const int g = (lane&7) ^ (lane>>3);
            gld16(inB + aoff*128 + ks*64 + g*8,
                  (char*)As[buf] + (ca*32 + wv*8)*128 + lane*16);
        }
        #pragma unroll
        for (int cb=0; cb<4; ++cb) {
            const int row = cb*32 + wv*8 + (lane>>3);
            gld16(wsrcB + (size_t)row*128 + ks*64 + (lane&7)*8,
                  (char*)Bs[buf] + (cb*32 + wv*8)*128 + lane*16);
        }
    };
    auto HCOMP = [&](int buf) {
        #pragma unroll
        for (int k2=0; k2<2; ++k2) {
            short8v wf[4], pf[2];
            const int sl = ((k2*4 + lg) ^ (lr & 7)) * 8;
            #pragma unroll
            for (int f=0; f<4; ++f)
                wf[f] = *(const short8v*)&Bs[buf][(chh*64 + f*16 + lr)*64 + sl];
            #pragma unroll
            for (int m=0; m<2; ++m)
                pf[m] = *(const short8v*)&As[buf][(pxh*32 + m*16 + lr)*64 + sl];
            #pragma unroll
            for (int f=0; f<4; ++f)
                #pragma unroll
                for (int m=0; m<2; ++m)
                    acc[f][m] = __builtin_amdgcn_mfma_f32_16x16x32_bf16(wf[f], pf[m], acc[f][m],0,0,0);
        }
    };

    HSTAGE(0, 0);
    __syncthreads();
    HSTAGE(1, 1);
    HCOMP(0);
    __syncthreads();
    HCOMP(1);

    #pragma unroll
    for (int f=0; f<4; ++f) {
        const int c = chh*64 + f*16 + lg*4;
        #pragma unroll
        for (int m=0; m<2; ++m) {
            const int px = p0 + pxh*32 + m*16 + lr;
            if constexpr (EPI == 3) {
                const float* bp = bias + c;
                #pragma unroll
                for (int r=0; r<4; ++r) {
                    const size_t o = ((size_t)b*128 + c + r)*HW + px;
                    fout[o] = elu_f(acc[f][m][r] + bp[r]) + xres[o];
                }
            } else {
                const float4 bb = *(const float4*)(bias + c);
                const float v0=acc[f][m][0]+bb.x, v1=acc[f][m][1]+bb.y;
                const float v2=acc[f][m][2]+bb.z, v3=acc[f][m][3]+bb.w;
                ushort4 e;
                if constexpr (EPI == 2) {
                    const ushort4 c4 = *(const ushort4*)(aux + ((size_t)b*HW+px)*128 + c);
                    e.x = f2bf(elu_f(bf2f(c4.x) + elu_f(v0)));
                    e.y = f2bf(elu_f(bf2f(c4.y) + elu_f(v1)));
                    e.z = f2bf(elu_f(bf2f(c4.z) + elu_f(v2)));
                    e.w = f2bf(elu_f(bf2f(c4.w) + elu_f(v3)));
                } else {
                    e.x=f2bf(elu_f(v0)); e.y=f2bf(elu_f(v1));
                    e.z=f2bf(elu_f(v2)); e.w=f2bf(elu_f(v3));
                }
                u16* dst = (DUAL && by) ? dst1 : dst0;
                *(ushort4*)(dst + ((size_t)b*HW+px)*128 + c) = e;
            }
        }
    }
}

// ---------------------------------------------------------------------------
// qkv GEMM, gload_lds BK=64, NS=2, NOUT=192 (padded). Input padded bf16 Sb.
// ---------------------------------------------------------------------------
__global__ __launch_bounds__(256)
void qkvg(const u16* __restrict__ Wq, const float* __restrict__ qkvw,
          const float* __restrict__ bias, const u16* __restrict__ Sb,
          u16* __restrict__ qo, u16* __restrict__ ko, u16* __restrict__ vo)
{
    __shared__ u16 As[2][64*64];
    __shared__ u16 Bs[2][192*64];
    const int tid = threadIdx.x;
    const int b = blockIdx.z, p0 = blockIdx.x*64;
    const int wv = tid>>6, lane = tid&63, lr = lane&15, lg = lane>>4;
    const int pxh = wv&1, chh = wv>>1;
    const u16* ebB = Sb + (size_t)b*PB*128;
    f32x4 acc[6][2] = {};

    auto QSTAGE = [&](int ks, int buf) {
        #pragma unroll
        for (int ca=0; ca<2; ++ca) {
            const int row = ca*32 + wv*8 + (lane>>3);
            const int px = p0 + row;
            const int pad = GP + px + (px>>5);
            const int g = (lane&7) ^ (lane>>3);
            gld16(ebB + (size_t)pad*128 + ks*64 + g*8,
                  (char*)As[buf] + (ca*32 + wv*8)*128 + lane*16);
        }
        #pragma unroll
        for (int cb=0; cb<6; ++cb) {
            const int row = cb*32 + wv*8 + (lane>>3);
            gld16(Wq + (size_t)row*128 + ks*64 + (lane&7)*8,
                  (char*)Bs[buf] + (cb*32 + wv*8)*128 + lane*16);
        }
    };
    auto QCOMP = [&](int buf) {
        #pragma unroll
        for (int k2=0; k2<2; ++k2) {
            short8v wf[6], pf[2];
            const int sl = ((k2*4 + lg) ^ (lr & 7)) * 8;
            #pragma unroll
            for (int f=0; f<6; ++f)
                wf[f] = *(const short8v*)&Bs[buf][(chh*96 + f*16 + lr)*64 + sl];
            #pragma unroll
            for (int m=0; m<2; ++m)
                pf[m] = *(const short8v*)&As[buf][(pxh*32 + m*16 + lr)*64 + sl];
            #pragma unroll
            for (int f=0; f<6; ++f)
                #pragma unroll
                for (int m=0; m<2; ++m)
                    acc[f][m] = __builtin_amdgcn_mfma_f32_16x16x32_bf16(wf[f], pf[m], acc[f][m],0,0,0);
        }
    };

    QSTAGE(0, 0);
    __syncthreads();
    QSTAGE(1, 1);
    QCOMP(0);
    __syncthreads();
    QCOMP(1);

    #pragma unroll
    for (int f=0; f<6; ++f) {
        const int row0 = chh*96 + f*16;
        if (row0 >= 160) continue;
        #pragma unroll
        for (int m=0; m<2; ++m) {
            const int px = p0 + pxh*32 + m*16 + lr;
            const float pyv = (float)(px>>5)*0.03125f - 0.5f;
            const float pxv = (float)(px&31)*0.03125f - 0.5f;
            #pragma unroll
            for (int r=0; r<4; ++r) {
                const int mm = row0 + lg*4 + r;
                const float val = acc[f][m][r] + bias[mm]
                                + qkvw[(size_t)mm*130 + 128]*pyv
                                + qkvw[(size_t)mm*130 + 129]*pxv;
                if (mm < 16)      qo[((size_t)b*HW+px)*16 + mm]        = f2bf(0.25f*val);
                else if (mm < 32) ko[((size_t)b*HW+px)*16 + (mm-16)]   = f2bf(val);
                else              vo[((size_t)b*128 + (mm-32))*HW + px] = f2bf(val);
            }
        }
    }
}

// ---------------------------------------------------------------------------
// MFMA causal attention (r7-proven), 4 waves: 2 q-tiles x 2 d-halves.
// ---------------------------------------------------------------------------
__global__ __launch_bounds__(256)
void attn_mfma(const u16* __restrict__ qb, const u16* __restrict__ kb,
               const u16* __restrict__ vb, u16* __restrict__ ob)
{
    __shared__ u16 ks_[2][32*24];
    __shared__ u16 vs_[2][128*40];
    const int tid = threadIdx.x;
    const int bid = blockIdx.x;              // 0..511
    const int tp  = 15 - (bid >> 5);         // tile-pair, long first
    const int b   = bid & 31;
    const int wv = tid>>6, lane = tid&63;
    const int lq = lane&31, hf = lane>>5;
    const int qt = tp*2 + (wv&1);
    const int dh = wv>>1;
    const int q0 = qt*32;
    const int NC = tp*2 + 2;

    const short8v Qf = *(const short8v*)(qb + ((size_t)b*HW + q0 + lq)*16 + hf*8);
    f32x16 acc[2] = {{},{}};
    float mrun = -1e30f, lrun = 0.f;
    unsigned diagm = 0;
    #pragma unroll
    for (int r=0; r<16; ++r) {
        const int row = (r&3) + 8*(r>>2) + 4*hf;
        diagm |= (row <= lq) ? (1u<<r) : 0u;
    }
    const f32x16 zc = {};

    const int vrow = tid>>2, vg = tid&3;
    const int krow = tid>>1, kg = tid&1;
    const u16* vbb = vb + (size_t)b*128*HW;
    const u16* kbb = kb + (size_t)b*HW*16;
    uint4 rv0A, rv1A, rkA, rv0B, rv1B, rkB;

#define AGLD(c, RV0, RV1, RK) do {                                             \
    const int kv0_ = (c)*32;                                                   \
    RV0 = *(const uint4*)(vbb + (size_t)vrow*HW + kv0_ + vg*8);                \
    RV1 = *(const uint4*)(vbb + (size_t)(64+vrow)*HW + kv0_ + vg*8);           \
    if (tid < 64) RK = *(const uint4*)(kbb + (size_t)(kv0_ + krow)*16 + kg*8); \
} while(0)
#define ASST(buf, RV0, RV1, RK) do {                                           \
    *(uint4*)&vs_[buf][vrow*40 + vg*8] = RV0;                                  \
    *(uint4*)&vs_[buf][(64+vrow)*40 + vg*8] = RV1;                             \
    if (tid < 64) *(uint4*)&ks_[buf][krow*24 + kg*8] = RK;                     \
} while(0)

    auto CHUNK = [&](int buf, int cc) {
        if (cc > qt) return;
        const short8v Kf = *(const short8v*)&ks_[buf][lq*24 + hf*8];
        f32x16 st = __builtin_amdgcn_mfma_f32_32x32x16_bf16(Kf, Qf, zc, 0,0,0);
        if (cc == qt) {
            #pragma unroll
            for (int r=0;r<16;++r) st[r] = ((diagm>>r)&1) ? st[r] : -1e30f;
        }
        float mc = st[0];
        #pragma unroll
        for (int r=1;r<16;++r) mc = fmaxf(mc, st[r]);
        mc = fmaxf(mc, __shfl_xor(mc, 32));
        if (!__all(mc <= mrun)) {
            const float mnew = fmaxf(mrun, mc);
            const float corr = __expf(mrun - mnew);
            lrun *= corr;
            #pragma unroll
            for (int f=0;f<2;++f)
                #pragma unroll
                for (int r=0;r<16;++r) acc[f][r] *= corr;
            mrun = mnew;
        }
        float ps[16]; float lsum = 0.f;
        #pragma unroll
        for (int r=0;r<16;++r){ ps[r]=__expf(st[r]-mrun); lsum += ps[r]; }
        lrun += lsum + __shfl_xor(lsum, 32);
        unsigned pk[8], sw[8];
        #pragma unroll
        for (int i=0;i<8;++i)
            pk[i] = (unsigned)f2bf(ps[2*i]) | ((unsigned)f2bf(ps[2*i+1])<<16);
        #pragma unroll
        for (int i=0;i<8;++i) sw[i] = __shfl_xor(pk[i], 32);
        union { unsigned u[4]; short8v v; } B1, B2;
        B1.u[0]=hf?sw[2]:pk[0]; B1.u[1]=hf?sw[3]:pk[1];
        B1.u[2]=hf?pk[2]:sw[0]; B1.u[3]=hf?pk[3]:sw[1];
        B2.u[0]=hf?sw[6]:pk[4]; B2.u[1]=hf?sw[7]:pk[5];
        B2.u[2]=hf?pk[6]:sw[4]; B2.u[3]=hf?pk[7]:sw[5];
        #pragma unroll
        for (int f=0;f<2;++f) {
            const int fg = dh*2 + f;
            const short8v A1 = *(const short8v*)&vs_[buf][(fg*32+lq)*40 + hf*8];
            const short8v A2 = *(const short8v*)&vs_[buf][(fg*32+lq)*40 + 16 + hf*8];
            acc[f] = __builtin_amdgcn_mfma_f32_32x32x16_bf16(A1, B1.v, acc[f],0,0,0);
            acc[f] = __builtin_amdgcn_mfma_f32_32x32x16_bf16(A2, B2.v, acc[f],0,0,0);
        }
    };

    AGLD(0, rv0A, rv1A, rkA); ASST(0, rv0A, rv1A, rkA);
    AGLD(1, rv0B, rv1B, rkB);
    __syncthreads();
    for (int c = 0; c < NC; c += 2) {
        CHUNK(0, c);
        ASST(1, rv0B, rv1B, rkB);
        if (c+2 < NC) AGLD(c+2, rv0A, rv1A, rkA);
        __syncthreads();
        CHUNK(1, c+1);
        if (c+2 < NC) {
            ASST(0, rv0A, rv1A, rkA);
            if (c+3 < NC) AGLD(c+3, rv0B, rv1B, rkB);
        }
        __syncthreads();
    }
#undef AGLD
#undef ASST

    const float inv = 1.f / lrun;
    u16* orow = ob + ((size_t)b*HW + q0 + lq)*128;
    #pragma unroll
    for (int f=0; f<2; ++f) {
        #pragma unroll
        for (int g=0; g<4; ++g) {
            const int d0 = (dh*2+f)*32 + 8*g + 4*hf;
            ushort4 o4;
            o4.x = f2bf(acc[f][g*4+0]*inv);
            o4.y = f2bf(acc[f][g*4+1]*inv);
            o4.z = f2bf(acc[f][g*4+2]*inv);
            o4.w = f2bf(acc[f][g*4+3]*inv);
            *(ushort4*)(orow + d0) = o4;
        }
    }
}

extern "C" void kernel_launch(void* const* d_in, const int* in_sizes, int n_in,
                              void* d_out, int out_size, void* d_ws, size_t ws_size,
                              hipStream_t stream) {
    const float* x    = (const float*)d_in[0];
    const float* rw1  = (const float*)d_in[1];
    const float* rb1  = (const float*)d_in[2];
    const float* rw2  = (const float*)d_in[3];
    const float* rb2  = (const float*)d_in[4];
    const float* qkvw = (const float*)d_in[5];
    const float* qkvb = (const float*)d_in[6];
    const float* apw  = (const float*)d_in[7];
    const float* apb  = (const float*)d_in[8];
    const float* ocw  = (const float*)d_in[9];
    const float* ocb  = (const float*)d_in[10];
    const float* oaw  = (const float*)d_in[11];
    const float* oab  = (const float*)d_in[12];
    const float* opw  = (const float*)d_in[13];
    const float* opb  = (const float*)d_in[14];
    float* out = (float*)d_out;
    float* ws = (float*)d_ws;

    // Workspace (float offsets, <= 16M floats = 64 MiB):
    u16* Sb  = (u16*)ws;                     // padded bf16 state (B,PB,128)
    u16* Eb  = (u16*)(ws + 2293760);         // padded bf16(elu(state))
    u16* E2  = (u16*)(ws + 4587520);         // padded conv1 out
    u16* ob  = (u16*)(ws + 6881280);         // (B,HW,128) attn out; later Es
    u16* qb  = (u16*)(ws + 8978432);
    u16* kb  = (u16*)(ws + 9240576);
    u16* vb  = (u16*)(ws + 9502720);         // V^T (B,128,HW)
    u16* w1b = (u16*)(ws + 11599872);        // 6*128*512
    u16* w2b = (u16*)(ws + 11796480);        // 6*256*512
    u16* whs = (u16*)(ws + 12189696);        // 4*128*128 swizzled
    u16* qws = (u16*)(ws + 12222464);        // 192*128 swizzled
    u16* Ea  = (u16*)(ws + 12234752);        // (B,HW,128) elu(attn_out)
    u16* c1p = (u16*)(ws + 14331904);        // (B,HW,128) elu(c1)
    u16* Es  = ob;

    dim3 blk(256);
    wconv<<<4960, blk, 0, stream>>>(rw1, rw2, apw, ocw, oaw, opw, qkvw, w1b, w2b, whs, qws);
    gz<<<384, blk, 0, stream>>>(Eb, E2);
    init_k<<<dim3(32, 32), blk, 0, stream>>>(x, Sb, Eb);
    for (int i = 0; i < 6; ++i) {
        convg<32,0><<<dim3(32,1,32), blk, 0, stream>>>(
            w1b + (size_t)i*65536, rb1 + i*128, Eb, E2, nullptr);
        convg<64,1><<<dim3(16,2,32), blk, 0, stream>>>(
            w2b + (size_t)i*131072, rb2 + i*256, E2, Eb, Sb);
    }
    qkvg<<<dim3(16,1,32), blk, 0, stream>>>(qws, qkvw, qkvb, Sb, qb, kb, vb);
    attn_mfma<<<512, blk, 0, stream>>>(qb, kb, vb, ob);
    // g0 (by=0): Ea = elu(attn_proj(ob)); g1 (by=1): c1p = elu(out_conv(Eb))
    headg<0,1><<<dim3(16,2,32), blk, 0, stream>>>(
        whs, apb, ocb, ob, Eb, Ea, c1p, nullptr, nullptr, nullptr);
    // g2: Es = elu(c1p + elu(out_attn(Ea)))
    headg<2,0><<<dim3(16,1,32), blk, 0, stream>>>(
        whs + 32768, oab, nullptr, Ea, nullptr, Es, nullptr, c1p, nullptr, nullptr);
    // g3: out = elu(out_proj(Es)) + x
    headg<3,0><<<dim3(16,1,32), blk, 0, stream>>>(
        whs + 49152, opb, nullptr, Es, nullptr, nullptr, nullptr, nullptr, x, out);
}

// Round 10
// 258.748 us; speedup vs baseline: 2.1612x; 1.0773x over previous
//
#include <hip/hip_runtime.h>
#include <math.h>

#define HW 1024
#define RS 33            // padded row stride (32 px + 1 zero col)
#define GP 34            // zero guard pixels before each image
#define PB 1120          // padded pixels per batch image

typedef unsigned short u16;
typedef __attribute__((ext_vector_type(8))) short short8v;   // 8 bf16
typedef __attribute__((ext_vector_type(4))) float f32x4;
typedef __attribute__((ext_vector_type(16))) float f32x16;

__device__ __forceinline__ float elu_f(float x){ return x>0.f? x : (__expf(x)-1.f); }
__device__ __forceinline__ float sig_f(float x){ return 1.f/(1.f+__expf(-x)); }
__device__ __forceinline__ u16 f2bf(float f){ unsigned u=__float_as_uint(f); return (u16)((u + 0x7fffu + ((u>>16)&1u))>>16); }
__device__ __forceinline__ float bf2f(u16 h){ return __uint_as_float(((unsigned)h)<<16); }

__device__ __forceinline__ void gld16(const void* g, void* l) {
    __builtin_amdgcn_global_load_lds(
        (const __attribute__((address_space(1))) void*)g,
        (__attribute__((address_space(3))) void*)l, 16, 0, 0);
}

// ---------------------------------------------------------------------------
// Merged one-time weight convert + guard-slot zeroing.
// All GEMM weights get the BK64 granule-XOR swizzle baked in (stored slot s of
// row r holds granule g = s^(r&7)); conv weights tap-major K; conv2 weights
// pre-interleaved to gate Bs-row order. Tail blocks zero Eb/E2 guard slots.
// ---------------------------------------------------------------------------
__global__ __launch_bounds__(256)
void wconv(const float* __restrict__ rw1, const float* __restrict__ rw2,
           const float* __restrict__ apw, const float* __restrict__ ocw,
           const float* __restrict__ oaw, const float* __restrict__ opw,
           const float* __restrict__ qkvw,
           u16* __restrict__ w1b, u16* __restrict__ w2b,
           u16* __restrict__ whs, u16* __restrict__ qws,
           u16* __restrict__ Eb,  u16* __restrict__ E2)
{
    const int i = blockIdx.x*256 + threadIdx.x;
    if (i < 393216) {                       // conv1 weights: 6*128*512
        const int layer = i >> 16;
        const int r = (i >> 9) & 127;
        const int k = i & 511;
        const int ks = k >> 6, s = (k >> 3) & 7, j = k & 7;
        const int g = s ^ (r & 7);
        const int tap = ks >> 1;
        const int c = ((ks & 1) << 6) + g*8 + j;
        w1b[i] = f2bf(rw1[(size_t)layer*65536 + r*512 + c*4 + tap]);
    } else if (i < 1179648) {               // conv2 weights: 6*256*512
        const int ii = i - 393216;
        const int layer = ii >> 17;
        const int R = (ii >> 9) & 255;
        const int k = ii & 511;
        const int by = R >> 7, r = R & 127;
        const int h = (r >> 6) & 1, f2 = (r >> 4) & 3, rr = r & 15;
        const int ch = (f2 < 2) ? (by*64 + h*32 + f2*16 + rr)
                                : (128 + by*64 + h*32 + (f2-2)*16 + rr);
        const int ks = k >> 6, s = (k >> 3) & 7, j = k & 7;
        const int g = s ^ (R & 7);
        const int tap = ks >> 1;
        const int c = ((ks & 1) << 6) + g*8 + j;
        w2b[ii] = f2bf(rw2[(size_t)layer*131072 + ch*512 + c*4 + tap]);
    } else if (i < 1245184) {               // head 1x1 weights: 4*128*128, swizzled
        const int ii = i - 1179648;
        const int m = ii >> 14;
        const int rem = ii & 16383;
        const int r = rem >> 7, k = rem & 127;
        const int ks = k >> 6, s = (k >> 3) & 7, j = k & 7;
        const int g = s ^ (r & 7);
        const int c = (ks << 6) + g*8 + j;
        const float* src = (m==0)? apw : (m==1)? ocw : (m==2)? oaw : opw;
        whs[ii] = f2bf(src[r*128 + c]);
    } else if (i < 1269760) {               // qkv weights padded to 192 rows, swizzled
        const int ii = i - 1245184;
        const int r = ii >> 7, k = ii & 127;
        const int ks = k >> 6, s = (k >> 3) & 7, j = k & 7;
        const int g = s ^ (r & 7);
        const int c = (ks << 6) + g*8 + j;
        qws[ii] = (r < 160) ? f2bf(qkvw[(size_t)r*130 + c]) : (u16)0;
    } else if (i < 1368064) {               // guard-slot zeroing (2*49152 slots of 8 u16)
        const int ii = i - 1269760;
        const int half = ii / 49152;
        const int idx = ii % 49152;
        const int b = idx / 1536;
        const int rem = idx % 1536;
        const int g = rem >> 4, c8 = rem & 15;
        const int slot = (g < 34) ? g : (g < 65) ? (66 + 33*(g-34)) : (1089 + (g-65));
        u16* dst = (half ? E2 : Eb) + ((size_t)b*PB + slot)*128 + c8*8;
        uint4 z; z.x=0u; z.y=0u; z.z=0u; z.w=0u;
        *(uint4*)dst = z;
    }
}

// ---------------------------------------------------------------------------
// init: x (B,128,HW) f32 -> Sb (B,PB,128) bf16 state + Eb bf16(elu(x)) padded
// ---------------------------------------------------------------------------
__global__ __launch_bounds__(256)
void init_k(const float* __restrict__ x, u16* __restrict__ Sb, u16* __restrict__ Eb)
{
    __shared__ float t[32][132];
    const int b = blockIdx.y, p0 = blockIdx.x*32;
    const int tid = threadIdx.x;
    const int cr = tid >> 3, p4 = (tid & 7)*4;
    #pragma unroll
    for (int cc = 0; cc < 128; cc += 32) {
        const float4 v = *(const float4*)(x + ((size_t)b*128 + cc + cr)*HW + p0 + p4);
        t[p4+0][cc+cr]=v.x; t[p4+1][cc+cr]=v.y; t[p4+2][cc+cr]=v.z; t[p4+3][cc+cr]=v.w;
    }
    __syncthreads();
    const int pr = tid >> 3, c4 = (tid & 7)*4;
    const int px = p0 + pr;
    const int pad = GP + px + (px>>5);
    #pragma unroll
    for (int cc = 0; cc < 128; cc += 32) {
        const int c = cc + c4;
        float4 v; v.x=t[pr][c]; v.y=t[pr][c+1]; v.z=t[pr][c+2]; v.w=t[pr][c+3];
        ushort4 s4;
        s4.x=f2bf(v.x); s4.y=f2bf(v.y); s4.z=f2bf(v.z); s4.w=f2bf(v.w);
        *(ushort4*)(Sb + ((size_t)b*PB + pad)*128 + c) = s4;
        ushort4 e;
        e.x=f2bf(elu_f(v.x)); e.y=f2bf(elu_f(v.y)); e.z=f2bf(elu_f(v.z)); e.w=f2bf(elu_f(v.w));
        *(ushort4*)(Eb + ((size_t)b*PB + pad)*128 + c) = e;
    }
}

// ---------------------------------------------------------------------------
// global_load_lds conv2x2 GEMM, 3-buffer LDS pipeline with counted vmcnt:
// per step: wait vmcnt(6) [2-steps-old buffer landed; newer 6 loads stay in
// flight across the barrier] -> s_barrier -> issue stage(ks+2) -> compute(ks).
// EPI 0: out0 = bf16(elu(acc+bias)) padded                          (conv1)
// EPI 1: gate: o = Sio + t1*sig(t2); Sio=bf16(o); out0=bf16(elu(o)) (conv2)
// ---------------------------------------------------------------------------
#define GSTAGE(ks, buf) do {                                                     \
    const int tap_ = (ks) >> 1;                                                  \
    const int off_ = (tap_>>1)*RS + (tap_&1) - RS - 1;                           \
    const int c0_  = ((ks) & 1) << 6;                                            \
    _Pragma("unroll")                                                            \
    for (int ca_=0; ca_<2; ++ca_) {                                              \
        const int row_ = ca_*32 + wv*8 + (lane>>3);                              \
        const int px_  = p0 + row_;                                              \
        const int pad_ = GP + px_ + (px_>>5);                                    \
        const int g_   = (lane&7) ^ (lane>>3);                                   \
        gld16(ebB + (size_t)(pad_ + off_)*128 + c0_ + g_*8,                      \
              (char*)As[buf] + (ca_*32 + wv*8)*128 + lane*16);                   \
    }                                                                            \
    _Pragma("unroll")                                                            \
    for (int cb_=0; cb_<4; ++cb_) {                                              \
        const int row_ = cb_*32 + wv*8 + (lane>>3);                              \
        gld16(wbB + (size_t)row_*512 + (ks)*64 + (lane&7)*8,                     \
              (char*)Bs[buf] + (cb_*32 + wv*8)*128 + lane*16);                   \
    }                                                                            \
} while(0)

#define GCOMP(buf) do {                                                          \
    _Pragma("unroll")                                                            \
    for (int k2_=0; k2_<2; ++k2_) {                                              \
        short8v wf_[4], pf_[2];                                                  \
        const int sl_ = ((k2_*4 + lg) ^ (lr & 7)) * 8;                           \
        _Pragma("unroll")                                                        \
        for (int f_=0; f_<4; ++f_)                                               \
            wf_[f_] = *(const short8v*)&Bs[buf][(chh*64 + f_*16 + lr)*64 + sl_]; \
        _Pragma("unroll")                                                        \
        for (int m_=0; m_<2; ++m_)                                               \
            pf_[m_] = *(const short8v*)&As[buf][(pxh*32 + m_*16 + lr)*64 + sl_]; \
        _Pragma("unroll")                                                        \
        for (int f_=0; f_<4; ++f_)                                               \
            _Pragma("unroll")                                                    \
            for (int m_=0; m_<2; ++m_)                                           \
                acc[f_][m_] = __builtin_amdgcn_mfma_f32_16x16x32_bf16(wf_[f_], pf_[m_], acc[f_][m_],0,0,0); \
    }                                                                            \
} while(0)

template<int EPI>
__global__ __launch_bounds__(256)
void convg(const u16* __restrict__ Wb, const float* __restrict__ bias,
           const u16* __restrict__ Ein, u16* __restrict__ out0,
           u16* __restrict__ Sio)
{
    constexpr int NS = 8;              // K=512, BK=64, BM=64
    __shared__ u16 As[3][64*64];
    __shared__ u16 Bs[3][128*64];
    const int tid = threadIdx.x;
    const int b = blockIdx.z, p0 = blockIdx.x*64, cb0 = blockIdx.y*64;
    const int wv = tid>>6, lane = tid&63, lr = lane&15, lg = lane>>4;
    const int pxh = wv&1, chh = wv>>1;
    const u16* ebB = Ein + (size_t)b*PB*128;
    const u16* wbB = Wb + (size_t)blockIdx.y*128*512;
    f32x4 acc[4][2] = {};

    GSTAGE(0, 0);
    GSTAGE(1, 1);
    #pragma unroll
    for (int ks = 0; ks < NS; ++ks) {
        if (ks < NS-1) asm volatile("s_waitcnt vmcnt(6)" ::: "memory");
        else           asm volatile("s_waitcnt vmcnt(0)" ::: "memory");
        __builtin_amdgcn_s_barrier();
        __builtin_amdgcn_sched_barrier(0);
        if (ks + 2 < NS) GSTAGE(ks+2, (ks+2)%3);
        GCOMP(ks%3);
    }

    if constexpr (EPI == 1) {
        #pragma unroll
        for (int f=0; f<2; ++f) {
            const int c = cb0 + chh*32 + f*16 + lg*4;
            const float4 b1 = *(const float4*)(bias + c);
            const float4 b2 = *(const float4*)(bias + 128 + c);
            #pragma unroll
            for (int m=0; m<2; ++m) {
                const int px = p0 + pxh*32 + m*16 + lr;
                const int pad = GP + px + (px>>5);
                u16* sp = Sio + ((size_t)b*PB + pad)*128 + c;
                const ushort4 sv = *(const ushort4*)sp;
                const float o0 = bf2f(sv.x) + (acc[f][m][0]+b1.x)*sig_f(acc[f+2][m][0]+b2.x);
                const float o1 = bf2f(sv.y) + (acc[f][m][1]+b1.y)*sig_f(acc[f+2][m][1]+b2.y);
                const float o2 = bf2f(sv.z) + (acc[f][m][2]+b1.z)*sig_f(acc[f+2][m][2]+b2.z);
                const float o3 = bf2f(sv.w) + (acc[f][m][3]+b1.w)*sig_f(acc[f+2][m][3]+b2.w);
                ushort4 so;
                so.x=f2bf(o0); so.y=f2bf(o1); so.z=f2bf(o2); so.w=f2bf(o3);
                *(ushort4*)sp = so;
                ushort4 e;
                e.x=f2bf(elu_f(o0)); e.y=f2bf(elu_f(o1)); e.z=f2bf(elu_f(o2)); e.w=f2bf(elu_f(o3));
                *(ushort4*)(out0 + ((size_t)b*PB + pad)*128 + c) = e;
            }
        }
    } else {
        #pragma unroll
        for (int f=0; f<4; ++f) {
            const int c = chh*64 + f*16 + lg*4;
            const float4 bb = *(const float4*)(bias + c);
            #pragma unroll
            for (int m=0; m<2; ++m) {
                const int px = p0 + pxh*32 + m*16 + lr;
                const int pad = GP + px + (px>>5);
                ushort4 e;
                e.x=f2bf(elu_f(acc[f][m][0]+bb.x));
                e.y=f2bf(elu_f(acc[f][m][1]+bb.y));
                e.z=f2bf(elu_f(acc[f][m][2]+bb.z));
                e.w=f2bf(elu_f(acc[f][m][3]+bb.w));
                *(ushort4*)(out0 + ((size_t)b*PB + pad)*128 + c) = e;
            }
        }
    }
}

// ---------------------------------------------------------------------------
// Head 1x1 GEMM, gload_lds BK=64, NS=2, counted-vmcnt dbuf. BM=64.
// EPI 0 (DUAL): by=0: dst0 = bf16(elu(W0·in0 + bias0))   (attn_proj, unpadded in)
//               by=1: dst1 = bf16(elu(W1·in1 + bias1))   (out_conv, padded in)
// EPI 2: dst0 = bf16(elu( aux + elu(acc+bias0) ))        (out_attn + add c1)
// EPI 3: fout[ch-major] = elu(acc+bias0) + xres          (out_proj, f32)
// ---------------------------------------------------------------------------
template<int EPI, int DUAL>
__global__ __launch_bounds__(256)
void headg(const u16* __restrict__ Wh,
           const float* __restrict__ bias0, const float* __restrict__ bias1,
           const u16* __restrict__ in0, const u16* __restrict__ in1,
           u16* __restrict__ dst0, u16* __restrict__ dst1,
           const u16* __restrict__ aux, const float* __restrict__ xres,
           float* __restrict__ fout)
{
    __shared__ u16 As[2][64*64];
    __shared__ u16 Bs[2][128*64];
    const int tid = threadIdx.x;
    const int b = blockIdx.z, p0 = blockIdx.x*64;
    const int by = DUAL ? (int)blockIdx.y : 0;
    const int wv = tid>>6, lane = tid&63, lr = lane&15, lg = lane>>4;
    const int pxh = wv&1, chh = wv>>1;
    const u16* wsrcB = Wh + (size_t)by*16384;
    const float* bias = (DUAL && by) ? bias1 : bias0;
    const u16* inB = (DUAL && by) ? in1 : in0;
    f32x4 acc[4][2] = {};

    auto HSTAGE = [&](int ks, int buf) {
        #pragma unroll
        for (int ca=0; ca<2; ++ca) {
            const int row = ca*32 + wv*8 + (lane>>3);
            const int px = p0 + row;
            size_t aoff;
            if (DUAL && by) aoff = (size_t)b*PB + (GP + px + (px>>5));
            else            aoff = (size_t)b*HW + px;
            const int g = (lane&7) ^ (lane>>3);
            gld16(inB + aoff*128 + ks*64 + g*8,
                  (char*)As[buf] + (ca*32 + wv*8)*128 + lane*16);
        }
        #pragma unroll
        for (int cb=0; cb<4; ++cb) {
            const int row = cb*32 + wv*8 + (lane>>3);
            gld16(wsrcB + (size_t)row*128 + ks*64 + (lane&7)*8,
                  (char*)Bs[buf] + (cb*32 + wv*8)*128 + lane*16);
        }
    };
    auto HCOMP = [&](int buf) {
        #pragma unroll
        for (int k2=0; k2<2; ++k2) {
            short8v wf[4], pf[2];
            const int sl = ((k2*4 + lg) ^ (lr & 7)) * 8;
            #pragma unroll
            for (int f=0; f<4; ++f)
                wf[f] = *(const short8v*)&Bs[buf][(chh*64 + f*16 + lr)*64 + sl];
            #pragma unroll
            for (int m=0; m<2; ++m)
                pf[m] = *(const short8v*)&As[buf][(pxh*32 + m*16 + lr)*64 + sl];
            #pragma unroll
            for (int f=0; f<4; ++f)
                #pragma unroll
                for (int m=0; m<2; ++m)
                    acc[f][m] = __builtin_amdgcn_mfma_f32_16x16x32_bf16(wf[f], pf[m], acc[f][m],0,0,0);
        }
    };

    HSTAGE(0, 0);
    HSTAGE(1, 1);
    asm volatile("s_waitcnt vmcnt(6)" ::: "memory");
    __builtin_amdgcn_s_barrier();
    __builtin_amdgcn_sched_barrier(0);
    HCOMP(0);
    asm volatile("s_waitcnt vmcnt(0)" ::: "memory");
    __builtin_amdgcn_s_barrier();
    __builtin_amdgcn_sched_barrier(0);
    HCOMP(1);

    #pragma unroll
    for (int f=0; f<4; ++f) {
        const int c = chh*64 + f*16 + lg*4;
        #pragma unroll
        for (int m=0; m<2; ++m) {
            const int px = p0 + pxh*32 + m*16 + lr;
            if constexpr (EPI == 3) {
                const float* bp = bias + c;
                #pragma unroll
                for (int r=0; r<4; ++r) {
                    const size_t o = ((size_t)b*128 + c + r)*HW + px;
                    fout[o] = elu_f(acc[f][m][r] + bp[r]) + xres[o];
                }
            } else {
                const float4 bb = *(const float4*)(bias + c);
                const float v0=acc[f][m][0]+bb.x, v1=acc[f][m][1]+bb.y;
                const float v2=acc[f][m][2]+bb.z, v3=acc[f][m][3]+bb.w;
                ushort4 e;
                if constexpr (EPI == 2) {
                    const ushort4 c4 = *(const ushort4*)(aux + ((size_t)b*HW+px)*128 + c);
                    e.x = f2bf(elu_f(bf2f(c4.x) + elu_f(v0)));
                    e.y = f2bf(elu_f(bf2f(c4.y) + elu_f(v1)));
                    e.z = f2bf(elu_f(bf2f(c4.z) + elu_f(v2)));
                    e.w = f2bf(elu_f(bf2f(c4.w) + elu_f(v3)));
                } else {
                    e.x=f2bf(elu_f(v0)); e.y=f2bf(elu_f(v1));
                    e.z=f2bf(elu_f(v2)); e.w=f2bf(elu_f(v3));
                }
                u16* dst = (DUAL && by) ? dst1 : dst0;
                *(ushort4*)(dst + ((size_t)b*HW+px)*128 + c) = e;
            }
        }
    }
}

// ---------------------------------------------------------------------------
// qkv GEMM, gload_lds BK=64, NS=2, NOUT=192 (padded), counted-vmcnt dbuf.
// ---------------------------------------------------------------------------
__global__ __launch_bounds__(256)
void qkvg(const u16* __restrict__ Wq, const float* __restrict__ qkvw,
          const float* __restrict__ bias, const u16* __restrict__ Sb,
          u16* __restrict__ qo, u16* __restrict__ ko, u16* __restrict__ vo)
{
    __shared__ u16 As[2][64*64];
    __shared__ u16 Bs[2][192*64];
    const int tid = threadIdx.x;
    const int b = blockIdx.z, p0 = blockIdx.x*64;
    const int wv = tid>>6, lane = tid&63, lr = lane&15, lg = lane>>4;
    const int pxh = wv&1, chh = wv>>1;
    const u16* ebB = Sb + (size_t)b*PB*128;
    f32x4 acc[6][2] = {};

    auto QSTAGE = [&](int ks, int buf) {
        #pragma unroll
        for (int ca=0; ca<2; ++ca) {
            const int row = ca*32 + wv*8 + (lane>>3);
            const int px = p0 + row;
            const int pad = GP + px + (px>>5);
            const int g = (lane&7) ^ (lane>>3);
            gld16(ebB + (size_t)pad*128 + ks*64 + g*8,
                  (char*)As[buf] + (ca*32 + wv*8)*128 + lane*16);
        }
        #pragma unroll
        for (int cb=0; cb<6; ++cb) {
            const int row = cb*32 + wv*8 + (lane>>3);
            gld16(Wq + (size_t)row*128 + ks*64 + (lane&7)*8,
                  (char*)Bs[buf] + (cb*32 + wv*8)*128 + lane*16);
        }
    };
    auto QCOMP = [&](int buf) {
        #pragma unroll
        for (int k2=0; k2<2; ++k2) {
            short8v wf[6], pf[2];
            const int sl = ((k2*4 + lg) ^ (lr & 7)) * 8;
            #pragma unroll
            for (int f=0; f<6; ++f)
                wf[f] = *(const short8v*)&Bs[buf][(chh*96 + f*16 + lr)*64 + sl];
            #pragma unroll
            for (int m=0; m<2; ++m)
                pf[m] = *(const short8v*)&As[buf][(pxh*32 + m*16 + lr)*64 + sl];
            #pragma unroll
            for (int f=0; f<6; ++f)
                #pragma unroll
                for (int m=0; m<2; ++m)
                    acc[f][m] = __builtin_amdgcn_mfma_f32_16x16x32_bf16(wf[f], pf[m], acc[f][m],0,0,0);
        }
    };

    QSTAGE(0, 0);
    QSTAGE(1, 1);
    asm volatile("s_waitcnt vmcnt(8)" ::: "memory");
    __builtin_amdgcn_s_barrier();
    __builtin_amdgcn_sched_barrier(0);
    QCOMP(0);
    asm volatile("s_waitcnt vmcnt(0)" ::: "memory");
    __builtin_amdgcn_s_barrier();
    __builtin_amdgcn_sched_barrier(0);
    QCOMP(1);

    #pragma unroll
    for (int f=0; f<6; ++f) {
        const int row0 = chh*96 + f*16;
        if (row0 >= 160) continue;
        #pragma unroll
        for (int m=0; m<2; ++m) {
            const int px = p0 + pxh*32 + m*16 + lr;
            const float pyv = (float)(px>>5)*0.03125f - 0.5f;
            const float pxv = (float)(px&31)*0.03125f - 0.5f;
            #pragma unroll
            for (int r=0; r<4; ++r) {
                const int mm = row0 + lg*4 + r;
                const float val = acc[f][m][r] + bias[mm]
                                + qkvw[(size_t)mm*130 + 128]*pyv
                                + qkvw[(size_t)mm*130 + 129]*pxv;
                if (mm < 16)      qo[((size_t)b*HW+px)*16 + mm]        = f2bf(0.25f*val);
                else if (mm < 32) ko[((size_t)b*HW+px)*16 + (mm-16)]   = f2bf(val);
                else              vo[((size_t)b*128 + (mm-32))*HW + px] = f2bf(val);
            }
        }
    }
}

// ---------------------------------------------------------------------------
// MFMA causal attention (r7-proven), 4 waves: 2 q-tiles x 2 d-halves.
// ---------------------------------------------------------------------------
__global__ __launch_bounds__(256)
void attn_mfma(const u16* __restrict__ qb, const u16* __restrict__ kb,
               const u16* __restrict__ vb, u16* __restrict__ ob)
{
    __shared__ u16 ks_[2][32*24];
    __shared__ u16 vs_[2][128*40];
    const int tid = threadIdx.x;
    const int bid = blockIdx.x;              // 0..511
    const int tp  = 15 - (bid >> 5);         // tile-pair, long first
    const int b   = bid & 31;
    const int wv = tid>>6, lane = tid&63;
    const int lq = lane&31, hf = lane>>5;
    const int qt = tp*2 + (wv&1);
    const int dh = wv>>1;
    const int q0 = qt*32;
    const int NC = tp*2 + 2;

    const short8v Qf = *(const short8v*)(qb + ((size_t)b*HW + q0 + lq)*16 + hf*8);
    f32x16 acc[2] = {{},{}};
    float mrun = -1e30f, lrun = 0.f;
    unsigned diagm = 0;
    #pragma unroll
    for (int r=0; r<16; ++r) {
        const int row = (r&3) + 8*(r>>2) + 4*hf;
        diagm |= (row <= lq) ? (1u<<r) : 0u;
    }
    const f32x16 zc = {};

    const int vrow = tid>>2, vg = tid&3;
    const int krow = tid>>1, kg = tid&1;
    const u16* vbb = vb + (size_t)b*128*HW;
    const u16* kbb = kb + (size_t)b*HW*16;
    uint4 rv0A, rv1A, rkA, rv0B, rv1B, rkB;

#define AGLD(c, RV0, RV1, RK) do {                                             \
    const int kv0_ = (c)*32;                                                   \
    RV0 = *(const uint4*)(vbb + (size_t)vrow*HW + kv0_ + vg*8);                \
    RV1 = *(const uint4*)(vbb + (size_t)(64+vrow)*HW + kv0_ + vg*8);           \
    if (tid < 64) RK = *(const uint4*)(kbb + (size_t)(kv0_ + krow)*16 + kg*8); \
} while(0)
#define ASST(buf, RV0, RV1, RK) do {                                           \
    *(uint4*)&vs_[buf][vrow*40 + vg*8] = RV0;                                  \
    *(uint4*)&vs_[buf][(64+vrow)*40 + vg*8] = RV1;                             \
    if (tid < 64) *(uint4*)&ks_[buf][krow*24 + kg*8] = RK;                     \
} while(0)

    auto CHUNK = [&](int buf, int cc) {
        if (cc > qt) return;
        const short8v Kf = *(const short8v*)&ks_[buf][lq*24 + hf*8];
        f32x16 st = __builtin_amdgcn_mfma_f32_32x32x16_bf16(Kf, Qf, zc, 0,0,0);
        if (cc == qt) {
            #pragma unroll
            for (int r=0;r<16;++r) st[r] = ((diagm>>r)&1) ? st[r] : -1e30f;
        }
        float mc = st[0];
        #pragma unroll
        for (int r=1;r<16;++r) mc = fmaxf(mc, st[r]);
        mc = fmaxf(mc, __shfl_xor(mc, 32));
        if (!__all(mc <= mrun)) {
            const float mnew = fmaxf(mrun, mc);
            const float corr = __expf(mrun - mnew);
            lrun *= corr;
            #pragma unroll
            for (int f=0;f<2;++f)
                #pragma unroll
                for (int r=0;r<16;++r) acc[f][r] *= corr;
            mrun = mnew;
        }
        float ps[16]; float lsum = 0.f;
        #pragma unroll
        for (int r=0;r<16;++r){ ps[r]=__expf(st[r]-mrun); lsum += ps[r]; }
        lrun += lsum + __shfl_xor(lsum, 32);
        unsigned pk[8], sw[8];
        #pragma unroll
        for (int i=0;i<8;++i)
            pk[i] = (unsigned)f2bf(ps[2*i]) | ((unsigned)f2bf(ps[2*i+1])<<16);
        #pragma unroll
        for (int i=0;i<8;++i) sw[i] = __shfl_xor(pk[i], 32);
        union { unsigned u[4]; short8v v; } B1, B2;
        B1.u[0]=hf?sw[2]:pk[0]; B1.u[1]=hf?sw[3]:pk[1];
        B1.u[2]=hf?pk[2]:sw[0]; B1.u[3]=hf?pk[3]:sw[1];
        B2.u[0]=hf?sw[6]:pk[4]; B2.u[1]=hf?sw[7]:pk[5];
        B2.u[2]=hf?pk[6]:sw[4]; B2.u[3]=hf?pk[7]:sw[5];
        #pragma unroll
        for (int f=0;f<2;++f) {
            const int fg = dh*2 + f;
            const short8v A1 = *(const short8v*)&vs_[buf][(fg*32+lq)*40 + hf*8];
            const short8v A2 = *(const short8v*)&vs_[buf][(fg*32+lq)*40 + 16 + hf*8];
            acc[f] = __builtin_amdgcn_mfma_f32_32x32x16_bf16(A1, B1.v, acc[f],0,0,0);
            acc[f] = __builtin_amdgcn_mfma_f32_32x32x16_bf16(A2, B2.v, acc[f],0,0,0);
        }
    };

    AGLD(0, rv0A, rv1A, rkA); ASST(0, rv0A, rv1A, rkA);
    AGLD(1, rv0B, rv1B, rkB);
    __syncthreads();
    for (int c = 0; c < NC; c += 2) {
        CHUNK(0, c);
        ASST(1, rv0B, rv1B, rkB);
        if (c+2 < NC) AGLD(c+2, rv0A, rv1A, rkA);
        __syncthreads();
        CHUNK(1, c+1);
        if (c+2 < NC) {
            ASST(0, rv0A, rv1A, rkA);
            if (c+3 < NC) AGLD(c+3, rv0B, rv1B, rkB);
        }
        __syncthreads();
    }
#undef AGLD
#undef ASST

    const float inv = 1.f / lrun;
    u16* orow = ob + ((size_t)b*HW + q0 + lq)*128;
    #pragma unroll
    for (int f=0; f<2; ++f) {
        #pragma unroll
        for (int g=0; g<4; ++g) {
            const int d0 = (dh*2+f)*32 + 8*g + 4*hf;
            ushort4 o4;
            o4.x = f2bf(acc[f][g*4+0]*inv);
            o4.y = f2bf(acc[f][g*4+1]*inv);
            o4.z = f2bf(acc[f][g*4+2]*inv);
            o4.w = f2bf(acc[f][g*4+3]*inv);
            *(ushort4*)(orow + d0) = o4;
        }
    }
}

extern "C" void kernel_launch(void* const* d_in, const int* in_sizes, int n_in,
                              void* d_out, int out_size, void* d_ws, size_t ws_size,
                              hipStream_t stream) {
    const float* x    = (const float*)d_in[0];
    const float* rw1  = (const float*)d_in[1];
    const float* rb1  = (const float*)d_in[2];
    const float* rw2  = (const float*)d_in[3];
    const float* rb2  = (const float*)d_in[4];
    const float* qkvw = (const float*)d_in[5];
    const float* qkvb = (const float*)d_in[6];
    const float* apw  = (const float*)d_in[7];
    const float* apb  = (const float*)d_in[8];
    const float* ocw  = (const float*)d_in[9];
    const float* ocb  = (const float*)d_in[10];
    const float* oaw  = (const float*)d_in[11];
    const float* oab  = (const float*)d_in[12];
    const float* opw  = (const float*)d_in[13];
    const float* opb  = (const float*)d_in[14];
    float* out = (float*)d_out;
    float* ws = (float*)d_ws;

    // Workspace (float offsets, <= 16M floats = 64 MiB):
    u16* Sb  = (u16*)ws;                     // padded bf16 state (B,PB,128)
    u16* Eb  = (u16*)(ws + 2293760);         // padded bf16(elu(state))
    u16* E2  = (u16*)(ws + 4587520);         // padded conv1 out
    u16* ob  = (u16*)(ws + 6881280);         // (B,HW,128) attn out; later Es
    u16* qb  = (u16*)(ws + 8978432);
    u16* kb  = (u16*)(ws + 9240576);
    u16* vb  = (u16*)(ws + 9502720);         // V^T (B,128,HW)
    u16* w1b = (u16*)(ws + 11599872);        // 6*128*512
    u16* w2b = (u16*)(ws + 11796480);        // 6*256*512
    u16* whs = (u16*)(ws + 12189696);        // 4*128*128 swizzled
    u16* qws = (u16*)(ws + 12222464);        // 192*128 swizzled
    u16* Ea  = (u16*)(ws + 12234752);        // (B,HW,128) elu(attn_out)
    u16* c1p = (u16*)(ws + 14331904);        // (B,HW,128) elu(c1)
    u16* Es  = ob;

    dim3 blk(256);
    wconv<<<5344, blk, 0, stream>>>(rw1, rw2, apw, ocw, oaw, opw, qkvw,
                                    w1b, w2b, whs, qws, Eb, E2);
    init_k<<<dim3(32, 32), blk, 0, stream>>>(x, Sb, Eb);
    for (int i = 0; i < 6; ++i) {
        convg<0><<<dim3(16,1,32), blk, 0, stream>>>(
            w1b + (size_t)i*65536, rb1 + i*128, Eb, E2, nullptr);
        convg<1><<<dim3(16,2,32), blk, 0, stream>>>(
            w2b + (size_t)i*131072, rb2 + i*256, E2, Eb, Sb);
    }
    qkvg<<<dim3(16,1,32), blk, 0, stream>>>(qws, qkvw, qkvb, Sb, qb, kb, vb);
    attn_mfma<<<512, blk, 0, stream>>>(qb, kb, vb, ob);
    // g0 (by=0): Ea = elu(attn_proj(ob)); g1 (by=1): c1p = elu(out_conv(Eb))
    headg<0,1><<<dim3(16,2,32), blk, 0, stream>>>(
        whs, apb, ocb, ob, Eb, Ea, c1p, nullptr, nullptr, nullptr);
    // g2: Es = elu(c1p + elu(out_attn(Ea)))
    headg<2,0><<<dim3(16,1,32), blk, 0, stream>>>(
        whs + 32768, oab, nullptr, Ea, nullptr, Es, nullptr, c1p, nullptr, nullptr);
    // g3: out = elu(out_proj(Es)) + x
    headg<3,0><<<dim3(16,1,32), blk, 0, stream>>>(
        whs + 49152, opb, nullptr, Es, nullptr, nullptr, nullptr, nullptr, x, out);
}